// Round 2
// 347.512 us; speedup vs baseline: 1.0438x; 1.0438x over previous
//
#include <hip/hip_runtime.h>
#include <hip/hip_bf16.h>
#include <cstdint>

#define DI __device__ __forceinline__

typedef unsigned short u16;
typedef __bf16 bf16x8 __attribute__((ext_vector_type(8)));
typedef float f32x4 __attribute__((ext_vector_type(4)));

constexpr int Bc  = 2;
constexpr int Sc  = 1024;
constexpr int Cc  = 1024;
constexpr int Hc  = 16;
constexpr int HDc = 64;
constexpr int S2c = 2048;
constexpr int ECc = 4096;
constexpr int BSc  = Bc * Sc;   // 2048
constexpr int BS2c = Bc * S2c;  // 4096

constexpr int EPI_KV = 0, EPI_Q = 1, EPI_O = 3, EPI_GELU = 4, EPI_FINAL = 5, EPI_PART = 6;

DI u16 f2b(float f) {
  __hip_bfloat16 h = __float2bfloat16(f);
  u16 u;
  __builtin_memcpy(&u, &h, 2);
  return u;
}

// fast bf16 pack (round-half-up); fine for p in [0,1]
DI u16 f2b_fast(float f) {
  uint32_t u;
  __builtin_memcpy(&u, &f, 4);
  return (u16)((u + 0x8000u) >> 16);
}

// CK-style direct global->LDS (16B per lane; LDS dest = wave-uniform base + lane*16)
DI void glds16(const void* g, void* l) {
  auto* lp = reinterpret_cast<__attribute__((address_space(3))) uint32_t*>(
      reinterpret_cast<uintptr_t>(l));
  __builtin_amdgcn_global_load_lds(
      reinterpret_cast<const __attribute__((address_space(1))) uint32_t*>(
          reinterpret_cast<uintptr_t>(g)),
      lp, 16, 0, 0);
}

DI f32x4 mfma16(bf16x8 a, bf16x8 b, f32x4 c) {
  return __builtin_amdgcn_mfma_f32_16x16x32_bf16(a, b, c, 0, 0, 0);
}

// ------------- fused transpose of the four CxC weights: WT[n][k] = W[k][n] -------------
__global__ __launch_bounds__(256) void transpose4_kernel(const float* __restrict__ Wq,
                                                         const float* __restrict__ Wk,
                                                         const float* __restrict__ Wv,
                                                         const float* __restrict__ Wo,
                                                         u16* __restrict__ WqT,
                                                         u16* __restrict__ WkvT,
                                                         u16* __restrict__ WoT) {
  __shared__ float tile[32][33];
  const int z = blockIdx.z;
  const float* W = (z == 0) ? Wq : (z == 1) ? Wk : (z == 2) ? Wv : Wo;
  u16* WT = (z == 0) ? WqT : (z == 1) ? WkvT : (z == 2) ? (WkvT + (size_t)Cc * Cc) : WoT;
  const int bx = blockIdx.x, by = blockIdx.y;
  const int tx = threadIdx.x, ty = threadIdx.y;
  const int c = bx * 32 + tx;
#pragma unroll
  for (int i = ty; i < 32; i += 8) tile[i][tx] = W[(size_t)(by * 32 + i) * Cc + c];
  __syncthreads();
#pragma unroll
  for (int i = ty; i < 32; i += 8)
    WT[(size_t)(bx * 32 + i) * Cc + by * 32 + tx] = f2b(tile[tx][i]);
}

// ---------------- transpose + fp32->bf16 convert: WT[n][k] = W[k][n] ----------------
__global__ __launch_bounds__(256) void transpose_kernel(const float* __restrict__ W,
                                                        u16* __restrict__ WT, int R, int Cn) {
  __shared__ float tile[32][33];
  const int bx = blockIdx.x, by = blockIdx.y;
  const int tx = threadIdx.x, ty = threadIdx.y;
  const int c = bx * 32 + tx;
#pragma unroll
  for (int i = ty; i < 32; i += 8) tile[i][tx] = W[(size_t)(by * 32 + i) * Cn + c];
  __syncthreads();
#pragma unroll
  for (int i = ty; i < 32; i += 8)
    WT[(size_t)(bx * 32 + i) * R + by * 32 + tx] = f2b(tile[tx][i]);
}

// ---------------- prep: comb + LN(comb)->cx ; LN(all_embed)->ae ----------------
__global__ __launch_bounds__(256) void prep_ln_kernel(
    const float* __restrict__ fwd, const float* __restrict__ bwd, const float* __restrict__ g,
    const float* __restrict__ be, float* __restrict__ comb, u16* __restrict__ cx,
    u16* __restrict__ ae) {
  __shared__ float red[2][4];
  const int row = blockIdx.x, tid = threadIdx.x;
  const int c = tid * 4;
  float4 x;
  u16* dst;
  if (row < BSc) {
    const int b = row >> 10, s = row & (Sc - 1);
    const float4 f = *(const float4*)(fwd + ((size_t)(b * (Sc + 1) + s)) * Cc + c);
    const float4 r = *(const float4*)(bwd + ((size_t)(b * (Sc + 1) + s + 1)) * Cc + c);
    const float k = 0.70710678118654752f;
    x.x = (f.x + r.x) * k; x.y = (f.y + r.y) * k;
    x.z = (f.z + r.z) * k; x.w = (f.w + r.w) * k;
    *(float4*)(comb + (size_t)row * Cc + c) = x;
    dst = cx + (size_t)row * Cc;
  } else {
    const int idx = row - BSc;
    const int b = idx >> 11, t = idx & (S2c - 1);
    const float* src = (t < Sc) ? (fwd + ((size_t)(b * (Sc + 1) + t)) * Cc)
                                : (bwd + ((size_t)(b * (Sc + 1) + (t - Sc) + 1)) * Cc);
    x = *(const float4*)(src + c);
    dst = ae + (size_t)idx * Cc;
  }
  float s1 = x.x + x.y + x.z + x.w;
  float s2 = x.x * x.x + x.y * x.y + x.z * x.z + x.w * x.w;
  for (int off = 32; off; off >>= 1) { s1 += __shfl_down(s1, off); s2 += __shfl_down(s2, off); }
  if ((tid & 63) == 0) { red[0][tid >> 6] = s1; red[1][tid >> 6] = s2; }
  __syncthreads();
  s1 = red[0][0] + red[0][1] + red[0][2] + red[0][3];
  s2 = red[1][0] + red[1][1] + red[1][2] + red[1][3];
  const float mean = s1 * (1.0f / Cc);
  const float rstd = rsqrtf(s2 * (1.0f / Cc) - mean * mean + 1e-5f);
  const float4 gv = *(const float4*)(g + c);
  const float4 bv = *(const float4*)(be + c);
  ushort4 o;
  o.x = f2b((x.x - mean) * rstd * gv.x + bv.x);
  o.y = f2b((x.y - mean) * rstd * gv.y + bv.y);
  o.z = f2b((x.z - mean) * rstd * gv.z + bv.z);
  o.w = f2b((x.w - mean) * rstd * gv.w + bv.w);
  *(ushort4*)(dst + c) = o;
}

// ---------------- double LN: h = LN(LN(x,g2,b2),gm,bm) ----------------
__global__ __launch_bounds__(256) void ln2_kernel(const float* __restrict__ x,
                                                  const float* __restrict__ g2,
                                                  const float* __restrict__ b2,
                                                  const float* __restrict__ gm,
                                                  const float* __restrict__ bm,
                                                  u16* __restrict__ h) {
  __shared__ float red[2][4];
  const int row = blockIdx.x, tid = threadIdx.x;
  const int c = tid * 4;
  const float4 v = *(const float4*)(x + (size_t)row * Cc + c);
  float s1 = v.x + v.y + v.z + v.w;
  float s2 = v.x * v.x + v.y * v.y + v.z * v.z + v.w * v.w;
  for (int off = 32; off; off >>= 1) { s1 += __shfl_down(s1, off); s2 += __shfl_down(s2, off); }
  if ((tid & 63) == 0) { red[0][tid >> 6] = s1; red[1][tid >> 6] = s2; }
  __syncthreads();
  s1 = red[0][0] + red[0][1] + red[0][2] + red[0][3];
  s2 = red[1][0] + red[1][1] + red[1][2] + red[1][3];
  float mean = s1 * (1.0f / Cc);
  float rstd = rsqrtf(s2 * (1.0f / Cc) - mean * mean + 1e-5f);
  const float4 ga = *(const float4*)(g2 + c);
  const float4 ba = *(const float4*)(b2 + c);
  const float t0 = (v.x - mean) * rstd * ga.x + ba.x;
  const float t1 = (v.y - mean) * rstd * ga.y + ba.y;
  const float t2 = (v.z - mean) * rstd * ga.z + ba.z;
  const float t3 = (v.w - mean) * rstd * ga.w + ba.w;
  s1 = t0 + t1 + t2 + t3;
  s2 = t0 * t0 + t1 * t1 + t2 * t2 + t3 * t3;
  for (int off = 32; off; off >>= 1) { s1 += __shfl_down(s1, off); s2 += __shfl_down(s2, off); }
  __syncthreads();
  if ((tid & 63) == 0) { red[0][tid >> 6] = s1; red[1][tid >> 6] = s2; }
  __syncthreads();
  s1 = red[0][0] + red[0][1] + red[0][2] + red[0][3];
  s2 = red[1][0] + red[1][1] + red[1][2] + red[1][3];
  mean = s1 * (1.0f / Cc);
  rstd = rsqrtf(s2 * (1.0f / Cc) - mean * mean + 1e-5f);
  const float4 gb = *(const float4*)(gm + c);
  const float4 bb = *(const float4*)(bm + c);
  ushort4 o;
  o.x = f2b((t0 - mean) * rstd * gb.x + bb.x);
  o.y = f2b((t1 - mean) * rstd * gb.y + bb.y);
  o.z = f2b((t2 - mean) * rstd * gb.z + bb.z);
  o.w = f2b((t3 - mean) * rstd * gb.w + bb.w);
  *(ushort4*)(h + (size_t)row * Cc + c) = o;
}

// ---------------- GEMM: Y = A(MxK) @ BT(NxK)^T, fused epilogues ----------------
// 128x128 tile, 4 waves (64x64 each), BK=32, glds16 staging.
// R10/R11: T3-minimum 2-phase double-buffered K-loop (catalog recipe): issue next
// tile's glds16 BEFORE the ds_read+MFMA of the current tile, ONE barrier per
// K-step (the implicit vmcnt(0)+lgkmcnt(0) drain of __syncthreads). Loads for
// tile t+1 are in flight across the whole MFMA phase of tile t, fixing the
// exposed-latency stall of the previous 2-barrier loop (MfmaUtil 15% at only
// 2 blocks/CU). LDS 16->32 KB. NT = Ks/32 is even for every shape used here.
// Optional split-K via gridDim.z: slice z covers K/SK; EPI_PART writes raw
// f32 partials to pbuf[z].
template <int EPI, int SK>
__global__ __launch_bounds__(256) void gemm_kernel(
    const u16* __restrict__ A, const u16* __restrict__ BT, const float* __restrict__ bias,
    const float* __restrict__ bias2, const float* __restrict__ pos,
    u16* __restrict__ outb, u16* __restrict__ out2, float* __restrict__ pbuf,
    int M, int N, int K) {
  __shared__ u16 Asm[2][128 * 32];
  __shared__ u16 Bsm[2][128 * 32];
  const int tid = threadIdx.x;
  const int w = tid >> 6, lane = tid & 63, quad = lane >> 4, r16 = lane & 15;
  const int bm = blockIdx.y * 128, bn = blockIdx.x * 128;
  const int wm = (w & 1) * 64, wn = (w >> 1) * 64;
  const int Ks = K / SK, kb0 = blockIdx.z * Ks;

  const int srow = lane >> 2, scol = (lane & 3) * 8;
  const u16* aP = A + (size_t)(bm + w * 32 + srow) * K + kb0 + scol;
  const u16* bP = BT + (size_t)(bn + w * 32 + srow) * K + kb0 + scol;
  const size_t rstep = (size_t)16 * K;
  const int l0 = (w * 32) * 32;        // wave-uniform LDS stage base (u16 offset)
  const int l1 = (w * 32 + 16) * 32;

  f32x4 acc[4][4] = {};

  auto STAGE = [&](int buf, int ko) {
    glds16(aP + ko, &Asm[buf][l0]);
    glds16(aP + ko + rstep, &Asm[buf][l1]);
    glds16(bP + ko, &Bsm[buf][l0]);
    glds16(bP + ko + rstep, &Bsm[buf][l1]);
  };
  auto COMPUTE = [&](int buf) {
    bf16x8 af[4], bfr[4];
#pragma unroll
    for (int i = 0; i < 4; i++) {
      af[i] = *reinterpret_cast<const bf16x8*>(&Asm[buf][(wm + i * 16 + r16) * 32 + quad * 8]);
      bfr[i] = *reinterpret_cast<const bf16x8*>(&Bsm[buf][(wn + i * 16 + r16) * 32 + quad * 8]);
    }
#pragma unroll
    for (int mi = 0; mi < 4; mi++)
#pragma unroll
      for (int ni = 0; ni < 4; ni++) acc[mi][ni] = mfma16(af[mi], bfr[ni], acc[mi][ni]);
  };

  const int NT = Ks / 32;
  STAGE(0, 0);
  __syncthreads();
  for (int t = 0; t < NT; t += 2) {
    STAGE(1, (t + 1) * 32);   // in flight during COMPUTE(0); drained at the barrier
    COMPUTE(0);
    __syncthreads();
    if (t + 2 < NT) STAGE(0, (t + 2) * 32);
    COMPUTE(1);
    __syncthreads();
  }

#pragma unroll
  for (int mi = 0; mi < 4; mi++) {
#pragma unroll
    for (int ni = 0; ni < 4; ni++) {
      const int col = bn + wn + ni * 16 + r16;
      const int row0 = bm + wm + mi * 16 + quad * 4;
      if constexpr (EPI == EPI_PART) {
        float* pb = pbuf + (size_t)blockIdx.z * M * N;
#pragma unroll
        for (int r = 0; r < 4; r++) pb[(size_t)(row0 + r) * N + col] = acc[mi][ni][r];
      } else if constexpr (EPI == EPI_KV) {
        if (col < Cc) {
#pragma unroll
          for (int r = 0; r < 4; r++) {
            const int row = row0 + r;
            const int key = row & (S2c - 1);
            const float y =
                acc[mi][ni][r] + bias[col] + pos[(key & (Sc - 1)) * HDc + (col & 63)];
            outb[(size_t)row * Cc + col] = f2b(y);
          }
        } else {
          const int c2 = col - Cc;
          const int h = c2 >> 6, d = c2 & 63;
          const int b = row0 >> 11, key0 = row0 & (S2c - 1);
          const float bb = bias2[c2];
          ushort4 pk;
          pk.x = f2b(acc[mi][ni][0] + bb);
          pk.y = f2b(acc[mi][ni][1] + bb);
          pk.z = f2b(acc[mi][ni][2] + bb);
          pk.w = f2b(acc[mi][ni][3] + bb);
          *(ushort4*)&out2[(((size_t)(b * Hc + h) * HDc + d) << 11) + key0] = pk;
        }
      } else {  // EPI_GELU
#pragma unroll
        for (int r = 0; r < 4; r++) {
          const float y = acc[mi][ni][r] + bias[col];
          outb[(size_t)(row0 + r) * N + col] =
              f2b(0.5f * y * (1.0f + erff(y * 0.70710678118654752f)));
        }
      }
    }
  }
}

// ---------------- split-K reduce + epilogue (SK slices of MxN f32) ----------------
// EPI_Q: out = bf16((sum + bias + pos) * scale) ; EPI_O/EPI_FINAL: out = f32(sum + bias + add)
template <int EPI, int SK>
__global__ __launch_bounds__(256) void reduce_kernel(const float* __restrict__ pbuf,
                                                     const float* __restrict__ bias,
                                                     const float* __restrict__ pos,
                                                     const float* __restrict__ addsrc,
                                                     u16* __restrict__ outb,
                                                     float* __restrict__ outf, int M, int N) {
  const size_t flat = ((size_t)blockIdx.x * 256 + threadIdx.x) * 4;
  const int row = (int)(flat / N), col = (int)(flat % N);
  const size_t MN = (size_t)M * N;
  float4 s = *(const float4*)(pbuf + flat);
#pragma unroll
  for (int z = 1; z < SK; z++) {
    const float4 v = *(const float4*)(pbuf + z * MN + flat);
    s.x += v.x; s.y += v.y; s.z += v.z; s.w += v.w;
  }
  const float4 bv = *(const float4*)(bias + col);
  s.x += bv.x; s.y += bv.y; s.z += bv.z; s.w += bv.w;
  if constexpr (EPI == EPI_Q) {
    const int sq = row & (Sc - 1), d = col & 63;
    const float4 pv = *(const float4*)(pos + sq * HDc + d);
    constexpr float sc = 0.180336880111120426f;  // (1/8)*log2(e)
    ushort4 o;
    o.x = f2b((s.x + pv.x) * sc);
    o.y = f2b((s.y + pv.y) * sc);
    o.z = f2b((s.z + pv.z) * sc);
    o.w = f2b((s.w + pv.w) * sc);
    *(ushort4*)(outb + flat) = o;
  } else {
    const float4 av = *(const float4*)(addsrc + flat);
    float4 o;
    o.x = s.x + av.x; o.y = s.y + av.y; o.z = s.z + av.z; o.w = s.w + av.w;
    *(float4*)(outf + flat) = o;
  }
}

// ---------------- attention partials: grid (bh, qt, half) ----------------
// K/V tiles staged ONCE per block via cooperative glds16 into LDS (shared by all 4
// waves — R8/R9 loaded them 4x redundantly through VGPRs and the allocator
// serialized the loads). 2-barrier unit loop, GEMM-style. Sub-tiles use 64-B rows
// so fragment ds_read_b128 banks = (r16&1)*16+quad*4 -> 2-way (free).
// qb: [b,q,h,d] bf16 (pre-scaled by (1/8)*log2e); kb: [b,key(2S),h,d]; vT: [b,h,d,key(2S)]
__global__ __launch_bounds__(256) void attn_part_kernel(const u16* __restrict__ qb,
                                                        const u16* __restrict__ kb,
                                                        const u16* __restrict__ vT,
                                                        float* __restrict__ o_part,
                                                        float* __restrict__ l_part) {
  const int bh = blockIdx.x;
  const int qt = blockIdx.y;
  const int half = blockIdx.z;
  const int b = bh >> 4, head = bh & 15;
  const int tid = threadIdx.x;
  const int w = tid >> 6, lane = tid & 63, quad = lane >> 4, r16 = lane & 15;

  __shared__ u16 Kt[2][64 * 32];  // [ks][key][32 d]   rows 64 B
  __shared__ u16 Vt[2][64 * 32];  // [ks][d][32 keys]  rows 64 B
  __shared__ u16 Ps[4][16 * 68];  // per-wave P round-trip (stride 68: conflict-free)
  u16* ps = Ps[w];

  const int q0 = qt * 64;
  const int qw = q0 + w * 16;  // this wave's 16 queries

  bf16x8 aq[2];
  {
    const u16* qp = qb + ((size_t)((b * Sc + qw + r16) * Hc + head)) * HDc + quad * 8;
    aq[0] = *(const bf16x8*)qp;
    aq[1] = *(const bf16x8*)(qp + 32);
  }

  const size_t krow = (size_t)Hc * HDc;
  const u16* kbase = kb + ((size_t)b * S2c * Hc + head) * HDc;
  const u16* vbase = vT + ((size_t)(b * Hc + head)) * HDc * S2c;

  // cooperative staging map: wave w covers rows w*16 + lane/4, 16 B at (lane&3)*8
  const int srow = w * 16 + (lane >> 2);
  const int scol = (lane & 3) * 8;
  u16* kD0 = &Kt[0][w * 16 * 32];
  u16* kD1 = &Kt[1][w * 16 * 32];
  u16* vD0 = &Vt[0][w * 16 * 32];
  u16* vD1 = &Vt[1][w * 16 * 32];
  const u16* kS = kbase + (size_t)srow * krow + scol;   // + key0*krow (+32 for ks=1)
  const u16* vS = vbase + (size_t)srow * S2c + scol;    // + key0     (+32 for ks=1)

  f32x4 o_acc[4] = {};
  float lsum[4] = {};

  const int n = (half == 0) ? (qt + 1) : (16 - qt);
  const int kb0 = (half == 0) ? 0 : Sc + qt * 64;  // unit j covers keys kb0 + j*64 ..

  for (int j = 0; j < n; j++) {
    const int k0 = kb0 + j * 64;
    glds16(kS + (size_t)k0 * krow, kD0);
    glds16(kS + (size_t)k0 * krow + 32, kD1);
    glds16(vS + k0, vD0);
    glds16(vS + k0 + 32, vD1);
    __syncthreads();

    // QK^T from LDS
    f32x4 sacc[4] = {};
#pragma unroll
    for (int ks = 0; ks < 2; ks++)
#pragma unroll
      for (int ni = 0; ni < 4; ni++) {
        const bf16x8 bk = *(const bf16x8*)&Kt[ks][(ni * 16 + r16) * 32 + quad * 8];
        sacc[ni] = mfma16(aq[ks], bk, sacc[ni]);
      }

    const int mode = (half == 0) ? ((j == n - 1) ? 1 : 0) : ((j == 0) ? 2 : 0);
#pragma unroll
    for (int r = 0; r < 4; r++) {
      const int qrow = qw + quad * 4 + r;
#pragma unroll
      for (int ni = 0; ni < 4; ni++) {
        float s = sacc[ni][r];
        if (mode == 1) { const int key = k0 + ni * 16 + r16; if (key > qrow) s = -128.0f; }
        else if (mode == 2) { const int key = k0 - Sc + ni * 16 + r16; if (key < qrow) s = -128.0f; }
        const float pe = __builtin_amdgcn_exp2f(s);
        lsum[r] += pe;
        ps[(quad * 4 + r) * 68 + ni * 16 + r16] = f2b_fast(pe);
      }
    }

    // PV from LDS
#pragma unroll
    for (int ks = 0; ks < 2; ks++) {
      const bf16x8 ap = *(const bf16x8*)(&ps[r16 * 68 + ks * 32 + quad * 8]);
#pragma unroll
      for (int ni = 0; ni < 4; ni++) {
        const bf16x8 bv_ = *(const bf16x8*)&Vt[ks][(ni * 16 + r16) * 32 + quad * 8];
        o_acc[ni] = mfma16(ap, bv_, o_acc[ni]);
      }
    }
    __syncthreads();
  }

#pragma unroll
  for (int r = 0; r < 4; r++) {
    float l = lsum[r];
    l += __shfl_xor(l, 1);
    l += __shfl_xor(l, 2);
    l += __shfl_xor(l, 4);
    l += __shfl_xor(l, 8);
    lsum[r] = l;
  }

  const size_t rowbase = (((size_t)half * Bc + b) * Hc + head) * Sc + qw;
  float* ob = o_part + rowbase * HDc;
#pragma unroll
  for (int r = 0; r < 4; r++) {
    const int rl = quad * 4 + r;
#pragma unroll
    for (int ni = 0; ni < 4; ni++) ob[(size_t)rl * HDc + ni * 16 + r16] = o_acc[ni][r];
    if (r16 == 0) l_part[rowbase + rl] = lsum[r];
  }
}

// ---------------- combine halves + normalize -> bf16 [b,q,h,d] ----------------
__global__ __launch_bounds__(256) void attn_norm_kernel(const float* __restrict__ o_part,
                                                        const float* __restrict__ l_part,
                                                        u16* __restrict__ ob) {
  constexpr size_t HS = (size_t)Bc * Hc * Sc * HDc;
  constexpr size_t HL = (size_t)Bc * Hc * Sc;
  const int flat = blockIdx.x * 256 + threadIdx.x;
  const int row = flat >> 4, d0 = (flat & 15) * 4;
  const int q = row & (Sc - 1), h = (row >> 10) & 15, b = row >> 14;
  const float4 o0 = *(const float4*)(o_part + (size_t)row * HDc + d0);
  const float4 o1 = *(const float4*)(o_part + HS + (size_t)row * HDc + d0);
  const float rl = 1.0f / (l_part[row] + l_part[HL + row]);
  ushort4 o;
  o.x = f2b((o0.x + o1.x) * rl);
  o.y = f2b((o0.y + o1.y) * rl);
  o.z = f2b((o0.z + o1.z) * rl);
  o.w = f2b((o0.w + o1.w) * rl);
  *(ushort4*)(ob + ((size_t)((b * Sc + q) * Hc + h)) * HDc + d0) = o;
}

extern "C" void kernel_launch(void* const* d_in, const int* in_sizes, int n_in, void* d_out,
                              int out_size, void* d_ws, size_t ws_size, hipStream_t stream) {
  const float* fwd = (const float*)d_in[0];
  const float* bwd = (const float*)d_in[1];
  const float* pos = (const float*)d_in[2];
  const float* ln1g = (const float*)d_in[3];
  const float* ln1b = (const float*)d_in[4];
  const float* Wq = (const float*)d_in[5];
  const float* bq = (const float*)d_in[6];
  const float* Wk = (const float*)d_in[7];
  const float* bk = (const float*)d_in[8];
  const float* Wv = (const float*)d_in[9];
  const float* bv = (const float*)d_in[10];
  const float* Wo = (const float*)d_in[11];
  const float* bo = (const float*)d_in[12];
  const float* ln2g = (const float*)d_in[13];
  const float* ln2b = (const float*)d_in[14];
  const float* mlpg = (const float*)d_in[15];
  const float* mlpb = (const float*)d_in[16];
  const float* W1 = (const float*)d_in[17];
  const float* b1 = (const float*)d_in[18];
  const float* W2 = (const float*)d_in[19];
  const float* b2 = (const float*)d_in[20];

  char* p = (char*)d_ws;
  auto alloc = [&](size_t bytes) -> char* {
    char* r = p;
    p += (bytes + 255) & ~(size_t)255;
    return r;
  };
  float* comb = (float*)alloc((size_t)BSc * Cc * 4);
  float* xbuf = (float*)alloc((size_t)BSc * Cc * 4);
  u16* cx = (u16*)alloc((size_t)BSc * Cc * 2);
  u16* ae = (u16*)alloc((size_t)BS2c * Cc * 2);
  u16* qbuf = (u16*)alloc((size_t)BSc * Cc * 2);
  u16* kbuf = (u16*)alloc((size_t)BS2c * Cc * 2);
  u16* vTb = (u16*)alloc((size_t)BS2c * Cc * 2);
  u16* obuf = (u16*)alloc((size_t)BSc * Cc * 2);
  u16* hb = (u16*)alloc((size_t)BSc * Cc * 2);
  char* big = alloc((size_t)2 * BSc * Hc * HDc * 4 > (size_t)BSc * ECc * 2
                        ? (size_t)2 * BSc * Hc * HDc * 4
                        : (size_t)BSc * ECc * 2);
  float* o_part = (float*)big;
  u16* midb = (u16*)big;
  float* l_part = (float*)alloc((size_t)2 * Bc * Hc * Sc * 4);
  float* pbuf = (float*)alloc((size_t)4 * BSc * Cc * 4);  // 4 split-K slices of 2048x1024 f32
  u16* WqT = (u16*)alloc((size_t)Cc * Cc * 2);
  u16* WkvT = (u16*)alloc((size_t)2 * Cc * Cc * 2);
  u16* WoT = (u16*)alloc((size_t)Cc * Cc * 2);
  u16* W1T = (u16*)alloc((size_t)ECc * Cc * 2);
  u16* W2T = (u16*)alloc((size_t)Cc * ECc * 2);

  const dim3 tb(32, 8);
  transpose4_kernel<<<dim3(32, 32, 4), tb, 0, stream>>>(Wq, Wk, Wv, Wo, WqT, WkvT, WoT);
  transpose_kernel<<<dim3(128, 32), tb, 0, stream>>>(W1, W1T, Cc, ECc);
  transpose_kernel<<<dim3(32, 128), tb, 0, stream>>>(W2, W2T, ECc, Cc);

  prep_ln_kernel<<<BSc + BS2c, 256, 0, stream>>>(fwd, bwd, ln1g, ln1b, comb, cx, ae);

  // Q = cx @ WqT^T  (split-K=4 -> 512 blocks)
  gemm_kernel<EPI_PART, 4><<<dim3(Cc / 128, BSc / 128, 4), 256, 0, stream>>>(
      cx, WqT, nullptr, nullptr, nullptr, nullptr, nullptr, pbuf, BSc, Cc, Cc);
  reduce_kernel<EPI_Q, 4><<<(BSc * Cc / 4) / 256, 256, 0, stream>>>(
      pbuf, bq, pos, nullptr, qbuf, nullptr, BSc, Cc);

  // K,V fused (N=2048, 512 blocks)
  gemm_kernel<EPI_KV, 1><<<dim3(2 * Cc / 128, BS2c / 128, 1), 256, 0, stream>>>(
      ae, WkvT, bk, bv, pos, kbuf, vTb, nullptr, BS2c, 2 * Cc, Cc);

  attn_part_kernel<<<dim3(Bc * Hc, Sc / 64, 2), 256, 0, stream>>>(qbuf, kbuf, vTb, o_part,
                                                                  l_part);
  attn_norm_kernel<<<(BSc * Hc * HDc / 4) / 256, 256, 0, stream>>>(o_part, l_part, obuf);

  // x = comb + (o @ WoT^T + bo)  (split-K=4)
  gemm_kernel<EPI_PART, 4><<<dim3(Cc / 128, BSc / 128, 4), 256, 0, stream>>>(
      obuf, WoT, nullptr, nullptr, nullptr, nullptr, nullptr, pbuf, BSc, Cc, Cc);
  reduce_kernel<EPI_O, 4><<<(BSc * Cc / 4) / 256, 256, 0, stream>>>(
      pbuf, bo, nullptr, comb, nullptr, xbuf, BSc, Cc);

  ln2_kernel<<<BSc, 256, 0, stream>>>(xbuf, ln2g, ln2b, mlpg, mlpb, hb);

  // mid = gelu(h @ W1T^T + b1)  (512 blocks)
  gemm_kernel<EPI_GELU, 1><<<dim3(ECc / 128, BSc / 128, 1), 256, 0, stream>>>(
      hb, W1T, b1, nullptr, nullptr, midb, nullptr, nullptr, BSc, ECc, Cc);

  // out = x + (mid @ W2T^T + b2)  (split-K=4 over K=4096 -> 512 blocks)
  gemm_kernel<EPI_PART, 4><<<dim3(Cc / 128, BSc / 128, 4), 256, 0, stream>>>(
      midb, W2T, nullptr, nullptr, nullptr, nullptr, nullptr, pbuf, BSc, Cc, ECc);
  reduce_kernel<EPI_FINAL, 4><<<(BSc * Cc / 4) / 256, 256, 0, stream>>>(
      pbuf, b2, nullptr, xbuf, nullptr, (float*)d_out, BSc, Cc);
}

// Round 3
// 339.385 us; speedup vs baseline: 1.0687x; 1.0239x over previous
//
#include <hip/hip_runtime.h>
#include <hip/hip_bf16.h>
#include <cstdint>

#define DI __device__ __forceinline__

typedef unsigned short u16;
typedef __bf16 bf16x8 __attribute__((ext_vector_type(8)));
typedef float f32x4 __attribute__((ext_vector_type(4)));

constexpr int Bc  = 2;
constexpr int Sc  = 1024;
constexpr int Cc  = 1024;
constexpr int Hc  = 16;
constexpr int HDc = 64;
constexpr int S2c = 2048;
constexpr int ECc = 4096;
constexpr int BSc  = Bc * Sc;   // 2048
constexpr int BS2c = Bc * S2c;  // 4096

constexpr int EPI_KV = 0, EPI_Q = 1, EPI_O = 3, EPI_GELU = 4, EPI_FINAL = 5, EPI_PART = 6;

DI u16 f2b(float f) {
  __hip_bfloat16 h = __float2bfloat16(f);
  u16 u;
  __builtin_memcpy(&u, &h, 2);
  return u;
}

// fast bf16 pack (round-half-up); fine for p in [0,1]
DI u16 f2b_fast(float f) {
  uint32_t u;
  __builtin_memcpy(&u, &f, 4);
  return (u16)((u + 0x8000u) >> 16);
}

// CK-style direct global->LDS (16B per lane; LDS dest = wave-uniform base + lane*16)
DI void glds16(const void* g, void* l) {
  auto* lp = reinterpret_cast<__attribute__((address_space(3))) uint32_t*>(
      reinterpret_cast<uintptr_t>(l));
  __builtin_amdgcn_global_load_lds(
      reinterpret_cast<const __attribute__((address_space(1))) uint32_t*>(
          reinterpret_cast<uintptr_t>(g)),
      lp, 16, 0, 0);
}

DI f32x4 mfma16(bf16x8 a, bf16x8 b, f32x4 c) {
  return __builtin_amdgcn_mfma_f32_16x16x32_bf16(a, b, c, 0, 0, 0);
}

// counted vmcnt wait + scheduling fence (rule #18: pin code motion around inline-asm waits)
#define PIPE_WAIT(N)                                            \
  do {                                                          \
    asm volatile("s_waitcnt vmcnt(" #N ")" ::: "memory");       \
    __builtin_amdgcn_sched_barrier(0);                          \
  } while (0)
#define PIPE_BAR()                                              \
  do {                                                          \
    __builtin_amdgcn_s_barrier();                               \
    __builtin_amdgcn_sched_barrier(0);                          \
  } while (0)

// ------------- fused transpose of the four CxC weights: WT[n][k] = W[k][n] -------------
__global__ __launch_bounds__(256) void transpose4_kernel(const float* __restrict__ Wq,
                                                         const float* __restrict__ Wk,
                                                         const float* __restrict__ Wv,
                                                         const float* __restrict__ Wo,
                                                         u16* __restrict__ WqT,
                                                         u16* __restrict__ WkvT,
                                                         u16* __restrict__ WoT) {
  __shared__ float tile[32][33];
  const int z = blockIdx.z;
  const float* W = (z == 0) ? Wq : (z == 1) ? Wk : (z == 2) ? Wv : Wo;
  u16* WT = (z == 0) ? WqT : (z == 1) ? WkvT : (z == 2) ? (WkvT + (size_t)Cc * Cc) : WoT;
  const int bx = blockIdx.x, by = blockIdx.y;
  const int tx = threadIdx.x, ty = threadIdx.y;
  const int c = bx * 32 + tx;
#pragma unroll
  for (int i = ty; i < 32; i += 8) tile[i][tx] = W[(size_t)(by * 32 + i) * Cc + c];
  __syncthreads();
#pragma unroll
  for (int i = ty; i < 32; i += 8)
    WT[(size_t)(bx * 32 + i) * Cc + by * 32 + tx] = f2b(tile[tx][i]);
}

// ---------------- transpose + fp32->bf16 convert: WT[n][k] = W[k][n] ----------------
__global__ __launch_bounds__(256) void transpose_kernel(const float* __restrict__ W,
                                                        u16* __restrict__ WT, int R, int Cn) {
  __shared__ float tile[32][33];
  const int bx = blockIdx.x, by = blockIdx.y;
  const int tx = threadIdx.x, ty = threadIdx.y;
  const int c = bx * 32 + tx;
#pragma unroll
  for (int i = ty; i < 32; i += 8) tile[i][tx] = W[(size_t)(by * 32 + i) * Cn + c];
  __syncthreads();
#pragma unroll
  for (int i = ty; i < 32; i += 8)
    WT[(size_t)(bx * 32 + i) * R + by * 32 + tx] = f2b(tile[tx][i]);
}

// ---------------- prep: comb + LN(comb)->cx ; LN(all_embed)->ae ----------------
__global__ __launch_bounds__(256) void prep_ln_kernel(
    const float* __restrict__ fwd, const float* __restrict__ bwd, const float* __restrict__ g,
    const float* __restrict__ be, float* __restrict__ comb, u16* __restrict__ cx,
    u16* __restrict__ ae) {
  __shared__ float red[2][4];
  const int row = blockIdx.x, tid = threadIdx.x;
  const int c = tid * 4;
  float4 x;
  u16* dst;
  if (row < BSc) {
    const int b = row >> 10, s = row & (Sc - 1);
    const float4 f = *(const float4*)(fwd + ((size_t)(b * (Sc + 1) + s)) * Cc + c);
    const float4 r = *(const float4*)(bwd + ((size_t)(b * (Sc + 1) + s + 1)) * Cc + c);
    const float k = 0.70710678118654752f;
    x.x = (f.x + r.x) * k; x.y = (f.y + r.y) * k;
    x.z = (f.z + r.z) * k; x.w = (f.w + r.w) * k;
    *(float4*)(comb + (size_t)row * Cc + c) = x;
    dst = cx + (size_t)row * Cc;
  } else {
    const int idx = row - BSc;
    const int b = idx >> 11, t = idx & (S2c - 1);
    const float* src = (t < Sc) ? (fwd + ((size_t)(b * (Sc + 1) + t)) * Cc)
                                : (bwd + ((size_t)(b * (Sc + 1) + (t - Sc) + 1)) * Cc);
    x = *(const float4*)(src + c);
    dst = ae + (size_t)idx * Cc;
  }
  float s1 = x.x + x.y + x.z + x.w;
  float s2 = x.x * x.x + x.y * x.y + x.z * x.z + x.w * x.w;
  for (int off = 32; off; off >>= 1) { s1 += __shfl_down(s1, off); s2 += __shfl_down(s2, off); }
  if ((tid & 63) == 0) { red[0][tid >> 6] = s1; red[1][tid >> 6] = s2; }
  __syncthreads();
  s1 = red[0][0] + red[0][1] + red[0][2] + red[0][3];
  s2 = red[1][0] + red[1][1] + red[1][2] + red[1][3];
  const float mean = s1 * (1.0f / Cc);
  const float rstd = rsqrtf(s2 * (1.0f / Cc) - mean * mean + 1e-5f);
  const float4 gv = *(const float4*)(g + c);
  const float4 bv = *(const float4*)(be + c);
  ushort4 o;
  o.x = f2b((x.x - mean) * rstd * gv.x + bv.x);
  o.y = f2b((x.y - mean) * rstd * gv.y + bv.y);
  o.z = f2b((x.z - mean) * rstd * gv.z + bv.z);
  o.w = f2b((x.w - mean) * rstd * gv.w + bv.w);
  *(ushort4*)(dst + c) = o;
}

// ---------------- double LN: h = LN(LN(x,g2,b2),gm,bm) ----------------
__global__ __launch_bounds__(256) void ln2_kernel(const float* __restrict__ x,
                                                  const float* __restrict__ g2,
                                                  const float* __restrict__ b2,
                                                  const float* __restrict__ gm,
                                                  const float* __restrict__ bm,
                                                  u16* __restrict__ h) {
  __shared__ float red[2][4];
  const int row = blockIdx.x, tid = threadIdx.x;
  const int c = tid * 4;
  const float4 v = *(const float4*)(x + (size_t)row * Cc + c);
  float s1 = v.x + v.y + v.z + v.w;
  float s2 = v.x * v.x + v.y * v.y + v.z * v.z + v.w * v.w;
  for (int off = 32; off; off >>= 1) { s1 += __shfl_down(s1, off); s2 += __shfl_down(s2, off); }
  if ((tid & 63) == 0) { red[0][tid >> 6] = s1; red[1][tid >> 6] = s2; }
  __syncthreads();
  s1 = red[0][0] + red[0][1] + red[0][2] + red[0][3];
  s2 = red[1][0] + red[1][1] + red[1][2] + red[1][3];
  float mean = s1 * (1.0f / Cc);
  float rstd = rsqrtf(s2 * (1.0f / Cc) - mean * mean + 1e-5f);
  const float4 ga = *(const float4*)(g2 + c);
  const float4 ba = *(const float4*)(b2 + c);
  const float t0 = (v.x - mean) * rstd * ga.x + ba.x;
  const float t1 = (v.y - mean) * rstd * ga.y + ba.y;
  const float t2 = (v.z - mean) * rstd * ga.z + ba.z;
  const float t3 = (v.w - mean) * rstd * ga.w + ba.w;
  s1 = t0 + t1 + t2 + t3;
  s2 = t0 * t0 + t1 * t1 + t2 * t2 + t3 * t3;
  for (int off = 32; off; off >>= 1) { s1 += __shfl_down(s1, off); s2 += __shfl_down(s2, off); }
  __syncthreads();
  if ((tid & 63) == 0) { red[0][tid >> 6] = s1; red[1][tid >> 6] = s2; }
  __syncthreads();
  s1 = red[0][0] + red[0][1] + red[0][2] + red[0][3];
  s2 = red[1][0] + red[1][1] + red[1][2] + red[1][3];
  mean = s1 * (1.0f / Cc);
  rstd = rsqrtf(s2 * (1.0f / Cc) - mean * mean + 1e-5f);
  const float4 gb = *(const float4*)(gm + c);
  const float4 bb = *(const float4*)(bm + c);
  ushort4 o;
  o.x = f2b((t0 - mean) * rstd * gb.x + bb.x);
  o.y = f2b((t1 - mean) * rstd * gb.y + bb.y);
  o.z = f2b((t2 - mean) * rstd * gb.z + bb.z);
  o.w = f2b((t3 - mean) * rstd * gb.w + bb.w);
  *(ushort4*)(h + (size_t)row * Cc + c) = o;
}

// ---------------- GEMM: Y = A(MxK) @ BT(NxK)^T, fused epilogues ----------------
// 128x128 tile, 4 waves (64x64 each), BK=32, glds16 staging.
// R12: T4 counted-vmcnt 4-deep pipeline. R2 post-mortem: the 2-buffer variant's
// single-object Asm[2] LDS forced the backend to insert vmcnt(0) before the
// first ds_read (can't disambiguate in-flight DMA writes to buf1 from reads of
// buf0) -> full drain with zero overlap, +65% cycles of pure stall (busy-cycles
// were conserved: MFMA 6.2 vs 6.3 us, VALU 16.0 vs 15.6 us). Fix:
//  - 4 physically DISTINCT LDS buffers per operand (alias-analysis clean);
//  - raw s_barrier + explicit counted s_waitcnt vmcnt(8) (= 4 loads/tile x 2
//    tiles in flight, T4 formula), ONE barrier per K-step, never vmcnt(0) in
//    steady state; tiles t+1,t+2 stay in flight across two compute phases.
//  - skew safety: pre-compute barrier bounds wave skew to 1 phase; writer
//    buffer (t+3)%4 is disjoint from all readable buffers {t,t+1,t+2}%4.
// LDS 64 KB -> 2 blocks/CU; every launch is 512 blocks (grid-limited 2/CU).
// NT = Ks/32 is divisible by 4 for every shape used here (8 or 32).
template <int EPI, int SK>
__global__ __launch_bounds__(256) void gemm_kernel(
    const u16* __restrict__ A, const u16* __restrict__ BT, const float* __restrict__ bias,
    const float* __restrict__ bias2, const float* __restrict__ pos,
    u16* __restrict__ outb, u16* __restrict__ out2, float* __restrict__ pbuf,
    int M, int N, int K) {
  __shared__ u16 A0s[128 * 32], A1s[128 * 32], A2s[128 * 32], A3s[128 * 32];
  __shared__ u16 B0s[128 * 32], B1s[128 * 32], B2s[128 * 32], B3s[128 * 32];
  const int tid = threadIdx.x;
  const int w = tid >> 6, lane = tid & 63, quad = lane >> 4, r16 = lane & 15;
  const int bm = blockIdx.y * 128, bn = blockIdx.x * 128;
  const int wm = (w & 1) * 64, wn = (w >> 1) * 64;
  const int Ks = K / SK, kb0 = blockIdx.z * Ks;

  const int srow = lane >> 2, scol = (lane & 3) * 8;
  const u16* aP = A + (size_t)(bm + w * 32 + srow) * K + kb0 + scol;
  const u16* bP = BT + (size_t)(bn + w * 32 + srow) * K + kb0 + scol;
  const size_t rstep = (size_t)16 * K;
  const int l0 = (w * 32) * 32;        // wave-uniform LDS stage base (u16 offset)
  const int l1 = (w * 32 + 16) * 32;

  f32x4 acc[4][4] = {};

  auto STAGE = [&](u16* Ad, u16* Bd, int t) {
    const int ko = t * 32;
    glds16(aP + ko, Ad + l0);
    glds16(aP + ko + rstep, Ad + l1);
    glds16(bP + ko, Bd + l0);
    glds16(bP + ko + rstep, Bd + l1);
  };
  auto COMPUTE = [&](const u16* As, const u16* Bs) {
    bf16x8 af[4], bfr[4];
#pragma unroll
    for (int i = 0; i < 4; i++) {
      af[i] = *reinterpret_cast<const bf16x8*>(&As[(wm + i * 16 + r16) * 32 + quad * 8]);
      bfr[i] = *reinterpret_cast<const bf16x8*>(&Bs[(wn + i * 16 + r16) * 32 + quad * 8]);
    }
#pragma unroll
    for (int mi = 0; mi < 4; mi++)
#pragma unroll
      for (int ni = 0; ni < 4; ni++) acc[mi][ni] = mfma16(af[mi], bfr[ni], acc[mi][ni]);
  };

  const int NT = Ks / 32;  // 8 or 32; divisible by 4
  STAGE(A0s, B0s, 0);
  STAGE(A1s, B1s, 1);
  for (int t = 0; t < NT; t += 4) {
    // phase p = t+0 : compute buf0, prefetch tile t+2 -> buf2
    if (t + 2 < NT) { STAGE(A2s, B2s, t + 2); PIPE_WAIT(8); }
    else if (t + 1 < NT) PIPE_WAIT(4);
    else PIPE_WAIT(0);
    PIPE_BAR();
    COMPUTE(A0s, B0s);
    // phase p = t+1 : compute buf1, prefetch tile t+3 -> buf3
    if (t + 3 < NT) { STAGE(A3s, B3s, t + 3); PIPE_WAIT(8); }
    else if (t + 2 < NT) PIPE_WAIT(4);
    else PIPE_WAIT(0);
    PIPE_BAR();
    COMPUTE(A1s, B1s);
    // phase p = t+2 : compute buf2, prefetch tile t+4 -> buf0
    if (t + 4 < NT) { STAGE(A0s, B0s, t + 4); PIPE_WAIT(8); }
    else if (t + 3 < NT) PIPE_WAIT(4);
    else PIPE_WAIT(0);
    PIPE_BAR();
    COMPUTE(A2s, B2s);
    // phase p = t+3 : compute buf3, prefetch tile t+5 -> buf1
    if (t + 5 < NT) { STAGE(A1s, B1s, t + 5); PIPE_WAIT(8); }
    else if (t + 4 < NT) PIPE_WAIT(4);
    else PIPE_WAIT(0);
    PIPE_BAR();
    COMPUTE(A3s, B3s);
  }

#pragma unroll
  for (int mi = 0; mi < 4; mi++) {
#pragma unroll
    for (int ni = 0; ni < 4; ni++) {
      const int col = bn + wn + ni * 16 + r16;
      const int row0 = bm + wm + mi * 16 + quad * 4;
      if constexpr (EPI == EPI_PART) {
        float* pb = pbuf + (size_t)blockIdx.z * M * N;
#pragma unroll
        for (int r = 0; r < 4; r++) pb[(size_t)(row0 + r) * N + col] = acc[mi][ni][r];
      } else if constexpr (EPI == EPI_KV) {
        if (col < Cc) {
#pragma unroll
          for (int r = 0; r < 4; r++) {
            const int row = row0 + r;
            const int key = row & (S2c - 1);
            const float y =
                acc[mi][ni][r] + bias[col] + pos[(key & (Sc - 1)) * HDc + (col & 63)];
            outb[(size_t)row * Cc + col] = f2b(y);
          }
        } else {
          const int c2 = col - Cc;
          const int h = c2 >> 6, d = c2 & 63;
          const int b = row0 >> 11, key0 = row0 & (S2c - 1);
          const float bb = bias2[c2];
          ushort4 pk;
          pk.x = f2b(acc[mi][ni][0] + bb);
          pk.y = f2b(acc[mi][ni][1] + bb);
          pk.z = f2b(acc[mi][ni][2] + bb);
          pk.w = f2b(acc[mi][ni][3] + bb);
          *(ushort4*)&out2[(((size_t)(b * Hc + h) * HDc + d) << 11) + key0] = pk;
        }
      } else {  // EPI_GELU
#pragma unroll
        for (int r = 0; r < 4; r++) {
          const float y = acc[mi][ni][r] + bias[col];
          outb[(size_t)(row0 + r) * N + col] =
              f2b(0.5f * y * (1.0f + erff(y * 0.70710678118654752f)));
        }
      }
    }
  }
}

// ---------------- split-K reduce + epilogue (SK slices of MxN f32) ----------------
// EPI_Q: out = bf16((sum + bias + pos) * scale) ; EPI_O/EPI_FINAL: out = f32(sum + bias + add)
template <int EPI, int SK>
__global__ __launch_bounds__(256) void reduce_kernel(const float* __restrict__ pbuf,
                                                     const float* __restrict__ bias,
                                                     const float* __restrict__ pos,
                                                     const float* __restrict__ addsrc,
                                                     u16* __restrict__ outb,
                                                     float* __restrict__ outf, int M, int N) {
  const size_t flat = ((size_t)blockIdx.x * 256 + threadIdx.x) * 4;
  const int row = (int)(flat / N), col = (int)(flat % N);
  const size_t MN = (size_t)M * N;
  float4 s = *(const float4*)(pbuf + flat);
#pragma unroll
  for (int z = 1; z < SK; z++) {
    const float4 v = *(const float4*)(pbuf + z * MN + flat);
    s.x += v.x; s.y += v.y; s.z += v.z; s.w += v.w;
  }
  const float4 bv = *(const float4*)(bias + col);
  s.x += bv.x; s.y += bv.y; s.z += bv.z; s.w += bv.w;
  if constexpr (EPI == EPI_Q) {
    const int sq = row & (Sc - 1), d = col & 63;
    const float4 pv = *(const float4*)(pos + sq * HDc + d);
    constexpr float sc = 0.180336880111120426f;  // (1/8)*log2(e)
    ushort4 o;
    o.x = f2b((s.x + pv.x) * sc);
    o.y = f2b((s.y + pv.y) * sc);
    o.z = f2b((s.z + pv.z) * sc);
    o.w = f2b((s.w + pv.w) * sc);
    *(ushort4*)(outb + flat) = o;
  } else {
    const float4 av = *(const float4*)(addsrc + flat);
    float4 o;
    o.x = s.x + av.x; o.y = s.y + av.y; o.z = s.z + av.z; o.w = s.w + av.w;
    *(float4*)(outf + flat) = o;
  }
}

// ---------------- attention partials: grid (bh, qt, half) ----------------
// K/V tiles staged ONCE per block via cooperative glds16 into LDS (shared by all 4
// waves — R8/R9 loaded them 4x redundantly through VGPRs and the allocator
// serialized the loads). 2-barrier unit loop, GEMM-style. Sub-tiles use 64-B rows
// so fragment ds_read_b128 banks = (r16&1)*16+quad*4 -> 2-way (free).
// qb: [b,q,h,d] bf16 (pre-scaled by (1/8)*log2e); kb: [b,key(2S),h,d]; vT: [b,h,d,key(2S)]
__global__ __launch_bounds__(256) void attn_part_kernel(const u16* __restrict__ qb,
                                                        const u16* __restrict__ kb,
                                                        const u16* __restrict__ vT,
                                                        float* __restrict__ o_part,
                                                        float* __restrict__ l_part) {
  const int bh = blockIdx.x;
  const int qt = blockIdx.y;
  const int half = blockIdx.z;
  const int b = bh >> 4, head = bh & 15;
  const int tid = threadIdx.x;
  const int w = tid >> 6, lane = tid & 63, quad = lane >> 4, r16 = lane & 15;

  __shared__ u16 Kt[2][64 * 32];  // [ks][key][32 d]   rows 64 B
  __shared__ u16 Vt[2][64 * 32];  // [ks][d][32 keys]  rows 64 B
  __shared__ u16 Ps[4][16 * 68];  // per-wave P round-trip (stride 68: conflict-free)
  u16* ps = Ps[w];

  const int q0 = qt * 64;
  const int qw = q0 + w * 16;  // this wave's 16 queries

  bf16x8 aq[2];
  {
    const u16* qp = qb + ((size_t)((b * Sc + qw + r16) * Hc + head)) * HDc + quad * 8;
    aq[0] = *(const bf16x8*)qp;
    aq[1] = *(const bf16x8*)(qp + 32);
  }

  const size_t krow = (size_t)Hc * HDc;
  const u16* kbase = kb + ((size_t)b * S2c * Hc + head) * HDc;
  const u16* vbase = vT + ((size_t)(b * Hc + head)) * HDc * S2c;

  // cooperative staging map: wave w covers rows w*16 + lane/4, 16 B at (lane&3)*8
  const int srow = w * 16 + (lane >> 2);
  const int scol = (lane & 3) * 8;
  u16* kD0 = &Kt[0][w * 16 * 32];
  u16* kD1 = &Kt[1][w * 16 * 32];
  u16* vD0 = &Vt[0][w * 16 * 32];
  u16* vD1 = &Vt[1][w * 16 * 32];
  const u16* kS = kbase + (size_t)srow * krow + scol;   // + key0*krow (+32 for ks=1)
  const u16* vS = vbase + (size_t)srow * S2c + scol;    // + key0     (+32 for ks=1)

  f32x4 o_acc[4] = {};
  float lsum[4] = {};

  const int n = (half == 0) ? (qt + 1) : (16 - qt);
  const int kb0 = (half == 0) ? 0 : Sc + qt * 64;  // unit j covers keys kb0 + j*64 ..

  for (int j = 0; j < n; j++) {
    const int k0 = kb0 + j * 64;
    glds16(kS + (size_t)k0 * krow, kD0);
    glds16(kS + (size_t)k0 * krow + 32, kD1);
    glds16(vS + k0, vD0);
    glds16(vS + k0 + 32, vD1);
    __syncthreads();

    // QK^T from LDS
    f32x4 sacc[4] = {};
#pragma unroll
    for (int ks = 0; ks < 2; ks++)
#pragma unroll
      for (int ni = 0; ni < 4; ni++) {
        const bf16x8 bk = *(const bf16x8*)&Kt[ks][(ni * 16 + r16) * 32 + quad * 8];
        sacc[ni] = mfma16(aq[ks], bk, sacc[ni]);
      }

    const int mode = (half == 0) ? ((j == n - 1) ? 1 : 0) : ((j == 0) ? 2 : 0);
#pragma unroll
    for (int r = 0; r < 4; r++) {
      const int qrow = qw + quad * 4 + r;
#pragma unroll
      for (int ni = 0; ni < 4; ni++) {
        float s = sacc[ni][r];
        if (mode == 1) { const int key = k0 + ni * 16 + r16; if (key > qrow) s = -128.0f; }
        else if (mode == 2) { const int key = k0 - Sc + ni * 16 + r16; if (key < qrow) s = -128.0f; }
        const float pe = __builtin_amdgcn_exp2f(s);
        lsum[r] += pe;
        ps[(quad * 4 + r) * 68 + ni * 16 + r16] = f2b_fast(pe);
      }
    }

    // PV from LDS
#pragma unroll
    for (int ks = 0; ks < 2; ks++) {
      const bf16x8 ap = *(const bf16x8*)(&ps[r16 * 68 + ks * 32 + quad * 8]);
#pragma unroll
      for (int ni = 0; ni < 4; ni++) {
        const bf16x8 bv_ = *(const bf16x8*)&Vt[ks][(ni * 16 + r16) * 32 + quad * 8];
        o_acc[ni] = mfma16(ap, bv_, o_acc[ni]);
      }
    }
    __syncthreads();
  }

#pragma unroll
  for (int r = 0; r < 4; r++) {
    float l = lsum[r];
    l += __shfl_xor(l, 1);
    l += __shfl_xor(l, 2);
    l += __shfl_xor(l, 4);
    l += __shfl_xor(l, 8);
    lsum[r] = l;
  }

  const size_t rowbase = (((size_t)half * Bc + b) * Hc + head) * Sc + qw;
  float* ob = o_part + rowbase * HDc;
#pragma unroll
  for (int r = 0; r < 4; r++) {
    const int rl = quad * 4 + r;
#pragma unroll
    for (int ni = 0; ni < 4; ni++) ob[(size_t)rl * HDc + ni * 16 + r16] = o_acc[ni][r];
    if (r16 == 0) l_part[rowbase + rl] = lsum[r];
  }
}

// ---------------- combine halves + normalize -> bf16 [b,q,h,d] ----------------
__global__ __launch_bounds__(256) void attn_norm_kernel(const float* __restrict__ o_part,
                                                        const float* __restrict__ l_part,
                                                        u16* __restrict__ ob) {
  constexpr size_t HS = (size_t)Bc * Hc * Sc * HDc;
  constexpr size_t HL = (size_t)Bc * Hc * Sc;
  const int flat = blockIdx.x * 256 + threadIdx.x;
  const int row = flat >> 4, d0 = (flat & 15) * 4;
  const int q = row & (Sc - 1), h = (row >> 10) & 15, b = row >> 14;
  const float4 o0 = *(const float4*)(o_part + (size_t)row * HDc + d0);
  const float4 o1 = *(const float4*)(o_part + HS + (size_t)row * HDc + d0);
  const float rl = 1.0f / (l_part[row] + l_part[HL + row]);
  ushort4 o;
  o.x = f2b((o0.x + o1.x) * rl);
  o.y = f2b((o0.y + o1.y) * rl);
  o.z = f2b((o0.z + o1.z) * rl);
  o.w = f2b((o0.w + o1.w) * rl);
  *(ushort4*)(ob + ((size_t)((b * Sc + q) * Hc + h)) * HDc + d0) = o;
}

extern "C" void kernel_launch(void* const* d_in, const int* in_sizes, int n_in, void* d_out,
                              int out_size, void* d_ws, size_t ws_size, hipStream_t stream) {
  const float* fwd = (const float*)d_in[0];
  const float* bwd = (const float*)d_in[1];
  const float* pos = (const float*)d_in[2];
  const float* ln1g = (const float*)d_in[3];
  const float* ln1b = (const float*)d_in[4];
  const float* Wq = (const float*)d_in[5];
  const float* bq = (const float*)d_in[6];
  const float* Wk = (const float*)d_in[7];
  const float* bk = (const float*)d_in[8];
  const float* Wv = (const float*)d_in[9];
  const float* bv = (const float*)d_in[10];
  const float* Wo = (const float*)d_in[11];
  const float* bo = (const float*)d_in[12];
  const float* ln2g = (const float*)d_in[13];
  const float* ln2b = (const float*)d_in[14];
  const float* mlpg = (const float*)d_in[15];
  const float* mlpb = (const float*)d_in[16];
  const float* W1 = (const float*)d_in[17];
  const float* b1 = (const float*)d_in[18];
  const float* W2 = (const float*)d_in[19];
  const float* b2 = (const float*)d_in[20];

  char* p = (char*)d_ws;
  auto alloc = [&](size_t bytes) -> char* {
    char* r = p;
    p += (bytes + 255) & ~(size_t)255;
    return r;
  };
  float* comb = (float*)alloc((size_t)BSc * Cc * 4);
  float* xbuf = (float*)alloc((size_t)BSc * Cc * 4);
  u16* cx = (u16*)alloc((size_t)BSc * Cc * 2);
  u16* ae = (u16*)alloc((size_t)BS2c * Cc * 2);
  u16* qbuf = (u16*)alloc((size_t)BSc * Cc * 2);
  u16* kbuf = (u16*)alloc((size_t)BS2c * Cc * 2);
  u16* vTb = (u16*)alloc((size_t)BS2c * Cc * 2);
  u16* obuf = (u16*)alloc((size_t)BSc * Cc * 2);
  u16* hb = (u16*)alloc((size_t)BSc * Cc * 2);
  char* big = alloc((size_t)2 * BSc * Hc * HDc * 4 > (size_t)BSc * ECc * 2
                        ? (size_t)2 * BSc * Hc * HDc * 4
                        : (size_t)BSc * ECc * 2);
  float* o_part = (float*)big;
  u16* midb = (u16*)big;
  float* l_part = (float*)alloc((size_t)2 * Bc * Hc * Sc * 4);
  float* pbuf = (float*)alloc((size_t)4 * BSc * Cc * 4);  // 4 split-K slices of 2048x1024 f32
  u16* WqT = (u16*)alloc((size_t)Cc * Cc * 2);
  u16* WkvT = (u16*)alloc((size_t)2 * Cc * Cc * 2);
  u16* WoT = (u16*)alloc((size_t)Cc * Cc * 2);
  u16* W1T = (u16*)alloc((size_t)ECc * Cc * 2);
  u16* W2T = (u16*)alloc((size_t)Cc * ECc * 2);

  const dim3 tb(32, 8);
  transpose4_kernel<<<dim3(32, 32, 4), tb, 0, stream>>>(Wq, Wk, Wv, Wo, WqT, WkvT, WoT);
  transpose_kernel<<<dim3(128, 32), tb, 0, stream>>>(W1, W1T, Cc, ECc);
  transpose_kernel<<<dim3(32, 128), tb, 0, stream>>>(W2, W2T, ECc, Cc);

  prep_ln_kernel<<<BSc + BS2c, 256, 0, stream>>>(fwd, bwd, ln1g, ln1b, comb, cx, ae);

  // Q = cx @ WqT^T  (split-K=4 -> 512 blocks)
  gemm_kernel<EPI_PART, 4><<<dim3(Cc / 128, BSc / 128, 4), 256, 0, stream>>>(
      cx, WqT, nullptr, nullptr, nullptr, nullptr, nullptr, pbuf, BSc, Cc, Cc);
  reduce_kernel<EPI_Q, 4><<<(BSc * Cc / 4) / 256, 256, 0, stream>>>(
      pbuf, bq, pos, nullptr, qbuf, nullptr, BSc, Cc);

  // K,V fused (N=2048, 512 blocks)
  gemm_kernel<EPI_KV, 1><<<dim3(2 * Cc / 128, BS2c / 128, 1), 256, 0, stream>>>(
      ae, WkvT, bk, bv, pos, kbuf, vTb, nullptr, BS2c, 2 * Cc, Cc);

  attn_part_kernel<<<dim3(Bc * Hc, Sc / 64, 2), 256, 0, stream>>>(qbuf, kbuf, vTb, o_part,
                                                                  l_part);
  attn_norm_kernel<<<(BSc * Hc * HDc / 4) / 256, 256, 0, stream>>>(o_part, l_part, obuf);

  // x = comb + (o @ WoT^T + bo)  (split-K=4)
  gemm_kernel<EPI_PART, 4><<<dim3(Cc / 128, BSc / 128, 4), 256, 0, stream>>>(
      obuf, WoT, nullptr, nullptr, nullptr, nullptr, nullptr, pbuf, BSc, Cc, Cc);
  reduce_kernel<EPI_O, 4><<<(BSc * Cc / 4) / 256, 256, 0, stream>>>(
      pbuf, bo, nullptr, comb, nullptr, xbuf, BSc, Cc);

  ln2_kernel<<<BSc, 256, 0, stream>>>(xbuf, ln2g, ln2b, mlpg, mlpb, hb);

  // mid = gelu(h @ W1T^T + b1)  (512 blocks)
  gemm_kernel<EPI_GELU, 1><<<dim3(ECc / 128, BSc / 128, 1), 256, 0, stream>>>(
      hb, W1T, b1, nullptr, nullptr, midb, nullptr, nullptr, BSc, ECc, Cc);

  // out = x + (mid @ W2T^T + b2)  (split-K=4 over K=4096 -> 512 blocks)
  gemm_kernel<EPI_PART, 4><<<dim3(Cc / 128, BSc / 128, 4), 256, 0, stream>>>(
      midb, W2T, nullptr, nullptr, nullptr, nullptr, nullptr, pbuf, BSc, Cc, ECc);
  reduce_kernel<EPI_FINAL, 4><<<(BSc * Cc / 4) / 256, 256, 0, stream>>>(
      pbuf, b2, nullptr, xbuf, nullptr, (float*)d_out, BSc, Cc);
}

// Round 4
// 331.913 us; speedup vs baseline: 1.0928x; 1.0225x over previous
//
#include <hip/hip_runtime.h>
#include <hip/hip_bf16.h>
#include <cstdint>

#define DI __device__ __forceinline__

typedef unsigned short u16;
typedef __bf16 bf16x8 __attribute__((ext_vector_type(8)));
typedef float f32x4 __attribute__((ext_vector_type(4)));

constexpr int Bc  = 2;
constexpr int Sc  = 1024;
constexpr int Cc  = 1024;
constexpr int Hc  = 16;
constexpr int HDc = 64;
constexpr int S2c = 2048;
constexpr int ECc = 4096;
constexpr int BSc  = Bc * Sc;   // 2048
constexpr int BS2c = Bc * S2c;  // 4096

constexpr int EPI_KV = 0, EPI_Q = 1, EPI_O = 3, EPI_GELU = 4, EPI_FINAL = 5, EPI_PART = 6;

DI u16 f2b(float f) {
  __hip_bfloat16 h = __float2bfloat16(f);
  u16 u;
  __builtin_memcpy(&u, &h, 2);
  return u;
}

// fast bf16 pack (round-half-up); fine for p in [0,1]
DI u16 f2b_fast(float f) {
  uint32_t u;
  __builtin_memcpy(&u, &f, 4);
  return (u16)((u + 0x8000u) >> 16);
}

// CK-style direct global->LDS (16B per lane; LDS dest = wave-uniform base + lane*16)
DI void glds16(const void* g, void* l) {
  auto* lp = reinterpret_cast<__attribute__((address_space(3))) uint32_t*>(
      reinterpret_cast<uintptr_t>(l));
  __builtin_amdgcn_global_load_lds(
      reinterpret_cast<const __attribute__((address_space(1))) uint32_t*>(
          reinterpret_cast<uintptr_t>(g)),
      lp, 16, 0, 0);
}

DI f32x4 mfma16(bf16x8 a, bf16x8 b, f32x4 c) {
  return __builtin_amdgcn_mfma_f32_16x16x32_bf16(a, b, c, 0, 0, 0);
}

// counted vmcnt wait + scheduling fence (rule #18: pin code motion around inline-asm waits)
#define PIPE_WAIT(N)                                            \
  do {                                                          \
    asm volatile("s_waitcnt vmcnt(" #N ")" ::: "memory");       \
    __builtin_amdgcn_sched_barrier(0);                          \
  } while (0)
#define PIPE_BAR()                                              \
  do {                                                          \
    __builtin_amdgcn_s_barrier();                               \
    __builtin_amdgcn_sched_barrier(0);                          \
  } while (0)

// ------------- fused transpose of the four CxC weights: WT[n][k] = W[k][n] -------------
__global__ __launch_bounds__(256) void transpose4_kernel(const float* __restrict__ Wq,
                                                         const float* __restrict__ Wk,
                                                         const float* __restrict__ Wv,
                                                         const float* __restrict__ Wo,
                                                         u16* __restrict__ WqT,
                                                         u16* __restrict__ WkvT,
                                                         u16* __restrict__ WoT) {
  __shared__ float tile[32][33];
  const int z = blockIdx.z;
  const float* W = (z == 0) ? Wq : (z == 1) ? Wk : (z == 2) ? Wv : Wo;
  u16* WT = (z == 0) ? WqT : (z == 1) ? WkvT : (z == 2) ? (WkvT + (size_t)Cc * Cc) : WoT;
  const int bx = blockIdx.x, by = blockIdx.y;
  const int tx = threadIdx.x, ty = threadIdx.y;
  const int c = bx * 32 + tx;
#pragma unroll
  for (int i = ty; i < 32; i += 8) tile[i][tx] = W[(size_t)(by * 32 + i) * Cc + c];
  __syncthreads();
#pragma unroll
  for (int i = ty; i < 32; i += 8)
    WT[(size_t)(bx * 32 + i) * Cc + by * 32 + tx] = f2b(tile[tx][i]);
}

// ---------------- transpose + fp32->bf16 convert: WT[n][k] = W[k][n] ----------------
__global__ __launch_bounds__(256) void transpose_kernel(const float* __restrict__ W,
                                                        u16* __restrict__ WT, int R, int Cn) {
  __shared__ float tile[32][33];
  const int bx = blockIdx.x, by = blockIdx.y;
  const int tx = threadIdx.x, ty = threadIdx.y;
  const int c = bx * 32 + tx;
#pragma unroll
  for (int i = ty; i < 32; i += 8) tile[i][tx] = W[(size_t)(by * 32 + i) * Cn + c];
  __syncthreads();
#pragma unroll
  for (int i = ty; i < 32; i += 8)
    WT[(size_t)(bx * 32 + i) * R + by * 32 + tx] = f2b(tile[tx][i]);
}

// ---------------- prep: comb + LN(comb)->cx ; LN(all_embed)->ae ----------------
__global__ __launch_bounds__(256) void prep_ln_kernel(
    const float* __restrict__ fwd, const float* __restrict__ bwd, const float* __restrict__ g,
    const float* __restrict__ be, float* __restrict__ comb, u16* __restrict__ cx,
    u16* __restrict__ ae) {
  __shared__ float red[2][4];
  const int row = blockIdx.x, tid = threadIdx.x;
  const int c = tid * 4;
  float4 x;
  u16* dst;
  if (row < BSc) {
    const int b = row >> 10, s = row & (Sc - 1);
    const float4 f = *(const float4*)(fwd + ((size_t)(b * (Sc + 1) + s)) * Cc + c);
    const float4 r = *(const float4*)(bwd + ((size_t)(b * (Sc + 1) + s + 1)) * Cc + c);
    const float k = 0.70710678118654752f;
    x.x = (f.x + r.x) * k; x.y = (f.y + r.y) * k;
    x.z = (f.z + r.z) * k; x.w = (f.w + r.w) * k;
    *(float4*)(comb + (size_t)row * Cc + c) = x;
    dst = cx + (size_t)row * Cc;
  } else {
    const int idx = row - BSc;
    const int b = idx >> 11, t = idx & (S2c - 1);
    const float* src = (t < Sc) ? (fwd + ((size_t)(b * (Sc + 1) + t)) * Cc)
                                : (bwd + ((size_t)(b * (Sc + 1) + (t - Sc) + 1)) * Cc);
    x = *(const float4*)(src + c);
    dst = ae + (size_t)idx * Cc;
  }
  float s1 = x.x + x.y + x.z + x.w;
  float s2 = x.x * x.x + x.y * x.y + x.z * x.z + x.w * x.w;
  for (int off = 32; off; off >>= 1) { s1 += __shfl_down(s1, off); s2 += __shfl_down(s2, off); }
  if ((tid & 63) == 0) { red[0][tid >> 6] = s1; red[1][tid >> 6] = s2; }
  __syncthreads();
  s1 = red[0][0] + red[0][1] + red[0][2] + red[0][3];
  s2 = red[1][0] + red[1][1] + red[1][2] + red[1][3];
  const float mean = s1 * (1.0f / Cc);
  const float rstd = rsqrtf(s2 * (1.0f / Cc) - mean * mean + 1e-5f);
  const float4 gv = *(const float4*)(g + c);
  const float4 bv = *(const float4*)(be + c);
  ushort4 o;
  o.x = f2b((x.x - mean) * rstd * gv.x + bv.x);
  o.y = f2b((x.y - mean) * rstd * gv.y + bv.y);
  o.z = f2b((x.z - mean) * rstd * gv.z + bv.z);
  o.w = f2b((x.w - mean) * rstd * gv.w + bv.w);
  *(ushort4*)(dst + c) = o;
}

// ---------------- double LN: h = LN(LN(x,g2,b2),gm,bm) ----------------
__global__ __launch_bounds__(256) void ln2_kernel(const float* __restrict__ x,
                                                  const float* __restrict__ g2,
                                                  const float* __restrict__ b2,
                                                  const float* __restrict__ gm,
                                                  const float* __restrict__ bm,
                                                  u16* __restrict__ h) {
  __shared__ float red[2][4];
  const int row = blockIdx.x, tid = threadIdx.x;
  const int c = tid * 4;
  const float4 v = *(const float4*)(x + (size_t)row * Cc + c);
  float s1 = v.x + v.y + v.z + v.w;
  float s2 = v.x * v.x + v.y * v.y + v.z * v.z + v.w * v.w;
  for (int off = 32; off; off >>= 1) { s1 += __shfl_down(s1, off); s2 += __shfl_down(s2, off); }
  if ((tid & 63) == 0) { red[0][tid >> 6] = s1; red[1][tid >> 6] = s2; }
  __syncthreads();
  s1 = red[0][0] + red[0][1] + red[0][2] + red[0][3];
  s2 = red[1][0] + red[1][1] + red[1][2] + red[1][3];
  float mean = s1 * (1.0f / Cc);
  float rstd = rsqrtf(s2 * (1.0f / Cc) - mean * mean + 1e-5f);
  const float4 ga = *(const float4*)(g2 + c);
  const float4 ba = *(const float4*)(b2 + c);
  const float t0 = (v.x - mean) * rstd * ga.x + ba.x;
  const float t1 = (v.y - mean) * rstd * ga.y + ba.y;
  const float t2 = (v.z - mean) * rstd * ga.z + ba.z;
  const float t3 = (v.w - mean) * rstd * ga.w + ba.w;
  s1 = t0 + t1 + t2 + t3;
  s2 = t0 * t0 + t1 * t1 + t2 * t2 + t3 * t3;
  for (int off = 32; off; off >>= 1) { s1 += __shfl_down(s1, off); s2 += __shfl_down(s2, off); }
  __syncthreads();
  if ((tid & 63) == 0) { red[0][tid >> 6] = s1; red[1][tid >> 6] = s2; }
  __syncthreads();
  s1 = red[0][0] + red[0][1] + red[0][2] + red[0][3];
  s2 = red[1][0] + red[1][1] + red[1][2] + red[1][3];
  mean = s1 * (1.0f / Cc);
  rstd = rsqrtf(s2 * (1.0f / Cc) - mean * mean + 1e-5f);
  const float4 gb = *(const float4*)(gm + c);
  const float4 bb = *(const float4*)(bm + c);
  ushort4 o;
  o.x = f2b((t0 - mean) * rstd * gb.x + bb.x);
  o.y = f2b((t1 - mean) * rstd * gb.y + bb.y);
  o.z = f2b((t2 - mean) * rstd * gb.z + bb.z);
  o.w = f2b((t3 - mean) * rstd * gb.w + bb.w);
  *(ushort4*)(h + (size_t)row * Cc + c) = o;
}

// ---------------- GEMM: Y = A(MxK) @ BT(NxK)^T, fused epilogues ----------------
// 128x128 tile, 4 waves (64x64 each), BK=32, glds16 staging.
// R12 (kept, verified R3): T4 counted-vmcnt 4-deep pipeline. 4 physically
// distinct LDS buffers per operand (alias-analysis clean); raw s_barrier +
// counted s_waitcnt vmcnt(8) (4 loads/tile x 2 tiles in flight); ONE barrier
// per K-step; never vmcnt(0) in steady state. Writer buffer (t+3)%4 disjoint
// from readable {t,t+1,t+2}%4; pre-compute barrier bounds wave skew to 1 phase.
template <int EPI, int SK>
__global__ __launch_bounds__(256) void gemm_kernel(
    const u16* __restrict__ A, const u16* __restrict__ BT, const float* __restrict__ bias,
    const float* __restrict__ bias2, const float* __restrict__ pos,
    u16* __restrict__ outb, u16* __restrict__ out2, float* __restrict__ pbuf,
    int M, int N, int K) {
  __shared__ u16 A0s[128 * 32], A1s[128 * 32], A2s[128 * 32], A3s[128 * 32];
  __shared__ u16 B0s[128 * 32], B1s[128 * 32], B2s[128 * 32], B3s[128 * 32];
  const int tid = threadIdx.x;
  const int w = tid >> 6, lane = tid & 63, quad = lane >> 4, r16 = lane & 15;
  const int bm = blockIdx.y * 128, bn = blockIdx.x * 128;
  const int wm = (w & 1) * 64, wn = (w >> 1) * 64;
  const int Ks = K / SK, kb0 = blockIdx.z * Ks;

  const int srow = lane >> 2, scol = (lane & 3) * 8;
  const u16* aP = A + (size_t)(bm + w * 32 + srow) * K + kb0 + scol;
  const u16* bP = BT + (size_t)(bn + w * 32 + srow) * K + kb0 + scol;
  const size_t rstep = (size_t)16 * K;
  const int l0 = (w * 32) * 32;        // wave-uniform LDS stage base (u16 offset)
  const int l1 = (w * 32 + 16) * 32;

  f32x4 acc[4][4] = {};

  auto STAGE = [&](u16* Ad, u16* Bd, int t) {
    const int ko = t * 32;
    glds16(aP + ko, Ad + l0);
    glds16(aP + ko + rstep, Ad + l1);
    glds16(bP + ko, Bd + l0);
    glds16(bP + ko + rstep, Bd + l1);
  };
  auto COMPUTE = [&](const u16* As, const u16* Bs) {
    bf16x8 af[4], bfr[4];
#pragma unroll
    for (int i = 0; i < 4; i++) {
      af[i] = *reinterpret_cast<const bf16x8*>(&As[(wm + i * 16 + r16) * 32 + quad * 8]);
      bfr[i] = *reinterpret_cast<const bf16x8*>(&Bs[(wn + i * 16 + r16) * 32 + quad * 8]);
    }
#pragma unroll
    for (int mi = 0; mi < 4; mi++)
#pragma unroll
      for (int ni = 0; ni < 4; ni++) acc[mi][ni] = mfma16(af[mi], bfr[ni], acc[mi][ni]);
  };

  const int NT = Ks / 32;  // 8 or 32; divisible by 4
  STAGE(A0s, B0s, 0);
  STAGE(A1s, B1s, 1);
  for (int t = 0; t < NT; t += 4) {
    if (t + 2 < NT) { STAGE(A2s, B2s, t + 2); PIPE_WAIT(8); }
    else if (t + 1 < NT) PIPE_WAIT(4);
    else PIPE_WAIT(0);
    PIPE_BAR();
    COMPUTE(A0s, B0s);
    if (t + 3 < NT) { STAGE(A3s, B3s, t + 3); PIPE_WAIT(8); }
    else if (t + 2 < NT) PIPE_WAIT(4);
    else PIPE_WAIT(0);
    PIPE_BAR();
    COMPUTE(A1s, B1s);
    if (t + 4 < NT) { STAGE(A0s, B0s, t + 4); PIPE_WAIT(8); }
    else if (t + 3 < NT) PIPE_WAIT(4);
    else PIPE_WAIT(0);
    PIPE_BAR();
    COMPUTE(A2s, B2s);
    if (t + 5 < NT) { STAGE(A1s, B1s, t + 5); PIPE_WAIT(8); }
    else if (t + 4 < NT) PIPE_WAIT(4);
    else PIPE_WAIT(0);
    PIPE_BAR();
    COMPUTE(A3s, B3s);
  }

#pragma unroll
  for (int mi = 0; mi < 4; mi++) {
#pragma unroll
    for (int ni = 0; ni < 4; ni++) {
      const int col = bn + wn + ni * 16 + r16;
      const int row0 = bm + wm + mi * 16 + quad * 4;
      if constexpr (EPI == EPI_PART) {
        float* pb = pbuf + (size_t)blockIdx.z * M * N;
#pragma unroll
        for (int r = 0; r < 4; r++) pb[(size_t)(row0 + r) * N + col] = acc[mi][ni][r];
      } else if constexpr (EPI == EPI_KV) {
        if (col < Cc) {
#pragma unroll
          for (int r = 0; r < 4; r++) {
            const int row = row0 + r;
            const int key = row & (S2c - 1);
            const float y =
                acc[mi][ni][r] + bias[col] + pos[(key & (Sc - 1)) * HDc + (col & 63)];
            outb[(size_t)row * Cc + col] = f2b(y);
          }
        } else {
          const int c2 = col - Cc;
          const int h = c2 >> 6, d = c2 & 63;
          const int b = row0 >> 11, key0 = row0 & (S2c - 1);
          const float bb = bias2[c2];
          ushort4 pk;
          pk.x = f2b(acc[mi][ni][0] + bb);
          pk.y = f2b(acc[mi][ni][1] + bb);
          pk.z = f2b(acc[mi][ni][2] + bb);
          pk.w = f2b(acc[mi][ni][3] + bb);
          *(ushort4*)&out2[(((size_t)(b * Hc + h) * HDc + d) << 11) + key0] = pk;
        }
      } else {  // EPI_GELU
#pragma unroll
        for (int r = 0; r < 4; r++) {
          const float y = acc[mi][ni][r] + bias[col];
          outb[(size_t)(row0 + r) * N + col] =
              f2b(0.5f * y * (1.0f + erff(y * 0.70710678118654752f)));
        }
      }
    }
  }
}

// ---------------- split-K reduce + epilogue (SK slices of MxN f32) ----------------
// EPI_Q: out = bf16((sum + bias + pos) * scale) ; EPI_O/EPI_FINAL: out = f32(sum + bias + add)
template <int EPI, int SK>
__global__ __launch_bounds__(256) void reduce_kernel(const float* __restrict__ pbuf,
                                                     const float* __restrict__ bias,
                                                     const float* __restrict__ pos,
                                                     const float* __restrict__ addsrc,
                                                     u16* __restrict__ outb,
                                                     float* __restrict__ outf, int M, int N) {
  const size_t flat = ((size_t)blockIdx.x * 256 + threadIdx.x) * 4;
  const int row = (int)(flat / N), col = (int)(flat % N);
  const size_t MN = (size_t)M * N;
  float4 s = *(const float4*)(pbuf + flat);
#pragma unroll
  for (int z = 1; z < SK; z++) {
    const float4 v = *(const float4*)(pbuf + z * MN + flat);
    s.x += v.x; s.y += v.y; s.z += v.z; s.w += v.w;
  }
  const float4 bv = *(const float4*)(bias + col);
  s.x += bv.x; s.y += bv.y; s.z += bv.z; s.w += bv.w;
  if constexpr (EPI == EPI_Q) {
    const int sq = row & (Sc - 1), d = col & 63;
    const float4 pv = *(const float4*)(pos + sq * HDc + d);
    constexpr float sc = 0.180336880111120426f;  // (1/8)*log2(e)
    ushort4 o;
    o.x = f2b((s.x + pv.x) * sc);
    o.y = f2b((s.y + pv.y) * sc);
    o.z = f2b((s.z + pv.z) * sc);
    o.w = f2b((s.w + pv.w) * sc);
    *(ushort4*)(outb + flat) = o;
  } else {
    const float4 av = *(const float4*)(addsrc + flat);
    float4 o;
    o.x = s.x + av.x; o.y = s.y + av.y; o.z = s.z + av.z; o.w = s.w + av.w;
    *(float4*)(outf + flat) = o;
  }
}

// ---------------- fused attention: grid (bh, qt) ----------------
// R13: merge the half dimension -> every block does exactly (qt+1)+(16-qt) = 17
// units (uniform work; R3's grid (bh,qt,half) ran 1..16 units per block and
// averaged 23% occupancy from retirement imbalance), and apply the R3-proven
// T4 counted-vmcnt pipeline to the unit loop: 4 distinct K buffers + 4 distinct
// V buffers (alias-clean), raw s_barrier, vmcnt(8) = 4 loads/unit x 2 units in
// flight, ONE barrier per unit. Since one block now sees both halves, o/l are
// accumulated in-register across all 17 units and the block writes normalized
// bf16 output directly -> o_part/l_part (16.8 MB write + 16.8+ MB read) and the
// attn_norm kernel are eliminated.
// Unit p: p<=qt -> keys p*64.. (f-half; mask key>qrow at p==qt);
//         p>qt  -> keys Sc+(p-1)*64.. (r-half; mask key-Sc<qrow at p==qt+1).
// qb: [b,q,h,d] bf16 (pre-scaled by (1/8)*log2e); kb: [b,key(2S),h,d];
// vT: [b,h,d,key(2S)]; ob: [b,q,h,d] bf16.
__global__ __launch_bounds__(256) void attn_kernel(const u16* __restrict__ qb,
                                                   const u16* __restrict__ kb,
                                                   const u16* __restrict__ vT,
                                                   u16* __restrict__ ob) {
  const int bh = blockIdx.x;
  const int qt = blockIdx.y;
  const int b = bh >> 4, head = bh & 15;
  const int tid = threadIdx.x;
  const int w = tid >> 6, lane = tid & 63, quad = lane >> 4, r16 = lane & 15;

  // per-unit K tile: [ks(2)][64 keys][32 d] (64-B rows); V tile: [ks][64 d][32 keys]
  __shared__ u16 K0s[4096], K1s[4096], K2s[4096], K3s[4096];
  __shared__ u16 V0s[4096], V1s[4096], V2s[4096], V3s[4096];
  __shared__ u16 Ps[4][16 * 68];  // per-wave P round-trip (stride 68: conflict-free)
  u16* ps = Ps[w];

  const int qw = qt * 64 + w * 16;  // this wave's 16 queries

  bf16x8 aq[2];
  {
    const u16* qp = qb + ((size_t)((b * Sc + qw + r16) * Hc + head)) * HDc + quad * 8;
    aq[0] = *(const bf16x8*)qp;
    aq[1] = *(const bf16x8*)(qp + 32);
  }

  const size_t krow = (size_t)Hc * HDc;
  const u16* kbase = kb + ((size_t)b * S2c * Hc + head) * HDc;
  const u16* vbase = vT + ((size_t)(b * Hc + head)) * HDc * S2c;

  // cooperative staging map: wave w covers rows w*16 + lane/4, 16 B at (lane&3)*8
  const int srow = w * 16 + (lane >> 2);
  const int scol = (lane & 3) * 8;
  const int stg = w * 16 * 32;  // wave-uniform LDS stage base (u16 offset)
  const u16* kS = kbase + (size_t)srow * krow + scol;   // + key0*krow (+32 for ks=1)
  const u16* vS = vbase + (size_t)srow * S2c + scol;    // + key0     (+32 for ks=1)

  f32x4 o_acc[4] = {};
  float lsum[4] = {};

  auto K0OF = [&](int p) -> int { return (p <= qt) ? p * 64 : Sc + (p - 1) * 64; };

  auto STAGE = [&](u16* Kd, u16* Vd, int p) {
    const int k0 = K0OF(p);
    glds16(kS + (size_t)k0 * krow, Kd + stg);
    glds16(kS + (size_t)k0 * krow + 32, Kd + 2048 + stg);
    glds16(vS + k0, Vd + stg);
    glds16(vS + k0 + 32, Vd + 2048 + stg);
  };

  auto COMPUTE = [&](const u16* Kc, const u16* Vc, int p) {
    const int k0 = K0OF(p);
    // QK^T from LDS
    f32x4 sacc[4] = {};
#pragma unroll
    for (int ks = 0; ks < 2; ks++)
#pragma unroll
      for (int ni = 0; ni < 4; ni++) {
        const bf16x8 bk = *(const bf16x8*)&Kc[ks * 2048 + (ni * 16 + r16) * 32 + quad * 8];
        sacc[ni] = mfma16(aq[ks], bk, sacc[ni]);
      }
    const int mode = (p == qt) ? 1 : ((p == qt + 1) ? 2 : 0);
#pragma unroll
    for (int r = 0; r < 4; r++) {
      const int qrow = qw + quad * 4 + r;
#pragma unroll
      for (int ni = 0; ni < 4; ni++) {
        float s = sacc[ni][r];
        if (mode == 1) { const int key = k0 + ni * 16 + r16; if (key > qrow) s = -128.0f; }
        else if (mode == 2) { const int key = k0 - Sc + ni * 16 + r16; if (key < qrow) s = -128.0f; }
        const float pe = __builtin_amdgcn_exp2f(s);
        lsum[r] += pe;
        ps[(quad * 4 + r) * 68 + ni * 16 + r16] = f2b_fast(pe);
      }
    }
    // PV from LDS (Ps is wave-private: lgkm ordering only, no barrier needed)
#pragma unroll
    for (int ks = 0; ks < 2; ks++) {
      const bf16x8 ap = *(const bf16x8*)(&ps[r16 * 68 + ks * 32 + quad * 8]);
#pragma unroll
      for (int ni = 0; ni < 4; ni++) {
        const bf16x8 bv_ = *(const bf16x8*)&Vc[ks * 2048 + (ni * 16 + r16) * 32 + quad * 8];
        o_acc[ni] = mfma16(ap, bv_, o_acc[ni]);
      }
    }
  };

  constexpr int NU = 17;  // (qt+1) + (16-qt), uniform for all blocks
  STAGE(K0s, V0s, 0);
  STAGE(K1s, V1s, 1);
  for (int t = 0; t < NU; t += 4) {
    {
      if (t + 2 < NU) { STAGE(K2s, V2s, t + 2); PIPE_WAIT(8); }
      else if (t + 1 < NU) PIPE_WAIT(4);
      else PIPE_WAIT(0);
      PIPE_BAR();
      COMPUTE(K0s, V0s, t);
    }
    if (t + 1 < NU) {
      if (t + 3 < NU) { STAGE(K3s, V3s, t + 3); PIPE_WAIT(8); }
      else if (t + 2 < NU) PIPE_WAIT(4);
      else PIPE_WAIT(0);
      PIPE_BAR();
      COMPUTE(K1s, V1s, t + 1);
    }
    if (t + 2 < NU) {
      if (t + 4 < NU) { STAGE(K0s, V0s, t + 4); PIPE_WAIT(8); }
      else if (t + 3 < NU) PIPE_WAIT(4);
      else PIPE_WAIT(0);
      PIPE_BAR();
      COMPUTE(K2s, V2s, t + 2);
    }
    if (t + 3 < NU) {
      if (t + 5 < NU) { STAGE(K1s, V1s, t + 5); PIPE_WAIT(8); }
      else if (t + 4 < NU) PIPE_WAIT(4);
      else PIPE_WAIT(0);
      PIPE_BAR();
      COMPUTE(K3s, V3s, t + 3);
    }
  }

  // normalize in-register and write bf16 [b,q,h,d] directly
#pragma unroll
  for (int r = 0; r < 4; r++) {
    float l = lsum[r];
    l += __shfl_xor(l, 1);
    l += __shfl_xor(l, 2);
    l += __shfl_xor(l, 4);
    l += __shfl_xor(l, 8);
    lsum[r] = 1.0f / l;
  }
#pragma unroll
  for (int r = 0; r < 4; r++) {
    u16* od = ob + ((size_t)((b * Sc + qw + quad * 4 + r) * Hc + head)) * HDc;
#pragma unroll
    for (int ni = 0; ni < 4; ni++) od[ni * 16 + r16] = f2b(o_acc[ni][r] * lsum[r]);
  }
}

extern "C" void kernel_launch(void* const* d_in, const int* in_sizes, int n_in, void* d_out,
                              int out_size, void* d_ws, size_t ws_size, hipStream_t stream) {
  const float* fwd = (const float*)d_in[0];
  const float* bwd = (const float*)d_in[1];
  const float* pos = (const float*)d_in[2];
  const float* ln1g = (const float*)d_in[3];
  const float* ln1b = (const float*)d_in[4];
  const float* Wq = (const float*)d_in[5];
  const float* bq = (const float*)d_in[6];
  const float* Wk = (const float*)d_in[7];
  const float* bk = (const float*)d_in[8];
  const float* Wv = (const float*)d_in[9];
  const float* bv = (const float*)d_in[10];
  const float* Wo = (const float*)d_in[11];
  const float* bo = (const float*)d_in[12];
  const float* ln2g = (const float*)d_in[13];
  const float* ln2b = (const float*)d_in[14];
  const float* mlpg = (const float*)d_in[15];
  const float* mlpb = (const float*)d_in[16];
  const float* W1 = (const float*)d_in[17];
  const float* b1 = (const float*)d_in[18];
  const float* W2 = (const float*)d_in[19];
  const float* b2 = (const float*)d_in[20];

  char* p = (char*)d_ws;
  auto alloc = [&](size_t bytes) -> char* {
    char* r = p;
    p += (bytes + 255) & ~(size_t)255;
    return r;
  };
  float* comb = (float*)alloc((size_t)BSc * Cc * 4);
  float* xbuf = (float*)alloc((size_t)BSc * Cc * 4);
  u16* cx = (u16*)alloc((size_t)BSc * Cc * 2);
  u16* ae = (u16*)alloc((size_t)BS2c * Cc * 2);
  u16* qbuf = (u16*)alloc((size_t)BSc * Cc * 2);
  u16* kbuf = (u16*)alloc((size_t)BS2c * Cc * 2);
  u16* vTb = (u16*)alloc((size_t)BS2c * Cc * 2);
  u16* obuf = (u16*)alloc((size_t)BSc * Cc * 2);
  u16* hb = (u16*)alloc((size_t)BSc * Cc * 2);
  u16* midb = (u16*)alloc((size_t)BSc * ECc * 2);
  float* pbuf = (float*)alloc((size_t)4 * BSc * Cc * 4);  // 4 split-K slices of 2048x1024 f32
  u16* WqT = (u16*)alloc((size_t)Cc * Cc * 2);
  u16* WkvT = (u16*)alloc((size_t)2 * Cc * Cc * 2);
  u16* WoT = (u16*)alloc((size_t)Cc * Cc * 2);
  u16* W1T = (u16*)alloc((size_t)ECc * Cc * 2);
  u16* W2T = (u16*)alloc((size_t)Cc * ECc * 2);

  const dim3 tb(32, 8);
  transpose4_kernel<<<dim3(32, 32, 4), tb, 0, stream>>>(Wq, Wk, Wv, Wo, WqT, WkvT, WoT);
  transpose_kernel<<<dim3(128, 32), tb, 0, stream>>>(W1, W1T, Cc, ECc);
  transpose_kernel<<<dim3(32, 128), tb, 0, stream>>>(W2, W2T, ECc, Cc);

  prep_ln_kernel<<<BSc + BS2c, 256, 0, stream>>>(fwd, bwd, ln1g, ln1b, comb, cx, ae);

  // Q = cx @ WqT^T  (split-K=4 -> 512 blocks)
  gemm_kernel<EPI_PART, 4><<<dim3(Cc / 128, BSc / 128, 4), 256, 0, stream>>>(
      cx, WqT, nullptr, nullptr, nullptr, nullptr, nullptr, pbuf, BSc, Cc, Cc);
  reduce_kernel<EPI_Q, 4><<<(BSc * Cc / 4) / 256, 256, 0, stream>>>(
      pbuf, bq, pos, nullptr, qbuf, nullptr, BSc, Cc);

  // K,V fused (N=2048, 512 blocks)
  gemm_kernel<EPI_KV, 1><<<dim3(2 * Cc / 128, BS2c / 128, 1), 256, 0, stream>>>(
      ae, WkvT, bk, bv, pos, kbuf, vTb, nullptr, BS2c, 2 * Cc, Cc);

  // fused attention (both halves per block; writes normalized bf16 obuf directly)
  attn_kernel<<<dim3(Bc * Hc, Sc / 64), 256, 0, stream>>>(qbuf, kbuf, vTb, obuf);

  // x = comb + (o @ WoT^T + bo)  (split-K=4)
  gemm_kernel<EPI_PART, 4><<<dim3(Cc / 128, BSc / 128, 4), 256, 0, stream>>>(
      obuf, WoT, nullptr, nullptr, nullptr, nullptr, nullptr, pbuf, BSc, Cc, Cc);
  reduce_kernel<EPI_O, 4><<<(BSc * Cc / 4) / 256, 256, 0, stream>>>(
      pbuf, bo, nullptr, comb, nullptr, xbuf, BSc, Cc);

  ln2_kernel<<<BSc, 256, 0, stream>>>(xbuf, ln2g, ln2b, mlpg, mlpb, hb);

  // mid = gelu(h @ W1T^T + b1)  (512 blocks)
  gemm_kernel<EPI_GELU, 1><<<dim3(ECc / 128, BSc / 128, 1), 256, 0, stream>>>(
      hb, W1T, b1, nullptr, nullptr, midb, nullptr, nullptr, BSc, ECc, Cc);

  // out = x + (mid @ W2T^T + b2)  (split-K=4 over K=4096 -> 512 blocks)
  gemm_kernel<EPI_PART, 4><<<dim3(Cc / 128, BSc / 128, 4), 256, 0, stream>>>(
      midb, W2T, nullptr, nullptr, nullptr, nullptr, nullptr, pbuf, BSc, Cc, ECc);
  reduce_kernel<EPI_FINAL, 4><<<(BSc * Cc / 4) / 256, 256, 0, stream>>>(
      pbuf, b2, nullptr, xbuf, nullptr, (float*)d_out, BSc, Cc);
}

// Round 7
// 321.967 us; speedup vs baseline: 1.1266x; 1.0309x over previous
//
#include <hip/hip_runtime.h>
#include <hip/hip_bf16.h>
#include <cstdint>

#define DI __device__ __forceinline__

typedef unsigned short u16;
typedef __bf16 bf16x8 __attribute__((ext_vector_type(8)));
typedef float f32x4 __attribute__((ext_vector_type(4)));

constexpr int Bc  = 2;
constexpr int Sc  = 1024;
constexpr int Cc  = 1024;
constexpr int Hc  = 16;
constexpr int HDc = 64;
constexpr int S2c = 2048;
constexpr int ECc = 4096;
constexpr int BSc  = Bc * Sc;   // 2048
constexpr int BS2c = Bc * S2c;  // 4096

constexpr int EPI_KV = 0, EPI_Q = 1, EPI_O = 3, EPI_GELU = 4, EPI_FINAL = 5, EPI_PART = 6;

DI u16 f2b(float f) {
  __hip_bfloat16 h = __float2bfloat16(f);
  u16 u;
  __builtin_memcpy(&u, &h, 2);
  return u;
}

// fast bf16 pack (round-half-up); fine for p in [0,1]
DI u16 f2b_fast(float f) {
  uint32_t u;
  __builtin_memcpy(&u, &f, 4);
  return (u16)((u + 0x8000u) >> 16);
}

// CK-style direct global->LDS (16B per lane; LDS dest = wave-uniform base + lane*16)
DI void glds16(const void* g, void* l) {
  auto* lp = reinterpret_cast<__attribute__((address_space(3))) uint32_t*>(
      reinterpret_cast<uintptr_t>(l));
  __builtin_amdgcn_global_load_lds(
      reinterpret_cast<const __attribute__((address_space(1))) uint32_t*>(
          reinterpret_cast<uintptr_t>(g)),
      lp, 16, 0, 0);
}

DI f32x4 mfma16(bf16x8 a, bf16x8 b, f32x4 c) {
  return __builtin_amdgcn_mfma_f32_16x16x32_bf16(a, b, c, 0, 0, 0);
}

// counted vmcnt wait + scheduling fence (rule #18: pin code motion around inline-asm waits)
#define PIPE_WAIT(N)                                            \
  do {                                                          \
    asm volatile("s_waitcnt vmcnt(" #N ")" ::: "memory");       \
    __builtin_amdgcn_sched_barrier(0);                          \
  } while (0)
#define PIPE_BAR()                                              \
  do {                                                          \
    __builtin_amdgcn_s_barrier();                               \
    __builtin_amdgcn_sched_barrier(0);                          \
  } while (0)

// ------------- fused transpose of the four CxC weights: WT[n][k] = W[k][n] -------------
__global__ __launch_bounds__(256) void transpose4_kernel(const float* __restrict__ Wq,
                                                         const float* __restrict__ Wk,
                                                         const float* __restrict__ Wv,
                                                         const float* __restrict__ Wo,
                                                         u16* __restrict__ WqT,
                                                         u16* __restrict__ WkvT,
                                                         u16* __restrict__ WoT) {
  __shared__ float tile[32][33];
  const int z = blockIdx.z;
  const float* W = (z == 0) ? Wq : (z == 1) ? Wk : (z == 2) ? Wv : Wo;
  u16* WT = (z == 0) ? WqT : (z == 1) ? WkvT : (z == 2) ? (WkvT + (size_t)Cc * Cc) : WoT;
  const int bx = blockIdx.x, by = blockIdx.y;
  const int tx = threadIdx.x, ty = threadIdx.y;
  const int c = bx * 32 + tx;
#pragma unroll
  for (int i = ty; i < 32; i += 8) tile[i][tx] = W[(size_t)(by * 32 + i) * Cc + c];
  __syncthreads();
#pragma unroll
  for (int i = ty; i < 32; i += 8)
    WT[(size_t)(bx * 32 + i) * Cc + by * 32 + tx] = f2b(tile[tx][i]);
}

// ---------------- transpose + fp32->bf16 convert: WT[n][k] = W[k][n] ----------------
__global__ __launch_bounds__(256) void transpose_kernel(const float* __restrict__ W,
                                                        u16* __restrict__ WT, int R, int Cn) {
  __shared__ float tile[32][33];
  const int bx = blockIdx.x, by = blockIdx.y;
  const int tx = threadIdx.x, ty = threadIdx.y;
  const int c = bx * 32 + tx;
#pragma unroll
  for (int i = ty; i < 32; i += 8) tile[i][tx] = W[(size_t)(by * 32 + i) * Cn + c];
  __syncthreads();
#pragma unroll
  for (int i = ty; i < 32; i += 8)
    WT[(size_t)(bx * 32 + i) * R + by * 32 + tx] = f2b(tile[tx][i]);
}

// ---------------- prep: comb + LN(comb)->cx ; LN(all_embed)->ae ----------------
__global__ __launch_bounds__(256) void prep_ln_kernel(
    const float* __restrict__ fwd, const float* __restrict__ bwd, const float* __restrict__ g,
    const float* __restrict__ be, float* __restrict__ comb, u16* __restrict__ cx,
    u16* __restrict__ ae) {
  __shared__ float red[2][4];
  const int row = blockIdx.x, tid = threadIdx.x;
  const int c = tid * 4;
  float4 x;
  u16* dst;
  if (row < BSc) {
    const int b = row >> 10, s = row & (Sc - 1);
    const float4 f = *(const float4*)(fwd + ((size_t)(b * (Sc + 1) + s)) * Cc + c);
    const float4 r = *(const float4*)(bwd + ((size_t)(b * (Sc + 1) + s + 1)) * Cc + c);
    const float k = 0.70710678118654752f;
    x.x = (f.x + r.x) * k; x.y = (f.y + r.y) * k;
    x.z = (f.z + r.z) * k; x.w = (f.w + r.w) * k;
    *(float4*)(comb + (size_t)row * Cc + c) = x;
    dst = cx + (size_t)row * Cc;
  } else {
    const int idx = row - BSc;
    const int b = idx >> 11, t = idx & (S2c - 1);
    const float* src = (t < Sc) ? (fwd + ((size_t)(b * (Sc + 1) + t)) * Cc)
                                : (bwd + ((size_t)(b * (Sc + 1) + (t - Sc) + 1)) * Cc);
    x = *(const float4*)(src + c);
    dst = ae + (size_t)idx * Cc;
  }
  float s1 = x.x + x.y + x.z + x.w;
  float s2 = x.x * x.x + x.y * x.y + x.z * x.z + x.w * x.w;
  for (int off = 32; off; off >>= 1) { s1 += __shfl_down(s1, off); s2 += __shfl_down(s2, off); }
  if ((tid & 63) == 0) { red[0][tid >> 6] = s1; red[1][tid >> 6] = s2; }
  __syncthreads();
  s1 = red[0][0] + red[0][1] + red[0][2] + red[0][3];
  s2 = red[1][0] + red[1][1] + red[1][2] + red[1][3];
  const float mean = s1 * (1.0f / Cc);
  const float rstd = rsqrtf(s2 * (1.0f / Cc) - mean * mean + 1e-5f);
  const float4 gv = *(const float4*)(g + c);
  const float4 bv = *(const float4*)(be + c);
  ushort4 o;
  o.x = f2b((x.x - mean) * rstd * gv.x + bv.x);
  o.y = f2b((x.y - mean) * rstd * gv.y + bv.y);
  o.z = f2b((x.z - mean) * rstd * gv.z + bv.z);
  o.w = f2b((x.w - mean) * rstd * gv.w + bv.w);
  *(ushort4*)(dst + c) = o;
}

// ---------------- double LN: h = LN(LN(x,g2,b2),gm,bm) ----------------
__global__ __launch_bounds__(256) void ln2_kernel(const float* __restrict__ x,
                                                  const float* __restrict__ g2,
                                                  const float* __restrict__ b2,
                                                  const float* __restrict__ gm,
                                                  const float* __restrict__ bm,
                                                  u16* __restrict__ h) {
  __shared__ float red[2][4];
  const int row = blockIdx.x, tid = threadIdx.x;
  const int c = tid * 4;
  const float4 v = *(const float4*)(x + (size_t)row * Cc + c);
  float s1 = v.x + v.y + v.z + v.w;
  float s2 = v.x * v.x + v.y * v.y + v.z * v.z + v.w * v.w;
  for (int off = 32; off; off >>= 1) { s1 += __shfl_down(s1, off); s2 += __shfl_down(s2, off); }
  if ((tid & 63) == 0) { red[0][tid >> 6] = s1; red[1][tid >> 6] = s2; }
  __syncthreads();
  s1 = red[0][0] + red[0][1] + red[0][2] + red[0][3];
  s2 = red[1][0] + red[1][1] + red[1][2] + red[1][3];
  float mean = s1 * (1.0f / Cc);
  float rstd = rsqrtf(s2 * (1.0f / Cc) - mean * mean + 1e-5f);
  const float4 ga = *(const float4*)(g2 + c);
  const float4 ba = *(const float4*)(b2 + c);
  const float t0 = (v.x - mean) * rstd * ga.x + ba.x;
  const float t1 = (v.y - mean) * rstd * ga.y + ba.y;
  const float t2 = (v.z - mean) * rstd * ga.z + ba.z;
  const float t3 = (v.w - mean) * rstd * ga.w + ba.w;
  s1 = t0 + t1 + t2 + t3;
  s2 = t0 * t0 + t1 * t1 + t2 * t2 + t3 * t3;
  for (int off = 32; off; off >>= 1) { s1 += __shfl_down(s1, off); s2 += __shfl_down(s2, off); }
  __syncthreads();
  if ((tid & 63) == 0) { red[0][tid >> 6] = s1; red[1][tid >> 6] = s2; }
  __syncthreads();
  s1 = red[0][0] + red[0][1] + red[0][2] + red[0][3];
  s2 = red[1][0] + red[1][1] + red[1][2] + red[1][3];
  mean = s1 * (1.0f / Cc);
  rstd = rsqrtf(s2 * (1.0f / Cc) - mean * mean + 1e-5f);
  const float4 gb = *(const float4*)(gm + c);
  const float4 bb = *(const float4*)(bm + c);
  ushort4 o;
  o.x = f2b((t0 - mean) * rstd * gb.x + bb.x);
  o.y = f2b((t1 - mean) * rstd * gb.y + bb.y);
  o.z = f2b((t2 - mean) * rstd * gb.z + bb.z);
  o.w = f2b((t3 - mean) * rstd * gb.w + bb.w);
  *(ushort4*)(h + (size_t)row * Cc + c) = o;
}

// ---------------- GEMM: Y = A(MxK) @ BT(NxK)^T, fused epilogues ----------------
// 128x128 tile, BK=32, glds16 staging, T4 counted-vmcnt 4-buffer pipeline
// (alias-clean distinct LDS objects; raw s_barrier; never vmcnt(0) in steady
// state — verified R3).
// R14/R15/R16: 8 waves (512 threads), wave = 64x32 quadrant (acc[4][2],
// 8 MFMA/step). Rationale: 256-thread blocks gave only 2 waves/SIMD (8
// waves/CU at the grid-limited 2 blocks/CU); all waves of a block are
// barrier-locked per K-step, so each barrier+vmcnt left the SIMD ~1 runnable
// wave. 512-thread blocks double it to 4 waves/SIMD — during one block's
// drain the other block's 2 waves/SIMD feed the matrix pipe. Staging: 512
// lanes x 16 B = the full 8 KB half-tile in ONE pass -> 1 A-load + 1 B-load
// per lane per tile, so steady-state wait = vmcnt(4) (2 loads x 2 tiles in
// flight); tails 2, 0.
template <int EPI, int SK>
__global__ __launch_bounds__(512) void gemm_kernel(
    const u16* __restrict__ A, const u16* __restrict__ BT, const float* __restrict__ bias,
    const float* __restrict__ bias2, const float* __restrict__ pos,
    u16* __restrict__ outb, u16* __restrict__ out2, float* __restrict__ pbuf,
    int M, int N, int K) {
  __shared__ u16 A0s[128 * 32], A1s[128 * 32], A2s[128 * 32], A3s[128 * 32];
  __shared__ u16 B0s[128 * 32], B1s[128 * 32], B2s[128 * 32], B3s[128 * 32];
  const int tid = threadIdx.x;
  const int w = tid >> 6, lane = tid & 63, quad = lane >> 4, r16 = lane & 15;
  const int bm = blockIdx.y * 128, bn = blockIdx.x * 128;
  const int wm = (w >> 2) * 64, wn = (w & 3) * 32;  // 2 M-waves x 4 N-waves
  const int Ks = K / SK, kb0 = blockIdx.z * Ks;

  const int srow = tid >> 2, scol = (tid & 3) * 8;  // 512 lanes cover 128 rows x 32 cols
  const u16* aP = A + (size_t)(bm + srow) * K + kb0 + scol;
  const u16* bP = BT + (size_t)(bn + srow) * K + kb0 + scol;
  const int stg = (w * 16) * 32;  // wave-uniform LDS stage base (u16 offset)

  f32x4 acc[4][2] = {};

  auto STAGE = [&](u16* Ad, u16* Bd, int t) {
    const int ko = t * 32;
    glds16(aP + ko, Ad + stg);
    glds16(bP + ko, Bd + stg);
  };
  auto COMPUTE = [&](const u16* As, const u16* Bs) {
    bf16x8 af[4], bfr[2];
#pragma unroll
    for (int i = 0; i < 4; i++)
      af[i] = *reinterpret_cast<const bf16x8*>(&As[(wm + i * 16 + r16) * 32 + quad * 8]);
#pragma unroll
    for (int i = 0; i < 2; i++)
      bfr[i] = *reinterpret_cast<const bf16x8*>(&Bs[(wn + i * 16 + r16) * 32 + quad * 8]);
#pragma unroll
    for (int mi = 0; mi < 4; mi++)
#pragma unroll
      for (int ni = 0; ni < 2; ni++) acc[mi][ni] = mfma16(af[mi], bfr[ni], acc[mi][ni]);
  };

  const int NT = Ks / 32;  // 8 or 32; divisible by 4
  STAGE(A0s, B0s, 0);
  STAGE(A1s, B1s, 1);
  for (int t = 0; t < NT; t += 4) {
    if (t + 2 < NT) { STAGE(A2s, B2s, t + 2); PIPE_WAIT(4); }
    else if (t + 1 < NT) PIPE_WAIT(2);
    else PIPE_WAIT(0);
    PIPE_BAR();
    COMPUTE(A0s, B0s);
    if (t + 3 < NT) { STAGE(A3s, B3s, t + 3); PIPE_WAIT(4); }
    else if (t + 2 < NT) PIPE_WAIT(2);
    else PIPE_WAIT(0);
    PIPE_BAR();
    COMPUTE(A1s, B1s);
    if (t + 4 < NT) { STAGE(A0s, B0s, t + 4); PIPE_WAIT(4); }
    else if (t + 3 < NT) PIPE_WAIT(2);
    else PIPE_WAIT(0);
    PIPE_BAR();
    COMPUTE(A2s, B2s);
    if (t + 5 < NT) { STAGE(A1s, B1s, t + 5); PIPE_WAIT(4); }
    else if (t + 4 < NT) PIPE_WAIT(2);
    else PIPE_WAIT(0);
    PIPE_BAR();
    COMPUTE(A3s, B3s);
  }

#pragma unroll
  for (int mi = 0; mi < 4; mi++) {
#pragma unroll
    for (int ni = 0; ni < 2; ni++) {
      const int col = bn + wn + ni * 16 + r16;
      const int row0 = bm + wm + mi * 16 + quad * 4;
      if constexpr (EPI == EPI_PART) {
        float* pb = pbuf + (size_t)blockIdx.z * M * N;
#pragma unroll
        for (int r = 0; r < 4; r++) pb[(size_t)(row0 + r) * N + col] = acc[mi][ni][r];
      } else if constexpr (EPI == EPI_KV) {
        if (col < Cc) {
#pragma unroll
          for (int r = 0; r < 4; r++) {
            const int row = row0 + r;
            const int key = row & (S2c - 1);
            const float y =
                acc[mi][ni][r] + bias[col] + pos[(key & (Sc - 1)) * HDc + (col & 63)];
            outb[(size_t)row * Cc + col] = f2b(y);
          }
        } else {
          const int c2 = col - Cc;
          const int h = c2 >> 6, d = c2 & 63;
          const int b = row0 >> 11, key0 = row0 & (S2c - 1);
          const float bb = bias2[c2];
          ushort4 pk;
          pk.x = f2b(acc[mi][ni][0] + bb);
          pk.y = f2b(acc[mi][ni][1] + bb);
          pk.z = f2b(acc[mi][ni][2] + bb);
          pk.w = f2b(acc[mi][ni][3] + bb);
          *(ushort4*)&out2[(((size_t)(b * Hc + h) * HDc + d) << 11) + key0] = pk;
        }
      } else {  // EPI_GELU
#pragma unroll
        for (int r = 0; r < 4; r++) {
          const float y = acc[mi][ni][r] + bias[col];
          outb[(size_t)(row0 + r) * N + col] =
              f2b(0.5f * y * (1.0f + erff(y * 0.70710678118654752f)));
        }
      }
    }
  }
}

// ---------------- split-K reduce + epilogue (SK slices of MxN f32) ----------------
// EPI_Q: out = bf16((sum + bias + pos) * scale) ; EPI_O/EPI_FINAL: out = f32(sum + bias + add)
template <int EPI, int SK>
__global__ __launch_bounds__(256) void reduce_kernel(const float* __restrict__ pbuf,
                                                     const float* __restrict__ bias,
                                                     const float* __restrict__ pos,
                                                     const float* __restrict__ addsrc,
                                                     u16* __restrict__ outb,
                                                     float* __restrict__ outf, int M, int N) {
  const size_t flat = ((size_t)blockIdx.x * 256 + threadIdx.x) * 4;
  const int row = (int)(flat / N), col = (int)(flat % N);
  const size_t MN = (size_t)M * N;
  float4 s = *(const float4*)(pbuf + flat);
#pragma unroll
  for (int z = 1; z < SK; z++) {
    const float4 v = *(const float4*)(pbuf + z * MN + flat);
    s.x += v.x; s.y += v.y; s.z += v.z; s.w += v.w;
  }
  const float4 bv = *(const float4*)(bias + col);
  s.x += bv.x; s.y += bv.y; s.z += bv.z; s.w += bv.w;
  if constexpr (EPI == EPI_Q) {
    const int sq = row & (Sc - 1), d = col & 63;
    const float4 pv = *(const float4*)(pos + sq * HDc + d);
    constexpr float sc = 0.180336880111120426f;  // (1/8)*log2(e)
    ushort4 o;
    o.x = f2b((s.x + pv.x) * sc);
    o.y = f2b((s.y + pv.y) * sc);
    o.z = f2b((s.z + pv.z) * sc);
    o.w = f2b((s.w + pv.w) * sc);
    *(ushort4*)(outb + flat) = o;
  } else {
    const float4 av = *(const float4*)(addsrc + flat);
    float4 o;
    o.x = s.x + av.x; o.y = s.y + av.y; o.z = s.z + av.z; o.w = s.w + av.w;
    *(float4*)(outf + flat) = o;
  }
}

// ---------------- fused attention: grid (bh, qt) ----------------
// R13 (kept, verified R4): both halves in one block -> uniform 17 units/block;
// T4 counted-vmcnt pipeline (4 distinct K + 4 distinct V buffers, raw
// s_barrier, vmcnt(8) = 4 loads/unit x 2 units in flight); o/l accumulated
// in-register across both halves; normalized bf16 output written directly
// (o_part/l_part buffers and attn_norm kernel eliminated).
// Unit p: p<=qt -> keys p*64.. (f-half; mask key>qrow at p==qt);
//         p>qt  -> keys Sc+(p-1)*64.. (r-half; mask key-Sc<qrow at p==qt+1).
// qb: [b,q,h,d] bf16 (pre-scaled by (1/8)*log2e); kb: [b,key(2S),h,d];
// vT: [b,h,d,key(2S)]; ob: [b,q,h,d] bf16.
__global__ __launch_bounds__(256) void attn_kernel(const u16* __restrict__ qb,
                                                   const u16* __restrict__ kb,
                                                   const u16* __restrict__ vT,
                                                   u16* __restrict__ ob) {
  const int bh = blockIdx.x;
  const int qt = blockIdx.y;
  const int b = bh >> 4, head = bh & 15;
  const int tid = threadIdx.x;
  const int w = tid >> 6, lane = tid & 63, quad = lane >> 4, r16 = lane & 15;

  // per-unit K tile: [ks(2)][64 keys][32 d] (64-B rows); V tile: [ks][64 d][32 keys]
  __shared__ u16 K0s[4096], K1s[4096], K2s[4096], K3s[4096];
  __shared__ u16 V0s[4096], V1s[4096], V2s[4096], V3s[4096];
  __shared__ u16 Ps[4][16 * 68];  // per-wave P round-trip (stride 68: conflict-free)
  u16* ps = Ps[w];

  const int qw = qt * 64 + w * 16;  // this wave's 16 queries

  bf16x8 aq[2];
  {
    const u16* qp = qb + ((size_t)((b * Sc + qw + r16) * Hc + head)) * HDc + quad * 8;
    aq[0] = *(const bf16x8*)qp;
    aq[1] = *(const bf16x8*)(qp + 32);
  }

  const size_t krow = (size_t)Hc * HDc;
  const u16* kbase = kb + ((size_t)b * S2c * Hc + head) * HDc;
  const u16* vbase = vT + ((size_t)(b * Hc + head)) * HDc * S2c;

  // cooperative staging map: wave w covers rows w*16 + lane/4, 16 B at (lane&3)*8
  const int srow = w * 16 + (lane >> 2);
  const int scol = (lane & 3) * 8;
  const int stg = w * 16 * 32;  // wave-uniform LDS stage base (u16 offset)
  const u16* kS = kbase + (size_t)srow * krow + scol;   // + key0*krow (+32 for ks=1)
  const u16* vS = vbase + (size_t)srow * S2c + scol;    // + key0     (+32 for ks=1)

  f32x4 o_acc[4] = {};
  float lsum[4] = {};

  auto K0OF = [&](int p) -> int { return (p <= qt) ? p * 64 : Sc + (p - 1) * 64; };

  auto STAGE = [&](u16* Kd, u16* Vd, int p) {
    const int k0 = K0OF(p);
    glds16(kS + (size_t)k0 * krow, Kd + stg);
    glds16(kS + (size_t)k0 * krow + 32, Kd + 2048 + stg);
    glds16(vS + k0, Vd + stg);
    glds16(vS + k0 + 32, Vd + 2048 + stg);
  };

  auto COMPUTE = [&](const u16* Kc, const u16* Vc, int p) {
    const int k0 = K0OF(p);
    // QK^T from LDS
    f32x4 sacc[4] = {};
#pragma unroll
    for (int ks = 0; ks < 2; ks++)
#pragma unroll
      for (int ni = 0; ni < 4; ni++) {
        const bf16x8 bk = *(const bf16x8*)&Kc[ks * 2048 + (ni * 16 + r16) * 32 + quad * 8];
        sacc[ni] = mfma16(aq[ks], bk, sacc[ni]);
      }
    const int mode = (p == qt) ? 1 : ((p == qt + 1) ? 2 : 0);
#pragma unroll
    for (int r = 0; r < 4; r++) {
      const int qrow = qw + quad * 4 + r;
#pragma unroll
      for (int ni = 0; ni < 4; ni++) {
        float s = sacc[ni][r];
        if (mode == 1) { const int key = k0 + ni * 16 + r16; if (key > qrow) s = -128.0f; }
        else if (mode == 2) { const int key = k0 - Sc + ni * 16 + r16; if (key < qrow) s = -128.0f; }
        const float pe = __builtin_amdgcn_exp2f(s);
        lsum[r] += pe;
        ps[(quad * 4 + r) * 68 + ni * 16 + r16] = f2b_fast(pe);
      }
    }
    // PV from LDS (Ps is wave-private: lgkm ordering only, no barrier needed)
#pragma unroll
    for (int ks = 0; ks < 2; ks++) {
      const bf16x8 ap = *(const bf16x8*)(&ps[r16 * 68 + ks * 32 + quad * 8]);
#pragma unroll
      for (int ni = 0; ni < 4; ni++) {
        const bf16x8 bv_ = *(const bf16x8*)&Vc[ks * 2048 + (ni * 16 + r16) * 32 + quad * 8];
        o_acc[ni] = mfma16(ap, bv_, o_acc[ni]);
      }
    }
  };

  constexpr int NU = 17;  // (qt+1) + (16-qt), uniform for all blocks
  STAGE(K0s, V0s, 0);
  STAGE(K1s, V1s, 1);
  for (int t = 0; t < NU; t += 4) {
    {
      if (t + 2 < NU) { STAGE(K2s, V2s, t + 2); PIPE_WAIT(8); }
      else if (t + 1 < NU) PIPE_WAIT(4);
      else PIPE_WAIT(0);
      PIPE_BAR();
      COMPUTE(K0s, V0s, t);
    }
    if (t + 1 < NU) {
      if (t + 3 < NU) { STAGE(K3s, V3s, t + 3); PIPE_WAIT(8); }
      else if (t + 2 < NU) PIPE_WAIT(4);
      else PIPE_WAIT(0);
      PIPE_BAR();
      COMPUTE(K1s, V1s, t + 1);
    }
    if (t + 2 < NU) {
      if (t + 4 < NU) { STAGE(K0s, V0s, t + 4); PIPE_WAIT(8); }
      else if (t + 3 < NU) PIPE_WAIT(4);
      else PIPE_WAIT(0);
      PIPE_BAR();
      COMPUTE(K2s, V2s, t + 2);
    }
    if (t + 3 < NU) {
      if (t + 5 < NU) { STAGE(K1s, V1s, t + 5); PIPE_WAIT(8); }
      else if (t + 4 < NU) PIPE_WAIT(4);
      else PIPE_WAIT(0);
      PIPE_BAR();
      COMPUTE(K3s, V3s, t + 3);
    }
  }

  // normalize in-register and write bf16 [b,q,h,d] directly
#pragma unroll
  for (int r = 0; r < 4; r++) {
    float l = lsum[r];
    l += __shfl_xor(l, 1);
    l += __shfl_xor(l, 2);
    l += __shfl_xor(l, 4);
    l += __shfl_xor(l, 8);
    lsum[r] = 1.0f / l;
  }
#pragma unroll
  for (int r = 0; r < 4; r++) {
    u16* od = ob + ((size_t)((b * Sc + qw + quad * 4 + r) * Hc + head)) * HDc;
#pragma unroll
    for (int ni = 0; ni < 4; ni++) od[ni * 16 + r16] = f2b(o_acc[ni][r] * lsum[r]);
  }
}

extern "C" void kernel_launch(void* const* d_in, const int* in_sizes, int n_in, void* d_out,
                              int out_size, void* d_ws, size_t ws_size, hipStream_t stream) {
  const float* fwd = (const float*)d_in[0];
  const float* bwd = (const float*)d_in[1];
  const float* pos = (const float*)d_in[2];
  const float* ln1g = (const float*)d_in[3];
  const float* ln1b = (const float*)d_in[4];
  const float* Wq = (const float*)d_in[5];
  const float* bq = (const float*)d_in[6];
  const float* Wk = (const float*)d_in[7];
  const float* bk = (const float*)d_in[8];
  const float* Wv = (const float*)d_in[9];
  const float* bv = (const float*)d_in[10];
  const float* Wo = (const float*)d_in[11];
  const float* bo = (const float*)d_in[12];
  const float* ln2g = (const float*)d_in[13];
  const float* ln2b = (const float*)d_in[14];
  const float* mlpg = (const float*)d_in[15];
  const float* mlpb = (const float*)d_in[16];
  const float* W1 = (const float*)d_in[17];
  const float* b1 = (const float*)d_in[18];
  const float* W2 = (const float*)d_in[19];
  const float* b2 = (const float*)d_in[20];

  char* p = (char*)d_ws;
  auto alloc = [&](size_t bytes) -> char* {
    char* r = p;
    p += (bytes + 255) & ~(size_t)255;
    return r;
  };
  float* comb = (float*)alloc((size_t)BSc * Cc * 4);
  float* xbuf = (float*)alloc((size_t)BSc * Cc * 4);
  u16* cx = (u16*)alloc((size_t)BSc * Cc * 2);
  u16* ae = (u16*)alloc((size_t)BS2c * Cc * 2);
  u16* qbuf = (u16*)alloc((size_t)BSc * Cc * 2);
  u16* kbuf = (u16*)alloc((size_t)BS2c * Cc * 2);
  u16* vTb = (u16*)alloc((size_t)BS2c * Cc * 2);
  u16* obuf = (u16*)alloc((size_t)BSc * Cc * 2);
  u16* hb = (u16*)alloc((size_t)BSc * Cc * 2);
  u16* midb = (u16*)alloc((size_t)BSc * ECc * 2);
  float* pbuf = (float*)alloc((size_t)4 * BSc * Cc * 4);  // 4 split-K slices of 2048x1024 f32
  u16* WqT = (u16*)alloc((size_t)Cc * Cc * 2);
  u16* WkvT = (u16*)alloc((size_t)2 * Cc * Cc * 2);
  u16* WoT = (u16*)alloc((size_t)Cc * Cc * 2);
  u16* W1T = (u16*)alloc((size_t)ECc * Cc * 2);
  u16* W2T = (u16*)alloc((size_t)Cc * ECc * 2);

  const dim3 tb(32, 8);
  transpose4_kernel<<<dim3(32, 32, 4), tb, 0, stream>>>(Wq, Wk, Wv, Wo, WqT, WkvT, WoT);
  transpose_kernel<<<dim3(128, 32), tb, 0, stream>>>(W1, W1T, Cc, ECc);
  transpose_kernel<<<dim3(32, 128), tb, 0, stream>>>(W2, W2T, ECc, Cc);

  prep_ln_kernel<<<BSc + BS2c, 256, 0, stream>>>(fwd, bwd, ln1g, ln1b, comb, cx, ae);

  // Q = cx @ WqT^T  (split-K=4 -> 512 blocks)
  gemm_kernel<EPI_PART, 4><<<dim3(Cc / 128, BSc / 128, 4), 512, 0, stream>>>(
      cx, WqT, nullptr, nullptr, nullptr, nullptr, nullptr, pbuf, BSc, Cc, Cc);
  reduce_kernel<EPI_Q, 4><<<(BSc * Cc / 4) / 256, 256, 0, stream>>>(
      pbuf, bq, pos, nullptr, qbuf, nullptr, BSc, Cc);

  // K,V fused (N=2048, 512 blocks)
  gemm_kernel<EPI_KV, 1><<<dim3(2 * Cc / 128, BS2c / 128, 1), 512, 0, stream>>>(
      ae, WkvT, bk, bv, pos, kbuf, vTb, nullptr, BS2c, 2 * Cc, Cc);

  // fused attention (both halves per block; writes normalized bf16 obuf directly)
  attn_kernel<<<dim3(Bc * Hc, Sc / 64), 256, 0, stream>>>(qbuf, kbuf, vTb, obuf);

  // x = comb + (o @ WoT^T + bo)  (split-K=4)
  gemm_kernel<EPI_PART, 4><<<dim3(Cc / 128, BSc / 128, 4), 512, 0, stream>>>(
      obuf, WoT, nullptr, nullptr, nullptr, nullptr, nullptr, pbuf, BSc, Cc, Cc);
  reduce_kernel<EPI_O, 4><<<(BSc * Cc / 4) / 256, 256, 0, stream>>>(
      pbuf, bo, nullptr, comb, nullptr, xbuf, BSc, Cc);

  ln2_kernel<<<BSc, 256, 0, stream>>>(xbuf, ln2g, ln2b, mlpg, mlpb, hb);

  // mid = gelu(h @ W1T^T + b1)  (512 blocks)
  gemm_kernel<EPI_GELU, 1><<<dim3(ECc / 128, BSc / 128, 1), 512, 0, stream>>>(
      hb, W1T, b1, nullptr, nullptr, midb, nullptr, nullptr, BSc, ECc, Cc);

  // out = x + (mid @ W2T^T + b2)  (split-K=4 over K=4096 -> 512 blocks)
  gemm_kernel<EPI_PART, 4><<<dim3(Cc / 128, BSc / 128, 4), 512, 0, stream>>>(
      midb, W2T, nullptr, nullptr, nullptr, nullptr, nullptr, pbuf, BSc, Cc, ECc);
  reduce_kernel<EPI_FINAL, 4><<<(BSc * Cc / 4) / 256, 256, 0, stream>>>(
      pbuf, b2, nullptr, xbuf, nullptr, (float*)d_out, BSc, Cc);
}

// Round 8
// 321.647 us; speedup vs baseline: 1.1277x; 1.0010x over previous
//
#include <hip/hip_runtime.h>
#include <hip/hip_bf16.h>
#include <cstdint>

#define DI __device__ __forceinline__

typedef unsigned short u16;
typedef __bf16 bf16x8 __attribute__((ext_vector_type(8)));
typedef float f32x4 __attribute__((ext_vector_type(4)));

constexpr int Bc  = 2;
constexpr int Sc  = 1024;
constexpr int Cc  = 1024;
constexpr int Hc  = 16;
constexpr int HDc = 64;
constexpr int S2c = 2048;
constexpr int ECc = 4096;
constexpr int BSc  = Bc * Sc;   // 2048
constexpr int BS2c = Bc * S2c;  // 4096

constexpr int EPI_KV = 0, EPI_Q = 1, EPI_GELU = 4, EPI_FINAL = 5, EPI_PART = 6;

DI u16 f2b(float f) {
  __hip_bfloat16 h = __float2bfloat16(f);
  u16 u;
  __builtin_memcpy(&u, &h, 2);
  return u;
}

// fast bf16 pack (round-half-up); fine for p in [0,1]
DI u16 f2b_fast(float f) {
  uint32_t u;
  __builtin_memcpy(&u, &f, 4);
  return (u16)((u + 0x8000u) >> 16);
}

// CK-style direct global->LDS (16B per lane; LDS dest = wave-uniform base + lane*16)
DI void glds16(const void* g, void* l) {
  auto* lp = reinterpret_cast<__attribute__((address_space(3))) uint32_t*>(
      reinterpret_cast<uintptr_t>(l));
  __builtin_amdgcn_global_load_lds(
      reinterpret_cast<const __attribute__((address_space(1))) uint32_t*>(
          reinterpret_cast<uintptr_t>(g)),
      lp, 16, 0, 0);
}

DI f32x4 mfma16(bf16x8 a, bf16x8 b, f32x4 c) {
  return __builtin_amdgcn_mfma_f32_16x16x32_bf16(a, b, c, 0, 0, 0);
}

// counted vmcnt wait + scheduling fence (rule #18: pin code motion around inline-asm waits)
#define PIPE_WAIT(N)                                            \
  do {                                                          \
    asm volatile("s_waitcnt vmcnt(" #N ")" ::: "memory");       \
    __builtin_amdgcn_sched_barrier(0);                          \
  } while (0)
#define PIPE_BAR()                                              \
  do {                                                          \
    __builtin_amdgcn_s_barrier();                               \
    __builtin_amdgcn_sched_barrier(0);                          \
  } while (0)

// ------------- fused transpose of the four CxC weights: WT[n][k] = W[k][n] -------------
__global__ __launch_bounds__(256) void transpose4_kernel(const float* __restrict__ Wq,
                                                         const float* __restrict__ Wk,
                                                         const float* __restrict__ Wv,
                                                         const float* __restrict__ Wo,
                                                         u16* __restrict__ WqT,
                                                         u16* __restrict__ WkvT,
                                                         u16* __restrict__ WoT) {
  __shared__ float tile[32][33];
  const int z = blockIdx.z;
  const float* W = (z == 0) ? Wq : (z == 1) ? Wk : (z == 2) ? Wv : Wo;
  u16* WT = (z == 0) ? WqT : (z == 1) ? WkvT : (z == 2) ? (WkvT + (size_t)Cc * Cc) : WoT;
  const int bx = blockIdx.x, by = blockIdx.y;
  const int tx = threadIdx.x, ty = threadIdx.y;
  const int c = bx * 32 + tx;
#pragma unroll
  for (int i = ty; i < 32; i += 8) tile[i][tx] = W[(size_t)(by * 32 + i) * Cc + c];
  __syncthreads();
#pragma unroll
  for (int i = ty; i < 32; i += 8)
    WT[(size_t)(bx * 32 + i) * Cc + by * 32 + tx] = f2b(tile[tx][i]);
}

// ---------------- transpose + fp32->bf16 convert: WT[n][k] = W[k][n] ----------------
__global__ __launch_bounds__(256) void transpose_kernel(const float* __restrict__ W,
                                                        u16* __restrict__ WT, int R, int Cn) {
  __shared__ float tile[32][33];
  const int bx = blockIdx.x, by = blockIdx.y;
  const int tx = threadIdx.x, ty = threadIdx.y;
  const int c = bx * 32 + tx;
#pragma unroll
  for (int i = ty; i < 32; i += 8) tile[i][tx] = W[(size_t)(by * 32 + i) * Cn + c];
  __syncthreads();
#pragma unroll
  for (int i = ty; i < 32; i += 8)
    WT[(size_t)(bx * 32 + i) * R + by * 32 + tx] = f2b(tile[tx][i]);
}

// ---------------- prep: comb + LN(comb)->cx ; LN(all_embed)->ae ----------------
__global__ __launch_bounds__(256) void prep_ln_kernel(
    const float* __restrict__ fwd, const float* __restrict__ bwd, const float* __restrict__ g,
    const float* __restrict__ be, float* __restrict__ comb, u16* __restrict__ cx,
    u16* __restrict__ ae) {
  __shared__ float red[2][4];
  const int row = blockIdx.x, tid = threadIdx.x;
  const int c = tid * 4;
  float4 x;
  u16* dst;
  if (row < BSc) {
    const int b = row >> 10, s = row & (Sc - 1);
    const float4 f = *(const float4*)(fwd + ((size_t)(b * (Sc + 1) + s)) * Cc + c);
    const float4 r = *(const float4*)(bwd + ((size_t)(b * (Sc + 1) + s + 1)) * Cc + c);
    const float k = 0.70710678118654752f;
    x.x = (f.x + r.x) * k; x.y = (f.y + r.y) * k;
    x.z = (f.z + r.z) * k; x.w = (f.w + r.w) * k;
    *(float4*)(comb + (size_t)row * Cc + c) = x;
    dst = cx + (size_t)row * Cc;
  } else {
    const int idx = row - BSc;
    const int b = idx >> 11, t = idx & (S2c - 1);
    const float* src = (t < Sc) ? (fwd + ((size_t)(b * (Sc + 1) + t)) * Cc)
                                : (bwd + ((size_t)(b * (Sc + 1) + (t - Sc) + 1)) * Cc);
    x = *(const float4*)(src + c);
    dst = ae + (size_t)idx * Cc;
  }
  float s1 = x.x + x.y + x.z + x.w;
  float s2 = x.x * x.x + x.y * x.y + x.z * x.z + x.w * x.w;
  for (int off = 32; off; off >>= 1) { s1 += __shfl_down(s1, off); s2 += __shfl_down(s2, off); }
  if ((tid & 63) == 0) { red[0][tid >> 6] = s1; red[1][tid >> 6] = s2; }
  __syncthreads();
  s1 = red[0][0] + red[0][1] + red[0][2] + red[0][3];
  s2 = red[1][0] + red[1][1] + red[1][2] + red[1][3];
  const float mean = s1 * (1.0f / Cc);
  const float rstd = rsqrtf(s2 * (1.0f / Cc) - mean * mean + 1e-5f);
  const float4 gv = *(const float4*)(g + c);
  const float4 bv = *(const float4*)(be + c);
  ushort4 o;
  o.x = f2b((x.x - mean) * rstd * gv.x + bv.x);
  o.y = f2b((x.y - mean) * rstd * gv.y + bv.y);
  o.z = f2b((x.z - mean) * rstd * gv.z + bv.z);
  o.w = f2b((x.w - mean) * rstd * gv.w + bv.w);
  *(ushort4*)(dst + c) = o;
}

// ------- fused split-K reduce (O projection) + residual + double LN -> hb -------
// Replaces reduce_kernel<EPI_O> + ln2_kernel: one block per row; computes
// x = sum_z pbuf + bo + comb (written to xbuf for the final residual), then
// h = LN(LN(x,g2,b2),gm,bm) in-register -> hb. Saves the 8.4 MB xbuf re-read
// and one dispatch.
__global__ __launch_bounds__(256) void reduceO_ln2_kernel(
    const float* __restrict__ pbuf, const float* __restrict__ bo,
    const float* __restrict__ comb, const float* __restrict__ g2,
    const float* __restrict__ b2, const float* __restrict__ gm,
    const float* __restrict__ bm, float* __restrict__ xbuf, u16* __restrict__ hb) {
  __shared__ float red[2][4];
  const int row = blockIdx.x, tid = threadIdx.x;
  const int c = tid * 4;
  constexpr size_t MN = (size_t)BSc * Cc;
  const size_t flat = (size_t)row * Cc + c;
  float4 s = *(const float4*)(pbuf + flat);
#pragma unroll
  for (int z = 1; z < 4; z++) {
    const float4 v = *(const float4*)(pbuf + z * MN + flat);
    s.x += v.x; s.y += v.y; s.z += v.z; s.w += v.w;
  }
  const float4 bv = *(const float4*)(bo + c);
  const float4 cv = *(const float4*)(comb + flat);
  s.x += bv.x + cv.x; s.y += bv.y + cv.y; s.z += bv.z + cv.z; s.w += bv.w + cv.w;
  *(float4*)(xbuf + flat) = s;
  float s1 = s.x + s.y + s.z + s.w;
  float s2 = s.x * s.x + s.y * s.y + s.z * s.z + s.w * s.w;
  for (int off = 32; off; off >>= 1) { s1 += __shfl_down(s1, off); s2 += __shfl_down(s2, off); }
  if ((tid & 63) == 0) { red[0][tid >> 6] = s1; red[1][tid >> 6] = s2; }
  __syncthreads();
  s1 = red[0][0] + red[0][1] + red[0][2] + red[0][3];
  s2 = red[1][0] + red[1][1] + red[1][2] + red[1][3];
  float mean = s1 * (1.0f / Cc);
  float rstd = rsqrtf(s2 * (1.0f / Cc) - mean * mean + 1e-5f);
  const float4 ga = *(const float4*)(g2 + c);
  const float4 ba = *(const float4*)(b2 + c);
  const float t0 = (s.x - mean) * rstd * ga.x + ba.x;
  const float t1 = (s.y - mean) * rstd * ga.y + ba.y;
  const float t2 = (s.z - mean) * rstd * ga.z + ba.z;
  const float t3 = (s.w - mean) * rstd * ga.w + ba.w;
  s1 = t0 + t1 + t2 + t3;
  s2 = t0 * t0 + t1 * t1 + t2 * t2 + t3 * t3;
  for (int off = 32; off; off >>= 1) { s1 += __shfl_down(s1, off); s2 += __shfl_down(s2, off); }
  __syncthreads();
  if ((tid & 63) == 0) { red[0][tid >> 6] = s1; red[1][tid >> 6] = s2; }
  __syncthreads();
  s1 = red[0][0] + red[0][1] + red[0][2] + red[0][3];
  s2 = red[1][0] + red[1][1] + red[1][2] + red[1][3];
  mean = s1 * (1.0f / Cc);
  rstd = rsqrtf(s2 * (1.0f / Cc) - mean * mean + 1e-5f);
  const float4 gb = *(const float4*)(gm + c);
  const float4 bb = *(const float4*)(bm + c);
  ushort4 o;
  o.x = f2b((t0 - mean) * rstd * gb.x + bb.x);
  o.y = f2b((t1 - mean) * rstd * gb.y + bb.y);
  o.z = f2b((t2 - mean) * rstd * gb.z + bb.z);
  o.w = f2b((t3 - mean) * rstd * gb.w + bb.w);
  *(ushort4*)(hb + flat) = o;
}

// ---------------- GEMM: Y = A(MxK) @ BT(NxK)^T, fused epilogues ----------------
// 128x128 tile, BK=32, glds16 staging, T4 counted-vmcnt 4-buffer pipeline
// (alias-clean distinct LDS objects; raw s_barrier; never vmcnt(0) in steady
// state — verified R3; 512-thread step verified R7).
// R17: 16 waves (1024 threads), wave = 32x32 quadrant (acc[2][2], 4 MFMA/step).
// Extends the thrice-proven waves/SIMD lever: 512 blocks = 2 blocks/CU, so
// 1024-thread blocks give 32 waves/CU = 8 waves/SIMD (hardware max) if
// VGPR <= 64 (acc 16 + frags 16 + addr ~25). Fallback if VGPR in 65..128:
// 1 block/CU = 16 waves/CU = exactly R7's occupancy (bounded downside).
// Staging: lanes 0..511 stage the A tile, lanes 512..1023 the B tile ->
// exactly 1 glds16 per lane per tile; every wave issues 1 load per STAGE, so
// steady-state wait = vmcnt(2) (1 load x 2 tiles in flight); tails 1, 0.
template <int EPI, int SK>
__global__ __launch_bounds__(1024) void gemm_kernel(
    const u16* __restrict__ A, const u16* __restrict__ BT, const float* __restrict__ bias,
    const float* __restrict__ bias2, const float* __restrict__ pos,
    u16* __restrict__ outb, u16* __restrict__ out2, float* __restrict__ pbuf,
    int M, int N, int K) {
  __shared__ u16 A0s[128 * 32], A1s[128 * 32], A2s[128 * 32], A3s[128 * 32];
  __shared__ u16 B0s[128 * 32], B1s[128 * 32], B2s[128 * 32], B3s[128 * 32];
  const int tid = threadIdx.x;
  const int w = tid >> 6, lane = tid & 63, quad = lane >> 4, r16 = lane & 15;
  const int bm = blockIdx.y * 128, bn = blockIdx.x * 128;
  const int wm = ((w >> 2) & 3) * 32, wn = (w & 3) * 32;  // 4x4 waves of 32x32
  const int Ks = K / SK, kb0 = blockIdx.z * Ks;

  // staging split: lanes 0..511 -> A tile rows, lanes 512..1023 -> B tile rows
  const bool isB = (tid >= 512);
  const int t2 = tid & 511;
  const int srow = t2 >> 2, scol = (t2 & 3) * 8;  // 512 lanes cover 128 rows x 32 cols
  const u16* gP =
      (isB ? BT + (size_t)(bn + srow) * K : A + (size_t)(bm + srow) * K) + kb0 + scol;
  const int stg = ((w & 7) * 16) * 32;  // wave-uniform LDS stage base (u16 offset)

  f32x4 acc[2][2] = {};

  auto STAGE = [&](u16* Ad, u16* Bd, int t) {
    glds16(gP + t * 32, (isB ? Bd : Ad) + stg);
  };
  auto COMPUTE = [&](const u16* As, const u16* Bs) {
    bf16x8 af[2], bfr[2];
#pragma unroll
    for (int i = 0; i < 2; i++) {
      af[i] = *reinterpret_cast<const bf16x8*>(&As[(wm + i * 16 + r16) * 32 + quad * 8]);
      bfr[i] = *reinterpret_cast<const bf16x8*>(&Bs[(wn + i * 16 + r16) * 32 + quad * 8]);
    }
#pragma unroll
    for (int mi = 0; mi < 2; mi++)
#pragma unroll
      for (int ni = 0; ni < 2; ni++) acc[mi][ni] = mfma16(af[mi], bfr[ni], acc[mi][ni]);
  };

  const int NT = Ks / 32;  // 8 or 32; divisible by 4
  STAGE(A0s, B0s, 0);
  STAGE(A1s, B1s, 1);
  for (int t = 0; t < NT; t += 4) {
    if (t + 2 < NT) { STAGE(A2s, B2s, t + 2); PIPE_WAIT(2); }
    else if (t + 1 < NT) PIPE_WAIT(1);
    else PIPE_WAIT(0);
    PIPE_BAR();
    COMPUTE(A0s, B0s);
    if (t + 3 < NT) { STAGE(A3s, B3s, t + 3); PIPE_WAIT(2); }
    else if (t + 2 < NT) PIPE_WAIT(1);
    else PIPE_WAIT(0);
    PIPE_BAR();
    COMPUTE(A1s, B1s);
    if (t + 4 < NT) { STAGE(A0s, B0s, t + 4); PIPE_WAIT(2); }
    else if (t + 3 < NT) PIPE_WAIT(1);
    else PIPE_WAIT(0);
    PIPE_BAR();
    COMPUTE(A2s, B2s);
    if (t + 5 < NT) { STAGE(A1s, B1s, t + 5); PIPE_WAIT(2); }
    else if (t + 4 < NT) PIPE_WAIT(1);
    else PIPE_WAIT(0);
    PIPE_BAR();
    COMPUTE(A3s, B3s);
  }

#pragma unroll
  for (int mi = 0; mi < 2; mi++) {
#pragma unroll
    for (int ni = 0; ni < 2; ni++) {
      const int col = bn + wn + ni * 16 + r16;
      const int row0 = bm + wm + mi * 16 + quad * 4;
      if constexpr (EPI == EPI_PART) {
        float* pb = pbuf + (size_t)blockIdx.z * M * N;
#pragma unroll
        for (int r = 0; r < 4; r++) pb[(size_t)(row0 + r) * N + col] = acc[mi][ni][r];
      } else if constexpr (EPI == EPI_KV) {
        if (col < Cc) {
#pragma unroll
          for (int r = 0; r < 4; r++) {
            const int row = row0 + r;
            const int key = row & (S2c - 1);
            const float y =
                acc[mi][ni][r] + bias[col] + pos[(key & (Sc - 1)) * HDc + (col & 63)];
            outb[(size_t)row * Cc + col] = f2b(y);
          }
        } else {
          const int c2 = col - Cc;
          const int h = c2 >> 6, d = c2 & 63;
          const int b = row0 >> 11, key0 = row0 & (S2c - 1);
          const float bb = bias2[c2];
          ushort4 pk;
          pk.x = f2b(acc[mi][ni][0] + bb);
          pk.y = f2b(acc[mi][ni][1] + bb);
          pk.z = f2b(acc[mi][ni][2] + bb);
          pk.w = f2b(acc[mi][ni][3] + bb);
          *(ushort4*)&out2[(((size_t)(b * Hc + h) * HDc + d) << 11) + key0] = pk;
        }
      } else {  // EPI_GELU
#pragma unroll
        for (int r = 0; r < 4; r++) {
          const float y = acc[mi][ni][r] + bias[col];
          outb[(size_t)(row0 + r) * N + col] =
              f2b(0.5f * y * (1.0f + erff(y * 0.70710678118654752f)));
        }
      }
    }
  }
}

// ---------------- split-K reduce + epilogue (SK slices of MxN f32) ----------------
// EPI_Q: out = bf16((sum + bias + pos) * scale) ; EPI_FINAL: out = f32(sum + bias + add)
template <int EPI, int SK>
__global__ __launch_bounds__(256) void reduce_kernel(const float* __restrict__ pbuf,
                                                     const float* __restrict__ bias,
                                                     const float* __restrict__ pos,
                                                     const float* __restrict__ addsrc,
                                                     u16* __restrict__ outb,
                                                     float* __restrict__ outf, int M, int N) {
  const size_t flat = ((size_t)blockIdx.x * 256 + threadIdx.x) * 4;
  const int row = (int)(flat / N), col = (int)(flat % N);
  const size_t MN = (size_t)M * N;
  float4 s = *(const float4*)(pbuf + flat);
#pragma unroll
  for (int z = 1; z < SK; z++) {
    const float4 v = *(const float4*)(pbuf + z * MN + flat);
    s.x += v.x; s.y += v.y; s.z += v.z; s.w += v.w;
  }
  const float4 bv = *(const float4*)(bias + col);
  s.x += bv.x; s.y += bv.y; s.z += bv.z; s.w += bv.w;
  if constexpr (EPI == EPI_Q) {
    const int sq = row & (Sc - 1), d = col & 63;
    const float4 pv = *(const float4*)(pos + sq * HDc + d);
    constexpr float sc = 0.180336880111120426f;  // (1/8)*log2(e)
    ushort4 o;
    o.x = f2b((s.x + pv.x) * sc);
    o.y = f2b((s.y + pv.y) * sc);
    o.z = f2b((s.z + pv.z) * sc);
    o.w = f2b((s.w + pv.w) * sc);
    *(ushort4*)(outb + flat) = o;
  } else {
    const float4 av = *(const float4*)(addsrc + flat);
    float4 o;
    o.x = s.x + av.x; o.y = s.y + av.y; o.z = s.z + av.z; o.w = s.w + av.w;
    *(float4*)(outf + flat) = o;
  }
}

// ---------------- fused attention: grid (bh, qt) ----------------
// R13 (kept, verified R4): both halves in one block -> uniform 17 units/block;
// T4 counted-vmcnt pipeline (4 distinct K + 4 distinct V buffers, raw
// s_barrier, vmcnt(8) = 4 loads/unit x 2 units in flight); o/l accumulated
// in-register across both halves; normalized bf16 output written directly.
// Unit p: p<=qt -> keys p*64.. (f-half; mask key>qrow at p==qt);
//         p>qt  -> keys Sc+(p-1)*64.. (r-half; mask key-Sc<qrow at p==qt+1).
// qb: [b,q,h,d] bf16 (pre-scaled by (1/8)*log2e); kb: [b,key(2S),h,d];
// vT: [b,h,d,key(2S)]; ob: [b,q,h,d] bf16.
__global__ __launch_bounds__(256) void attn_kernel(const u16* __restrict__ qb,
                                                   const u16* __restrict__ kb,
                                                   const u16* __restrict__ vT,
                                                   u16* __restrict__ ob) {
  const int bh = blockIdx.x;
  const int qt = blockIdx.y;
  const int b = bh >> 4, head = bh & 15;
  const int tid = threadIdx.x;
  const int w = tid >> 6, lane = tid & 63, quad = lane >> 4, r16 = lane & 15;

  // per-unit K tile: [ks(2)][64 keys][32 d] (64-B rows); V tile: [ks][64 d][32 keys]
  __shared__ u16 K0s[4096], K1s[4096], K2s[4096], K3s[4096];
  __shared__ u16 V0s[4096], V1s[4096], V2s[4096], V3s[4096];
  __shared__ u16 Ps[4][16 * 68];  // per-wave P round-trip (stride 68: conflict-free)
  u16* ps = Ps[w];

  const int qw = qt * 64 + w * 16;  // this wave's 16 queries

  bf16x8 aq[2];
  {
    const u16* qp = qb + ((size_t)((b * Sc + qw + r16) * Hc + head)) * HDc + quad * 8;
    aq[0] = *(const bf16x8*)qp;
    aq[1] = *(const bf16x8*)(qp + 32);
  }

  const size_t krow = (size_t)Hc * HDc;
  const u16* kbase = kb + ((size_t)b * S2c * Hc + head) * HDc;
  const u16* vbase = vT + ((size_t)(b * Hc + head)) * HDc * S2c;

  // cooperative staging map: wave w covers rows w*16 + lane/4, 16 B at (lane&3)*8
  const int srow = w * 16 + (lane >> 2);
  const int scol = (lane & 3) * 8;
  const int stg = w * 16 * 32;  // wave-uniform LDS stage base (u16 offset)
  const u16* kS = kbase + (size_t)srow * krow + scol;   // + key0*krow (+32 for ks=1)
  const u16* vS = vbase + (size_t)srow * S2c + scol;    // + key0     (+32 for ks=1)

  f32x4 o_acc[4] = {};
  float lsum[4] = {};

  auto K0OF = [&](int p) -> int { return (p <= qt) ? p * 64 : Sc + (p - 1) * 64; };

  auto STAGE = [&](u16* Kd, u16* Vd, int p) {
    const int k0 = K0OF(p);
    glds16(kS + (size_t)k0 * krow, Kd + stg);
    glds16(kS + (size_t)k0 * krow + 32, Kd + 2048 + stg);
    glds16(vS + k0, Vd + stg);
    glds16(vS + k0 + 32, Vd + 2048 + stg);
  };

  auto COMPUTE = [&](const u16* Kc, const u16* Vc, int p) {
    const int k0 = K0OF(p);
    // QK^T from LDS
    f32x4 sacc[4] = {};
#pragma unroll
    for (int ks = 0; ks < 2; ks++)
#pragma unroll
      for (int ni = 0; ni < 4; ni++) {
        const bf16x8 bk = *(const bf16x8*)&Kc[ks * 2048 + (ni * 16 + r16) * 32 + quad * 8];
        sacc[ni] = mfma16(aq[ks], bk, sacc[ni]);
      }
    const int mode = (p == qt) ? 1 : ((p == qt + 1) ? 2 : 0);
#pragma unroll
    for (int r = 0; r < 4; r++) {
      const int qrow = qw + quad * 4 + r;
#pragma unroll
      for (int ni = 0; ni < 4; ni++) {
        float s = sacc[ni][r];
        if (mode == 1) { const int key = k0 + ni * 16 + r16; if (key > qrow) s = -128.0f; }
        else if (mode == 2) { const int key = k0 - Sc + ni * 16 + r16; if (key < qrow) s = -128.0f; }
        const float pe = __builtin_amdgcn_exp2f(s);
        lsum[r] += pe;
        ps[(quad * 4 + r) * 68 + ni * 16 + r16] = f2b_fast(pe);
      }
    }
    // PV from LDS (Ps is wave-private: lgkm ordering only, no barrier needed)
#pragma unroll
    for (int ks = 0; ks < 2; ks++) {
      const bf16x8 ap = *(const bf16x8*)(&ps[r16 * 68 + ks * 32 + quad * 8]);
#pragma unroll
      for (int ni = 0; ni < 4; ni++) {
        const bf16x8 bv_ = *(const bf16x8*)&Vc[ks * 2048 + (ni * 16 + r16) * 32 + quad * 8];
        o_acc[ni] = mfma16(ap, bv_, o_acc[ni]);
      }
    }
  };

  constexpr int NU = 17;  // (qt+1) + (16-qt), uniform for all blocks
  STAGE(K0s, V0s, 0);
  STAGE(K1s, V1s, 1);
  for (int t = 0; t < NU; t += 4) {
    {
      if (t + 2 < NU) { STAGE(K2s, V2s, t + 2); PIPE_WAIT(8); }
      else if (t + 1 < NU) PIPE_WAIT(4);
      else PIPE_WAIT(0);
      PIPE_BAR();
      COMPUTE(K0s, V0s, t);
    }
    if (t + 1 < NU) {
      if (t + 3 < NU) { STAGE(K3s, V3s, t + 3); PIPE_WAIT(8); }
      else if (t + 2 < NU) PIPE_WAIT(4);
      else PIPE_WAIT(0);
      PIPE_BAR();
      COMPUTE(K1s, V1s, t + 1);
    }
    if (t + 2 < NU) {
      if (t + 4 < NU) { STAGE(K0s, V0s, t + 4); PIPE_WAIT(8); }
      else if (t + 3 < NU) PIPE_WAIT(4);
      else PIPE_WAIT(0);
      PIPE_BAR();
      COMPUTE(K2s, V2s, t + 2);
    }
    if (t + 3 < NU) {
      if (t + 5 < NU) { STAGE(K1s, V1s, t + 5); PIPE_WAIT(8); }
      else if (t + 4 < NU) PIPE_WAIT(4);
      else PIPE_WAIT(0);
      PIPE_BAR();
      COMPUTE(K3s, V3s, t + 3);
    }
  }

  // normalize in-register and write bf16 [b,q,h,d] directly
#pragma unroll
  for (int r = 0; r < 4; r++) {
    float l = lsum[r];
    l += __shfl_xor(l, 1);
    l += __shfl_xor(l, 2);
    l += __shfl_xor(l, 4);
    l += __shfl_xor(l, 8);
    lsum[r] = 1.0f / l;
  }
#pragma unroll
  for (int r = 0; r < 4; r++) {
    u16* od = ob + ((size_t)((b * Sc + qw + quad * 4 + r) * Hc + head)) * HDc;
#pragma unroll
    for (int ni = 0; ni < 4; ni++) od[ni * 16 + r16] = f2b(o_acc[ni][r] * lsum[r]);
  }
}

extern "C" void kernel_launch(void* const* d_in, const int* in_sizes, int n_in, void* d_out,
                              int out_size, void* d_ws, size_t ws_size, hipStream_t stream) {
  const float* fwd = (const float*)d_in[0];
  const float* bwd = (const float*)d_in[1];
  const float* pos = (const float*)d_in[2];
  const float* ln1g = (const float*)d_in[3];
  const float* ln1b = (const float*)d_in[4];
  const float* Wq = (const float*)d_in[5];
  const float* bq = (const float*)d_in[6];
  const float* Wk = (const float*)d_in[7];
  const float* bk = (const float*)d_in[8];
  const float* Wv = (const float*)d_in[9];
  const float* bv = (const float*)d_in[10];
  const float* Wo = (const float*)d_in[11];
  const float* bo = (const float*)d_in[12];
  const float* ln2g = (const float*)d_in[13];
  const float* ln2b = (const float*)d_in[14];
  const float* mlpg = (const float*)d_in[15];
  const float* mlpb = (const float*)d_in[16];
  const float* W1 = (const float*)d_in[17];
  const float* b1 = (const float*)d_in[18];
  const float* W2 = (const float*)d_in[19];
  const float* b2 = (const float*)d_in[20];

  char* p = (char*)d_ws;
  auto alloc = [&](size_t bytes) -> char* {
    char* r = p;
    p += (bytes + 255) & ~(size_t)255;
    return r;
  };
  float* comb = (float*)alloc((size_t)BSc * Cc * 4);
  float* xbuf = (float*)alloc((size_t)BSc * Cc * 4);
  u16* cx = (u16*)alloc((size_t)BSc * Cc * 2);
  u16* ae = (u16*)alloc((size_t)BS2c * Cc * 2);
  u16* qbuf = (u16*)alloc((size_t)BSc * Cc * 2);
  u16* kbuf = (u16*)alloc((size_t)BS2c * Cc * 2);
  u16* vTb = (u16*)alloc((size_t)BS2c * Cc * 2);
  u16* obuf = (u16*)alloc((size_t)BSc * Cc * 2);
  u16* hb = (u16*)alloc((size_t)BSc * Cc * 2);
  u16* midb = (u16*)alloc((size_t)BSc * ECc * 2);
  float* pbuf = (float*)alloc((size_t)4 * BSc * Cc * 4);  // 4 split-K slices of 2048x1024 f32
  u16* WqT = (u16*)alloc((size_t)Cc * Cc * 2);
  u16* WkvT = (u16*)alloc((size_t)2 * Cc * Cc * 2);
  u16* WoT = (u16*)alloc((size_t)Cc * Cc * 2);
  u16* W1T = (u16*)alloc((size_t)ECc * Cc * 2);
  u16* W2T = (u16*)alloc((size_t)Cc * ECc * 2);

  const dim3 tb(32, 8);
  transpose4_kernel<<<dim3(32, 32, 4), tb, 0, stream>>>(Wq, Wk, Wv, Wo, WqT, WkvT, WoT);
  transpose_kernel<<<dim3(128, 32), tb, 0, stream>>>(W1, W1T, Cc, ECc);
  transpose_kernel<<<dim3(32, 128), tb, 0, stream>>>(W2, W2T, ECc, Cc);

  prep_ln_kernel<<<BSc + BS2c, 256, 0, stream>>>(fwd, bwd, ln1g, ln1b, comb, cx, ae);

  // Q = cx @ WqT^T  (split-K=4 -> 512 blocks)
  gemm_kernel<EPI_PART, 4><<<dim3(Cc / 128, BSc / 128, 4), 1024, 0, stream>>>(
      cx, WqT, nullptr, nullptr, nullptr, nullptr, nullptr, pbuf, BSc, Cc, Cc);
  reduce_kernel<EPI_Q, 4><<<(BSc * Cc / 4) / 256, 256, 0, stream>>>(
      pbuf, bq, pos, nullptr, qbuf, nullptr, BSc, Cc);

  // K,V fused (N=2048, 512 blocks)
  gemm_kernel<EPI_KV, 1><<<dim3(2 * Cc / 128, BS2c / 128, 1), 1024, 0, stream>>>(
      ae, WkvT, bk, bv, pos, kbuf, vTb, nullptr, BS2c, 2 * Cc, Cc);

  // fused attention (both halves per block; writes normalized bf16 obuf directly)
  attn_kernel<<<dim3(Bc * Hc, Sc / 64), 256, 0, stream>>>(qbuf, kbuf, vTb, obuf);

  // x = comb + (o @ WoT^T + bo)  (split-K=4), then fused residual + double-LN
  gemm_kernel<EPI_PART, 4><<<dim3(Cc / 128, BSc / 128, 4), 1024, 0, stream>>>(
      obuf, WoT, nullptr, nullptr, nullptr, nullptr, nullptr, pbuf, BSc, Cc, Cc);
  reduceO_ln2_kernel<<<BSc, 256, 0, stream>>>(pbuf, bo, comb, ln2g, ln2b, mlpg, mlpb,
                                              xbuf, hb);

  // mid = gelu(h @ W1T^T + b1)  (512 blocks)
  gemm_kernel<EPI_GELU, 1><<<dim3(ECc / 128, BSc / 128, 1), 1024, 0, stream>>>(
      hb, W1T, b1, nullptr, nullptr, midb, nullptr, nullptr, BSc, ECc, Cc);

  // out = x + (mid @ W2T^T + b2)  (split-K=4 over K=4096 -> 512 blocks)
  gemm_kernel<EPI_PART, 4><<<dim3(Cc / 128, BSc / 128, 4), 1024, 0, stream>>>(
      midb, W2T, nullptr, nullptr, nullptr, nullptr, nullptr, pbuf, BSc, Cc, ECc);
  reduce_kernel<EPI_FINAL, 4><<<(BSc * Cc / 4) / 256, 256, 0, stream>>>(
      pbuf, b2, nullptr, xbuf, nullptr, (float*)d_out, BSc, Cc);
}

// Round 9
// 307.639 us; speedup vs baseline: 1.1790x; 1.0455x over previous
//
#include <hip/hip_runtime.h>
#include <hip/hip_bf16.h>
#include <cstdint>

#define DI __device__ __forceinline__

typedef unsigned short u16;
typedef __bf16 bf16x8 __attribute__((ext_vector_type(8)));
typedef float f32x4 __attribute__((ext_vector_type(4)));

constexpr int Bc  = 2;
constexpr int Sc  = 1024;
constexpr int Cc  = 1024;
constexpr int Hc  = 16;
constexpr int HDc = 64;
constexpr int S2c = 2048;
constexpr int ECc = 4096;
constexpr int BSc  = Bc * Sc;   // 2048
constexpr int BS2c = Bc * S2c;  // 4096

constexpr int EPI_KV = 0, EPI_Q = 1, EPI_O = 3, EPI_GELU = 4, EPI_FINAL = 5;

DI u16 f2b(float f) {
  __hip_bfloat16 h = __float2bfloat16(f);
  u16 u;
  __builtin_memcpy(&u, &h, 2);
  return u;
}

// fast bf16 pack (round-half-up); fine for p in [0,1]
DI u16 f2b_fast(float f) {
  uint32_t u;
  __builtin_memcpy(&u, &f, 4);
  return (u16)((u + 0x8000u) >> 16);
}

// CK-style direct global->LDS (16B per lane; LDS dest = wave-uniform base + lane*16)
DI void glds16(const void* g, void* l) {
  auto* lp = reinterpret_cast<__attribute__((address_space(3))) uint32_t*>(
      reinterpret_cast<uintptr_t>(l));
  __builtin_amdgcn_global_load_lds(
      reinterpret_cast<const __attribute__((address_space(1))) uint32_t*>(
          reinterpret_cast<uintptr_t>(g)),
      lp, 16, 0, 0);
}

DI f32x4 mfma16(bf16x8 a, bf16x8 b, f32x4 c) {
  return __builtin_amdgcn_mfma_f32_16x16x32_bf16(a, b, c, 0, 0, 0);
}

// counted vmcnt wait + scheduling fence (rule #18: pin code motion around inline-asm waits)
#define PIPE_WAIT(N)                                            \
  do {                                                          \
    asm volatile("s_waitcnt vmcnt(" #N ")" ::: "memory");       \
    __builtin_amdgcn_sched_barrier(0);                          \
  } while (0)
#define PIPE_BAR()                                              \
  do {                                                          \
    __builtin_amdgcn_s_barrier();                               \
    __builtin_amdgcn_sched_barrier(0);                          \
  } while (0)
#define LGKM_FENCE()                                            \
  do {                                                          \
    asm volatile("s_waitcnt lgkmcnt(0)" ::: "memory");          \
    __builtin_amdgcn_sched_barrier(0);                          \
  } while (0)

// ------------- fused transpose of the four CxC weights: WT[n][k] = W[k][n] -------------
__global__ __launch_bounds__(256) void transpose4_kernel(const float* __restrict__ Wq,
                                                         const float* __restrict__ Wk,
                                                         const float* __restrict__ Wv,
                                                         const float* __restrict__ Wo,
                                                         u16* __restrict__ WqT,
                                                         u16* __restrict__ WkvT,
                                                         u16* __restrict__ WoT) {
  __shared__ float tile[32][33];
  const int z = blockIdx.z;
  const float* W = (z == 0) ? Wq : (z == 1) ? Wk : (z == 2) ? Wv : Wo;
  u16* WT = (z == 0) ? WqT : (z == 1) ? WkvT : (z == 2) ? (WkvT + (size_t)Cc * Cc) : WoT;
  const int bx = blockIdx.x, by = blockIdx.y;
  const int tx = threadIdx.x, ty = threadIdx.y;
  const int c = bx * 32 + tx;
#pragma unroll
  for (int i = ty; i < 32; i += 8) tile[i][tx] = W[(size_t)(by * 32 + i) * Cc + c];
  __syncthreads();
#pragma unroll
  for (int i = ty; i < 32; i += 8)
    WT[(size_t)(bx * 32 + i) * Cc + by * 32 + tx] = f2b(tile[tx][i]);
}

// ---------------- transpose + fp32->bf16 convert: WT[n][k] = W[k][n] ----------------
__global__ __launch_bounds__(256) void transpose_kernel(const float* __restrict__ W,
                                                        u16* __restrict__ WT, int R, int Cn) {
  __shared__ float tile[32][33];
  const int bx = blockIdx.x, by = blockIdx.y;
  const int tx = threadIdx.x, ty = threadIdx.y;
  const int c = bx * 32 + tx;
#pragma unroll
  for (int i = ty; i < 32; i += 8) tile[i][tx] = W[(size_t)(by * 32 + i) * Cn + c];
  __syncthreads();
#pragma unroll
  for (int i = ty; i < 32; i += 8)
    WT[(size_t)(bx * 32 + i) * R + by * 32 + tx] = f2b(tile[tx][i]);
}

// ---------------- prep: comb + LN(comb)->cx ; LN(all_embed)->ae ----------------
__global__ __launch_bounds__(256) void prep_ln_kernel(
    const float* __restrict__ fwd, const float* __restrict__ bwd, const float* __restrict__ g,
    const float* __restrict__ be, float* __restrict__ comb, u16* __restrict__ cx,
    u16* __restrict__ ae) {
  __shared__ float red[2][4];
  const int row = blockIdx.x, tid = threadIdx.x;
  const int c = tid * 4;
  float4 x;
  u16* dst;
  if (row < BSc) {
    const int b = row >> 10, s = row & (Sc - 1);
    const float4 f = *(const float4*)(fwd + ((size_t)(b * (Sc + 1) + s)) * Cc + c);
    const float4 r = *(const float4*)(bwd + ((size_t)(b * (Sc + 1) + s + 1)) * Cc + c);
    const float k = 0.70710678118654752f;
    x.x = (f.x + r.x) * k; x.y = (f.y + r.y) * k;
    x.z = (f.z + r.z) * k; x.w = (f.w + r.w) * k;
    *(float4*)(comb + (size_t)row * Cc + c) = x;
    dst = cx + (size_t)row * Cc;
  } else {
    const int idx = row - BSc;
    const int b = idx >> 11, t = idx & (S2c - 1);
    const float* src = (t < Sc) ? (fwd + ((size_t)(b * (Sc + 1) + t)) * Cc)
                                : (bwd + ((size_t)(b * (Sc + 1) + (t - Sc) + 1)) * Cc);
    x = *(const float4*)(src + c);
    dst = ae + (size_t)idx * Cc;
  }
  float s1 = x.x + x.y + x.z + x.w;
  float s2 = x.x * x.x + x.y * x.y + x.z * x.z + x.w * x.w;
  for (int off = 32; off; off >>= 1) { s1 += __shfl_down(s1, off); s2 += __shfl_down(s2, off); }
  if ((tid & 63) == 0) { red[0][tid >> 6] = s1; red[1][tid >> 6] = s2; }
  __syncthreads();
  s1 = red[0][0] + red[0][1] + red[0][2] + red[0][3];
  s2 = red[1][0] + red[1][1] + red[1][2] + red[1][3];
  const float mean = s1 * (1.0f / Cc);
  const float rstd = rsqrtf(s2 * (1.0f / Cc) - mean * mean + 1e-5f);
  const float4 gv = *(const float4*)(g + c);
  const float4 bv = *(const float4*)(be + c);
  ushort4 o;
  o.x = f2b((x.x - mean) * rstd * gv.x + bv.x);
  o.y = f2b((x.y - mean) * rstd * gv.y + bv.y);
  o.z = f2b((x.z - mean) * rstd * gv.z + bv.z);
  o.w = f2b((x.w - mean) * rstd * gv.w + bv.w);
  *(ushort4*)(dst + c) = o;
}

// ---------------- double LN: h = LN(LN(x,g2,b2),gm,bm) ----------------
__global__ __launch_bounds__(256) void ln2_kernel(const float* __restrict__ x,
                                                  const float* __restrict__ g2,
                                                  const float* __restrict__ b2,
                                                  const float* __restrict__ gm,
                                                  const float* __restrict__ bm,
                                                  u16* __restrict__ h) {
  __shared__ float red[2][4];
  const int row = blockIdx.x, tid = threadIdx.x;
  const int c = tid * 4;
  const float4 v = *(const float4*)(x + (size_t)row * Cc + c);
  float s1 = v.x + v.y + v.z + v.w;
  float s2 = v.x * v.x + v.y * v.y + v.z * v.z + v.w * v.w;
  for (int off = 32; off; off >>= 1) { s1 += __shfl_down(s1, off); s2 += __shfl_down(s2, off); }
  if ((tid & 63) == 0) { red[0][tid >> 6] = s1; red[1][tid >> 6] = s2; }
  __syncthreads();
  s1 = red[0][0] + red[0][1] + red[0][2] + red[0][3];
  s2 = red[1][0] + red[1][1] + red[1][2] + red[1][3];
  float mean = s1 * (1.0f / Cc);
  float rstd = rsqrtf(s2 * (1.0f / Cc) - mean * mean + 1e-5f);
  const float4 ga = *(const float4*)(g2 + c);
  const float4 ba = *(const float4*)(b2 + c);
  const float t0 = (v.x - mean) * rstd * ga.x + ba.x;
  const float t1 = (v.y - mean) * rstd * ga.y + ba.y;
  const float t2 = (v.z - mean) * rstd * ga.z + ba.z;
  const float t3 = (v.w - mean) * rstd * ga.w + ba.w;
  s1 = t0 + t1 + t2 + t3;
  s2 = t0 * t0 + t1 * t1 + t2 * t2 + t3 * t3;
  for (int off = 32; off; off >>= 1) { s1 += __shfl_down(s1, off); s2 += __shfl_down(s2, off); }
  __syncthreads();
  if ((tid & 63) == 0) { red[0][tid >> 6] = s1; red[1][tid >> 6] = s2; }
  __syncthreads();
  s1 = red[0][0] + red[0][1] + red[0][2] + red[0][3];
  s2 = red[1][0] + red[1][1] + red[1][2] + red[1][3];
  mean = s1 * (1.0f / Cc);
  rstd = rsqrtf(s2 * (1.0f / Cc) - mean * mean + 1e-5f);
  const float4 gb = *(const float4*)(gm + c);
  const float4 bb = *(const float4*)(bm + c);
  ushort4 o;
  o.x = f2b((t0 - mean) * rstd * gb.x + bb.x);
  o.y = f2b((t1 - mean) * rstd * gb.y + bb.y);
  o.z = f2b((t2 - mean) * rstd * gb.z + bb.z);
  o.w = f2b((t3 - mean) * rstd * gb.w + bb.w);
  *(ushort4*)(h + (size_t)row * Cc + c) = o;
}

// ---------------- GEMM (wide-N): Y = A(MxK) @ BT(NxK)^T, fused epilogues ----------------
// 128x128 tile, BK=32, glds16 staging, T4 counted-vmcnt 4-buffer pipeline.
// R7-MEASURED-GOOD configuration (restored after the neutral R8 1024-thr trial):
// 8 waves (512 threads), wave = 64x32 quadrant (acc[4][2], 8 MFMA/step);
// staging 512 lanes x 16 B = one 8 KB half-tile per pass (1 A + 1 B load/lane);
// steady-state wait vmcnt(4) (2 loads x 2 tiles in flight); tails 2, 0.
// Used for KV (N=2048) and MLP1 (N=4096) only.
template <int EPI>
__global__ __launch_bounds__(512) void gemm_kernel(
    const u16* __restrict__ A, const u16* __restrict__ BT, const float* __restrict__ bias,
    const float* __restrict__ bias2, const float* __restrict__ pos,
    u16* __restrict__ outb, u16* __restrict__ out2, int M, int N, int K) {
  __shared__ u16 A0s[128 * 32], A1s[128 * 32], A2s[128 * 32], A3s[128 * 32];
  __shared__ u16 B0s[128 * 32], B1s[128 * 32], B2s[128 * 32], B3s[128 * 32];
  const int tid = threadIdx.x;
  const int w = tid >> 6, lane = tid & 63, quad = lane >> 4, r16 = lane & 15;
  const int bm = blockIdx.y * 128, bn = blockIdx.x * 128;
  const int wm = (w >> 2) * 64, wn = (w & 3) * 32;  // 2 M-waves x 4 N-waves

  const int srow = tid >> 2, scol = (tid & 3) * 8;  // 512 lanes cover 128 rows x 32 cols
  const u16* aP = A + (size_t)(bm + srow) * K + scol;
  const u16* bP = BT + (size_t)(bn + srow) * K + scol;
  const int stg = (w * 16) * 32;  // wave-uniform LDS stage base (u16 offset)

  f32x4 acc[4][2] = {};

  auto STAGE = [&](u16* Ad, u16* Bd, int t) {
    const int ko = t * 32;
    glds16(aP + ko, Ad + stg);
    glds16(bP + ko, Bd + stg);
  };
  auto COMPUTE = [&](const u16* As, const u16* Bs) {
    bf16x8 af[4], bfr[2];
#pragma unroll
    for (int i = 0; i < 4; i++)
      af[i] = *reinterpret_cast<const bf16x8*>(&As[(wm + i * 16 + r16) * 32 + quad * 8]);
#pragma unroll
    for (int i = 0; i < 2; i++)
      bfr[i] = *reinterpret_cast<const bf16x8*>(&Bs[(wn + i * 16 + r16) * 32 + quad * 8]);
#pragma unroll
    for (int mi = 0; mi < 4; mi++)
#pragma unroll
      for (int ni = 0; ni < 2; ni++) acc[mi][ni] = mfma16(af[mi], bfr[ni], acc[mi][ni]);
  };

  const int NT = K / 32;  // 32 for all uses; divisible by 4
  STAGE(A0s, B0s, 0);
  STAGE(A1s, B1s, 1);
  for (int t = 0; t < NT; t += 4) {
    if (t + 2 < NT) { STAGE(A2s, B2s, t + 2); PIPE_WAIT(4); }
    else if (t + 1 < NT) PIPE_WAIT(2);
    else PIPE_WAIT(0);
    PIPE_BAR();
    COMPUTE(A0s, B0s);
    if (t + 3 < NT) { STAGE(A3s, B3s, t + 3); PIPE_WAIT(4); }
    else if (t + 2 < NT) PIPE_WAIT(2);
    else PIPE_WAIT(0);
    PIPE_BAR();
    COMPUTE(A1s, B1s);
    if (t + 4 < NT) { STAGE(A0s, B0s, t + 4); PIPE_WAIT(4); }
    else if (t + 3 < NT) PIPE_WAIT(2);
    else PIPE_WAIT(0);
    PIPE_BAR();
    COMPUTE(A2s, B2s);
    if (t + 5 < NT) { STAGE(A1s, B1s, t + 5); PIPE_WAIT(4); }
    else if (t + 4 < NT) PIPE_WAIT(2);
    else PIPE_WAIT(0);
    PIPE_BAR();
    COMPUTE(A3s, B3s);
  }

#pragma unroll
  for (int mi = 0; mi < 4; mi++) {
#pragma unroll
    for (int ni = 0; ni < 2; ni++) {
      const int col = bn + wn + ni * 16 + r16;
      const int row0 = bm + wm + mi * 16 + quad * 4;
      if constexpr (EPI == EPI_KV) {
        if (col < Cc) {
#pragma unroll
          for (int r = 0; r < 4; r++) {
            const int row = row0 + r;
            const int key = row & (S2c - 1);
            const float y =
                acc[mi][ni][r] + bias[col] + pos[(key & (Sc - 1)) * HDc + (col & 63)];
            outb[(size_t)row * Cc + col] = f2b(y);
          }
        } else {
          const int c2 = col - Cc;
          const int h = c2 >> 6, d = c2 & 63;
          const int b = row0 >> 11, key0 = row0 & (S2c - 1);
          const float bb = bias2[c2];
          ushort4 pk;
          pk.x = f2b(acc[mi][ni][0] + bb);
          pk.y = f2b(acc[mi][ni][1] + bb);
          pk.z = f2b(acc[mi][ni][2] + bb);
          pk.w = f2b(acc[mi][ni][3] + bb);
          *(ushort4*)&out2[(((size_t)(b * Hc + h) * HDc + d) << 11) + key0] = pk;
        }
      } else {  // EPI_GELU
#pragma unroll
        for (int r = 0; r < 4; r++) {
          const float y = acc[mi][ni][r] + bias[col];
          outb[(size_t)(row0 + r) * N + col] =
              f2b(0.5f * y * (1.0f + erff(y * 0.70710678118654752f)));
        }
      }
    }
  }
}

// ------------- GEMM64: 64x64 tile, intra-block split-K, fused epilogue -------------
// R18: replaces split-K gemm + reduce for the M=2048,N=1024 projections
// (Q, O, MLP2). 512 threads = 8 waves: 2x2 spatial quadrants (32x32, acc[2][2])
// x 2 K-halves. Grid (N/64)x(M/64) = 512 blocks = 2 blocks/CU x 8 waves =
// 4 waves/SIMD (the R7-proven occupancy). Same T4 pipeline and vmcnt ledger as
// the R7 gemm (2 loads/lane/tile -> vmcnt 4/2/0). After the K-loop, K-half-1
// waves dump acc into the dead A0s/A1s LDS (lgkmcnt(0)+barrier), K-half-0
// waves add and apply the fused epilogue. Eliminates the 32 MB pbuf write +
// 32 MB read + reduce dispatch per projection (~190 MB HBM total, 2 dispatches).
// LDS [128][32] u16 per buffer = [kh][row 64][col 32]; flat stage idx = tid*8.
template <int EPI>
__global__ __launch_bounds__(512) void gemm64_kernel(
    const u16* __restrict__ A, const u16* __restrict__ BT, const float* __restrict__ bias,
    const float* __restrict__ pos, const float* __restrict__ addsrc,
    u16* __restrict__ outb, float* __restrict__ outf, int M, int N, int K) {
  __shared__ u16 A0s[128 * 32], A1s[128 * 32], A2s[128 * 32], A3s[128 * 32];
  __shared__ u16 B0s[128 * 32], B1s[128 * 32], B2s[128 * 32], B3s[128 * 32];
  const int tid = threadIdx.x;
  const int w = tid >> 6, lane = tid & 63, quad = lane >> 4, r16 = lane & 15;
  const int kh = w >> 2, qd = w & 3;
  const int wm = (qd >> 1) * 32, wn = (qd & 1) * 32;
  const int bm = blockIdx.y * 64, bn = blockIdx.x * 64;
  const int K2 = K >> 1;

  // staging: lane tid stages A row (tid>>2)&63 of K-half tid>>8, 16 B at (tid&3)*8;
  // same for B. LDS flat dest = tid*8 u16 (wave-uniform base w*512 + lane*8).
  const int sr = (tid >> 2) & 63, sh = tid >> 8, scb = (tid & 3) * 8;
  const u16* aP = A + (size_t)(bm + sr) * K + sh * K2 + scb;
  const u16* bP = BT + (size_t)(bn + sr) * K + sh * K2 + scb;
  const int stg = w * 512;

  f32x4 acc[2][2] = {};

  auto STAGE = [&](u16* Ad, u16* Bd, int t) {
    glds16(aP + t * 32, Ad + stg);
    glds16(bP + t * 32, Bd + stg);
  };
  auto COMPUTE = [&](const u16* As, const u16* Bs) {
    bf16x8 af[2], bfr[2];
#pragma unroll
    for (int i = 0; i < 2; i++) {
      af[i] = *reinterpret_cast<const bf16x8*>(
          &As[(kh * 64 + wm + i * 16 + r16) * 32 + quad * 8]);
      bfr[i] = *reinterpret_cast<const bf16x8*>(
          &Bs[(kh * 64 + wn + i * 16 + r16) * 32 + quad * 8]);
    }
#pragma unroll
    for (int mi = 0; mi < 2; mi++)
#pragma unroll
      for (int ni = 0; ni < 2; ni++) acc[mi][ni] = mfma16(af[mi], bfr[ni], acc[mi][ni]);
  };

  const int NT = K2 / 32;  // 16 (K=1024) or 64 (K=4096); divisible by 4
  STAGE(A0s, B0s, 0);
  STAGE(A1s, B1s, 1);
  for (int t = 0; t < NT; t += 4) {
    if (t + 2 < NT) { STAGE(A2s, B2s, t + 2); PIPE_WAIT(4); }
    else if (t + 1 < NT) PIPE_WAIT(2);
    else PIPE_WAIT(0);
    PIPE_BAR();
    COMPUTE(A0s, B0s);
    if (t + 3 < NT) { STAGE(A3s, B3s, t + 3); PIPE_WAIT(4); }
    else if (t + 2 < NT) PIPE_WAIT(2);
    else PIPE_WAIT(0);
    PIPE_BAR();
    COMPUTE(A1s, B1s);
    if (t + 4 < NT) { STAGE(A0s, B0s, t + 4); PIPE_WAIT(4); }
    else if (t + 3 < NT) PIPE_WAIT(2);
    else PIPE_WAIT(0);
    PIPE_BAR();
    COMPUTE(A2s, B2s);
    if (t + 5 < NT) { STAGE(A1s, B1s, t + 5); PIPE_WAIT(4); }
    else if (t + 4 < NT) PIPE_WAIT(2);
    else PIPE_WAIT(0);
    PIPE_BAR();
    COMPUTE(A3s, B3s);
  }

  // cross-K-half reduction through the (now dead) A0s/A1s, then fused epilogue.
  PIPE_BAR();  // all LDS reads of the K-loop complete before reuse
  float* rb = (qd < 2 ? (float*)A0s : (float*)A1s) + (qd & 1) * 1024;  // 4 KB/quadrant
  if (kh == 1) {
#pragma unroll
    for (int mi = 0; mi < 2; mi++)
#pragma unroll
      for (int ni = 0; ni < 2; ni++)
#pragma unroll
        for (int r = 0; r < 4; r++)
          rb[(mi * 16 + quad * 4 + r) * 32 + ni * 16 + r16] = acc[mi][ni][r];
  }
  LGKM_FENCE();
  PIPE_BAR();
  if (kh == 0) {
#pragma unroll
    for (int mi = 0; mi < 2; mi++)
#pragma unroll
      for (int ni = 0; ni < 2; ni++) {
        const int col = bn + wn + ni * 16 + r16;
        const float bcol = bias[col];
#pragma unroll
        for (int r = 0; r < 4; r++) {
          const int row = bm + wm + mi * 16 + quad * 4 + r;
          const float y =
              acc[mi][ni][r] + rb[(mi * 16 + quad * 4 + r) * 32 + ni * 16 + r16] + bcol;
          const size_t flat = (size_t)row * N + col;
          if constexpr (EPI == EPI_Q) {
            constexpr float scq = 0.180336880111120426f;  // (1/8)*log2(e)
            outb[flat] = f2b((y + pos[(row & (Sc - 1)) * HDc + (col & 63)]) * scq);
          } else {  // EPI_O / EPI_FINAL: + addsrc, f32 out
            outf[flat] = y + addsrc[flat];
          }
        }
      }
  }
}

// ---------------- fused attention: grid (bh, qt) ----------------
// R13 (kept, verified R4): both halves in one block -> uniform 17 units/block;
// T4 counted-vmcnt pipeline (4 distinct K + 4 distinct V buffers, raw
// s_barrier, vmcnt(8) = 4 loads/unit x 2 units in flight); o/l accumulated
// in-register across both halves; normalized bf16 output written directly.
// Unit p: p<=qt -> keys p*64.. (f-half; mask key>qrow at p==qt);
//         p>qt  -> keys Sc+(p-1)*64.. (r-half; mask key-Sc<qrow at p==qt+1).
// qb: [b,q,h,d] bf16 (pre-scaled by (1/8)*log2e); kb: [b,key(2S),h,d];
// vT: [b,h,d,key(2S)]; ob: [b,q,h,d] bf16.
__global__ __launch_bounds__(256) void attn_kernel(const u16* __restrict__ qb,
                                                   const u16* __restrict__ kb,
                                                   const u16* __restrict__ vT,
                                                   u16* __restrict__ ob) {
  const int bh = blockIdx.x;
  const int qt = blockIdx.y;
  const int b = bh >> 4, head = bh & 15;
  const int tid = threadIdx.x;
  const int w = tid >> 6, lane = tid & 63, quad = lane >> 4, r16 = lane & 15;

  // per-unit K tile: [ks(2)][64 keys][32 d] (64-B rows); V tile: [ks][64 d][32 keys]
  __shared__ u16 K0s[4096], K1s[4096], K2s[4096], K3s[4096];
  __shared__ u16 V0s[4096], V1s[4096], V2s[4096], V3s[4096];
  __shared__ u16 Ps[4][16 * 68];  // per-wave P round-trip (stride 68: conflict-free)
  u16* ps = Ps[w];

  const int qw = qt * 64 + w * 16;  // this wave's 16 queries

  bf16x8 aq[2];
  {
    const u16* qp = qb + ((size_t)((b * Sc + qw + r16) * Hc + head)) * HDc + quad * 8;
    aq[0] = *(const bf16x8*)qp;
    aq[1] = *(const bf16x8*)(qp + 32);
  }

  const size_t krow = (size_t)Hc * HDc;
  const u16* kbase = kb + ((size_t)b * S2c * Hc + head) * HDc;
  const u16* vbase = vT + ((size_t)(b * Hc + head)) * HDc * S2c;

  // cooperative staging map: wave w covers rows w*16 + lane/4, 16 B at (lane&3)*8
  const int srow = w * 16 + (lane >> 2);
  const int scol = (lane & 3) * 8;
  const int stg = w * 16 * 32;  // wave-uniform LDS stage base (u16 offset)
  const u16* kS = kbase + (size_t)srow * krow + scol;   // + key0*krow (+32 for ks=1)
  const u16* vS = vbase + (size_t)srow * S2c + scol;    // + key0     (+32 for ks=1)

  f32x4 o_acc[4] = {};
  float lsum[4] = {};

  auto K0OF = [&](int p) -> int { return (p <= qt) ? p * 64 : Sc + (p - 1) * 64; };

  auto STAGE = [&](u16* Kd, u16* Vd, int p) {
    const int k0 = K0OF(p);
    glds16(kS + (size_t)k0 * krow, Kd + stg);
    glds16(kS + (size_t)k0 * krow + 32, Kd + 2048 + stg);
    glds16(vS + k0, Vd + stg);
    glds16(vS + k0 + 32, Vd + 2048 + stg);
  };

  auto COMPUTE = [&](const u16* Kc, const u16* Vc, int p) {
    const int k0 = K0OF(p);
    // QK^T from LDS
    f32x4 sacc[4] = {};
#pragma unroll
    for (int ks = 0; ks < 2; ks++)
#pragma unroll
      for (int ni = 0; ni < 4; ni++) {
        const bf16x8 bk = *(const bf16x8*)&Kc[ks * 2048 + (ni * 16 + r16) * 32 + quad * 8];
        sacc[ni] = mfma16(aq[ks], bk, sacc[ni]);
      }
    const int mode = (p == qt) ? 1 : ((p == qt + 1) ? 2 : 0);
#pragma unroll
    for (int r = 0; r < 4; r++) {
      const int qrow = qw + quad * 4 + r;
#pragma unroll
      for (int ni = 0; ni < 4; ni++) {
        float s = sacc[ni][r];
        if (mode == 1) { const int key = k0 + ni * 16 + r16; if (key > qrow) s = -128.0f; }
        else if (mode == 2) { const int key = k0 - Sc + ni * 16 + r16; if (key < qrow) s = -128.0f; }
        const float pe = __builtin_amdgcn_exp2f(s);
        lsum[r] += pe;
        ps[(quad * 4 + r) * 68 + ni * 16 + r16] = f2b_fast(pe);
      }
    }
    // PV from LDS (Ps is wave-private: lgkm ordering only, no barrier needed)
#pragma unroll
    for (int ks = 0; ks < 2; ks++) {
      const bf16x8 ap = *(const bf16x8*)(&ps[r16 * 68 + ks * 32 + quad * 8]);
#pragma unroll
      for (int ni = 0; ni < 4; ni++) {
        const bf16x8 bv_ = *(const bf16x8*)&Vc[ks * 2048 + (ni * 16 + r16) * 32 + quad * 8];
        o_acc[ni] = mfma16(ap, bv_, o_acc[ni]);
      }
    }
  };

  constexpr int NU = 17;  // (qt+1) + (16-qt), uniform for all blocks
  STAGE(K0s, V0s, 0);
  STAGE(K1s, V1s, 1);
  for (int t = 0; t < NU; t += 4) {
    {
      if (t + 2 < NU) { STAGE(K2s, V2s, t + 2); PIPE_WAIT(8); }
      else if (t + 1 < NU) PIPE_WAIT(4);
      else PIPE_WAIT(0);
      PIPE_BAR();
      COMPUTE(K0s, V0s, t);
    }
    if (t + 1 < NU) {
      if (t + 3 < NU) { STAGE(K3s, V3s, t + 3); PIPE_WAIT(8); }
      else if (t + 2 < NU) PIPE_WAIT(4);
      else PIPE_WAIT(0);
      PIPE_BAR();
      COMPUTE(K1s, V1s, t + 1);
    }
    if (t + 2 < NU) {
      if (t + 4 < NU) { STAGE(K0s, V0s, t + 4); PIPE_WAIT(8); }
      else if (t + 3 < NU) PIPE_WAIT(4);
      else PIPE_WAIT(0);
      PIPE_BAR();
      COMPUTE(K2s, V2s, t + 2);
    }
    if (t + 3 < NU) {
      if (t + 5 < NU) { STAGE(K1s, V1s, t + 5); PIPE_WAIT(8); }
      else if (t + 4 < NU) PIPE_WAIT(4);
      else PIPE_WAIT(0);
      PIPE_BAR();
      COMPUTE(K3s, V3s, t + 3);
    }
  }

  // normalize in-register and write bf16 [b,q,h,d] directly
#pragma unroll
  for (int r = 0; r < 4; r++) {
    float l = lsum[r];
    l += __shfl_xor(l, 1);
    l += __shfl_xor(l, 2);
    l += __shfl_xor(l, 4);
    l += __shfl_xor(l, 8);
    lsum[r] = 1.0f / l;
  }
#pragma unroll
  for (int r = 0; r < 4; r++) {
    u16* od = ob + ((size_t)((b * Sc + qw + quad * 4 + r) * Hc + head)) * HDc;
#pragma unroll
    for (int ni = 0; ni < 4; ni++) od[ni * 16 + r16] = f2b(o_acc[ni][r] * lsum[r]);
  }
}

extern "C" void kernel_launch(void* const* d_in, const int* in_sizes, int n_in, void* d_out,
                              int out_size, void* d_ws, size_t ws_size, hipStream_t stream) {
  const float* fwd = (const float*)d_in[0];
  const float* bwd = (const float*)d_in[1];
  const float* pos = (const float*)d_in[2];
  const float* ln1g = (const float*)d_in[3];
  const float* ln1b = (const float*)d_in[4];
  const float* Wq = (const float*)d_in[5];
  const float* bq = (const float*)d_in[6];
  const float* Wk = (const float*)d_in[7];
  const float* bk = (const float*)d_in[8];
  const float* Wv = (const float*)d_in[9];
  const float* bv = (const float*)d_in[10];
  const float* Wo = (const float*)d_in[11];
  const float* bo = (const float*)d_in[12];
  const float* ln2g = (const float*)d_in[13];
  const float* ln2b = (const float*)d_in[14];
  const float* mlpg = (const float*)d_in[15];
  const float* mlpb = (const float*)d_in[16];
  const float* W1 = (const float*)d_in[17];
  const float* b1 = (const float*)d_in[18];
  const float* W2 = (const float*)d_in[19];
  const float* b2 = (const float*)d_in[20];

  char* p = (char*)d_ws;
  auto alloc = [&](size_t bytes) -> char* {
    char* r = p;
    p += (bytes + 255) & ~(size_t)255;
    return r;
  };
  float* comb = (float*)alloc((size_t)BSc * Cc * 4);
  float* xbuf = (float*)alloc((size_t)BSc * Cc * 4);
  u16* cx = (u16*)alloc((size_t)BSc * Cc * 2);
  u16* ae = (u16*)alloc((size_t)BS2c * Cc * 2);
  u16* qbuf = (u16*)alloc((size_t)BSc * Cc * 2);
  u16* kbuf = (u16*)alloc((size_t)BS2c * Cc * 2);
  u16* vTb = (u16*)alloc((size_t)BS2c * Cc * 2);
  u16* obuf = (u16*)alloc((size_t)BSc * Cc * 2);
  u16* hb = (u16*)alloc((size_t)BSc * Cc * 2);
  u16* midb = (u16*)alloc((size_t)BSc * ECc * 2);
  u16* WqT = (u16*)alloc((size_t)Cc * Cc * 2);
  u16* WkvT = (u16*)alloc((size_t)2 * Cc * Cc * 2);
  u16* WoT = (u16*)alloc((size_t)Cc * Cc * 2);
  u16* W1T = (u16*)alloc((size_t)ECc * Cc * 2);
  u16* W2T = (u16*)alloc((size_t)Cc * ECc * 2);

  const dim3 tb(32, 8);
  transpose4_kernel<<<dim3(32, 32, 4), tb, 0, stream>>>(Wq, Wk, Wv, Wo, WqT, WkvT, WoT);
  transpose_kernel<<<dim3(128, 32), tb, 0, stream>>>(W1, W1T, Cc, ECc);
  transpose_kernel<<<dim3(32, 128), tb, 0, stream>>>(W2, W2T, ECc, Cc);

  prep_ln_kernel<<<BSc + BS2c, 256, 0, stream>>>(fwd, bwd, ln1g, ln1b, comb, cx, ae);

  // Q = bf16((cx @ WqT^T + bq + pos) * sc)  (64x64 tiles, fused epilogue, 512 blocks)
  gemm64_kernel<EPI_Q><<<dim3(Cc / 64, BSc / 64), 512, 0, stream>>>(
      cx, WqT, bq, pos, nullptr, qbuf, nullptr, BSc, Cc, Cc);

  // K,V fused (N=2048, 512 blocks)
  gemm_kernel<EPI_KV><<<dim3(2 * Cc / 128, BS2c / 128), 512, 0, stream>>>(
      ae, WkvT, bk, bv, pos, kbuf, vTb, BS2c, 2 * Cc, Cc);

  // fused attention (both halves per block; writes normalized bf16 obuf directly)
  attn_kernel<<<dim3(Bc * Hc, Sc / 64), 256, 0, stream>>>(qbuf, kbuf, vTb, obuf);

  // x = comb + (o @ WoT^T + bo)  (64x64 tiles, fused epilogue -> xbuf f32)
  gemm64_kernel<EPI_O><<<dim3(Cc / 64, BSc / 64), 512, 0, stream>>>(
      obuf, WoT, bo, nullptr, comb, nullptr, xbuf, BSc, Cc, Cc);

  ln2_kernel<<<BSc, 256, 0, stream>>>(xbuf, ln2g, ln2b, mlpg, mlpb, hb);

  // mid = gelu(h @ W1T^T + b1)  (N=4096, 512 blocks)
  gemm_kernel<EPI_GELU><<<dim3(ECc / 128, BSc / 128), 512, 0, stream>>>(
      hb, W1T, b1, nullptr, nullptr, midb, nullptr, BSc, ECc, Cc);

  // out = x + (mid @ W2T^T + b2)  (64x64 tiles over K=4096, fused epilogue -> d_out)
  gemm64_kernel<EPI_FINAL><<<dim3(Cc / 64, BSc / 64), 512, 0, stream>>>(
      midb, W2T, b2, nullptr, xbuf, nullptr, (float*)d_out, BSc, Cc, ECc);
}

// Round 10
// 300.187 us; speedup vs baseline: 1.2083x; 1.0248x over previous
//
#include <hip/hip_runtime.h>
#include <hip/hip_bf16.h>
#include <cstdint>

#define DI __device__ __forceinline__

typedef unsigned short u16;
typedef __bf16 bf16x8 __attribute__((ext_vector_type(8)));
typedef float f32x4 __attribute__((ext_vector_type(4)));

constexpr int Bc  = 2;
constexpr int Sc  = 1024;
constexpr int Cc  = 1024;
constexpr int Hc  = 16;
constexpr int HDc = 64;
constexpr int S2c = 2048;
constexpr int ECc = 4096;
constexpr int BSc  = Bc * Sc;   // 2048
constexpr int BS2c = Bc * S2c;  // 4096

constexpr int EPI_KV = 0, EPI_Q = 1, EPI_O = 3, EPI_GELU = 4, EPI_FINAL = 5;

DI u16 f2b(float f) {
  __hip_bfloat16 h = __float2bfloat16(f);
  u16 u;
  __builtin_memcpy(&u, &h, 2);
  return u;
}

// fast bf16 pack (round-half-up); fine for p in [0,1]
DI u16 f2b_fast(float f) {
  uint32_t u;
  __builtin_memcpy(&u, &f, 4);
  return (u16)((u + 0x8000u) >> 16);
}

// CK-style direct global->LDS (16B per lane; LDS dest = wave-uniform base + lane*16)
DI void glds16(const void* g, void* l) {
  auto* lp = reinterpret_cast<__attribute__((address_space(3))) uint32_t*>(
      reinterpret_cast<uintptr_t>(l));
  __builtin_amdgcn_global_load_lds(
      reinterpret_cast<const __attribute__((address_space(1))) uint32_t*>(
          reinterpret_cast<uintptr_t>(g)),
      lp, 16, 0, 0);
}

DI f32x4 mfma16(bf16x8 a, bf16x8 b, f32x4 c) {
  return __builtin_amdgcn_mfma_f32_16x16x32_bf16(a, b, c, 0, 0, 0);
}

// counted vmcnt wait + scheduling fence (rule #18: pin code motion around inline-asm waits)
#define PIPE_WAIT(N)                                            \
  do {                                                          \
    asm volatile("s_waitcnt vmcnt(" #N ")" ::: "memory");       \
    __builtin_amdgcn_sched_barrier(0);                          \
  } while (0)
#define PIPE_BAR()                                              \
  do {                                                          \
    __builtin_amdgcn_s_barrier();                               \
    __builtin_amdgcn_sched_barrier(0);                          \
  } while (0)
#define LGKM_FENCE()                                            \
  do {                                                          \
    asm volatile("s_waitcnt lgkmcnt(0)" ::: "memory");          \
    __builtin_amdgcn_sched_barrier(0);                          \
  } while (0)

// ------------- fused transpose of the four CxC weights: WT[n][k] = W[k][n] -------------
__global__ __launch_bounds__(256) void transpose4_kernel(const float* __restrict__ Wq,
                                                         const float* __restrict__ Wk,
                                                         const float* __restrict__ Wv,
                                                         const float* __restrict__ Wo,
                                                         u16* __restrict__ WqT,
                                                         u16* __restrict__ WkvT,
                                                         u16* __restrict__ WoT) {
  __shared__ float tile[32][33];
  const int z = blockIdx.z;
  const float* W = (z == 0) ? Wq : (z == 1) ? Wk : (z == 2) ? Wv : Wo;
  u16* WT = (z == 0) ? WqT : (z == 1) ? WkvT : (z == 2) ? (WkvT + (size_t)Cc * Cc) : WoT;
  const int bx = blockIdx.x, by = blockIdx.y;
  const int tx = threadIdx.x, ty = threadIdx.y;
  const int c = bx * 32 + tx;
#pragma unroll
  for (int i = ty; i < 32; i += 8) tile[i][tx] = W[(size_t)(by * 32 + i) * Cc + c];
  __syncthreads();
#pragma unroll
  for (int i = ty; i < 32; i += 8)
    WT[(size_t)(bx * 32 + i) * Cc + by * 32 + tx] = f2b(tile[tx][i]);
}

// ---------------- transpose + fp32->bf16 convert: WT[n][k] = W[k][n] ----------------
__global__ __launch_bounds__(256) void transpose_kernel(const float* __restrict__ W,
                                                        u16* __restrict__ WT, int R, int Cn) {
  __shared__ float tile[32][33];
  const int bx = blockIdx.x, by = blockIdx.y;
  const int tx = threadIdx.x, ty = threadIdx.y;
  const int c = bx * 32 + tx;
#pragma unroll
  for (int i = ty; i < 32; i += 8) tile[i][tx] = W[(size_t)(by * 32 + i) * Cn + c];
  __syncthreads();
#pragma unroll
  for (int i = ty; i < 32; i += 8)
    WT[(size_t)(bx * 32 + i) * R + by * 32 + tx] = f2b(tile[tx][i]);
}

// ---------------- prep: comb + LN(comb)->cx ; LN(all_embed)->ae ----------------
__global__ __launch_bounds__(256) void prep_ln_kernel(
    const float* __restrict__ fwd, const float* __restrict__ bwd, const float* __restrict__ g,
    const float* __restrict__ be, float* __restrict__ comb, u16* __restrict__ cx,
    u16* __restrict__ ae) {
  __shared__ float red[2][4];
  const int row = blockIdx.x, tid = threadIdx.x;
  const int c = tid * 4;
  float4 x;
  u16* dst;
  if (row < BSc) {
    const int b = row >> 10, s = row & (Sc - 1);
    const float4 f = *(const float4*)(fwd + ((size_t)(b * (Sc + 1) + s)) * Cc + c);
    const float4 r = *(const float4*)(bwd + ((size_t)(b * (Sc + 1) + s + 1)) * Cc + c);
    const float k = 0.70710678118654752f;
    x.x = (f.x + r.x) * k; x.y = (f.y + r.y) * k;
    x.z = (f.z + r.z) * k; x.w = (f.w + r.w) * k;
    *(float4*)(comb + (size_t)row * Cc + c) = x;
    dst = cx + (size_t)row * Cc;
  } else {
    const int idx = row - BSc;
    const int b = idx >> 11, t = idx & (S2c - 1);
    const float* src = (t < Sc) ? (fwd + ((size_t)(b * (Sc + 1) + t)) * Cc)
                                : (bwd + ((size_t)(b * (Sc + 1) + (t - Sc) + 1)) * Cc);
    x = *(const float4*)(src + c);
    dst = ae + (size_t)idx * Cc;
  }
  float s1 = x.x + x.y + x.z + x.w;
  float s2 = x.x * x.x + x.y * x.y + x.z * x.z + x.w * x.w;
  for (int off = 32; off; off >>= 1) { s1 += __shfl_down(s1, off); s2 += __shfl_down(s2, off); }
  if ((tid & 63) == 0) { red[0][tid >> 6] = s1; red[1][tid >> 6] = s2; }
  __syncthreads();
  s1 = red[0][0] + red[0][1] + red[0][2] + red[0][3];
  s2 = red[1][0] + red[1][1] + red[1][2] + red[1][3];
  const float mean = s1 * (1.0f / Cc);
  const float rstd = rsqrtf(s2 * (1.0f / Cc) - mean * mean + 1e-5f);
  const float4 gv = *(const float4*)(g + c);
  const float4 bv = *(const float4*)(be + c);
  ushort4 o;
  o.x = f2b((x.x - mean) * rstd * gv.x + bv.x);
  o.y = f2b((x.y - mean) * rstd * gv.y + bv.y);
  o.z = f2b((x.z - mean) * rstd * gv.z + bv.z);
  o.w = f2b((x.w - mean) * rstd * gv.w + bv.w);
  *(ushort4*)(dst + c) = o;
}

// ---------------- double LN: h = LN(LN(x,g2,b2),gm,bm) ----------------
__global__ __launch_bounds__(256) void ln2_kernel(const float* __restrict__ x,
                                                  const float* __restrict__ g2,
                                                  const float* __restrict__ b2,
                                                  const float* __restrict__ gm,
                                                  const float* __restrict__ bm,
                                                  u16* __restrict__ h) {
  __shared__ float red[2][4];
  const int row = blockIdx.x, tid = threadIdx.x;
  const int c = tid * 4;
  const float4 v = *(const float4*)(x + (size_t)row * Cc + c);
  float s1 = v.x + v.y + v.z + v.w;
  float s2 = v.x * v.x + v.y * v.y + v.z * v.z + v.w * v.w;
  for (int off = 32; off; off >>= 1) { s1 += __shfl_down(s1, off); s2 += __shfl_down(s2, off); }
  if ((tid & 63) == 0) { red[0][tid >> 6] = s1; red[1][tid >> 6] = s2; }
  __syncthreads();
  s1 = red[0][0] + red[0][1] + red[0][2] + red[0][3];
  s2 = red[1][0] + red[1][1] + red[1][2] + red[1][3];
  float mean = s1 * (1.0f / Cc);
  float rstd = rsqrtf(s2 * (1.0f / Cc) - mean * mean + 1e-5f);
  const float4 ga = *(const float4*)(g2 + c);
  const float4 ba = *(const float4*)(b2 + c);
  const float t0 = (v.x - mean) * rstd * ga.x + ba.x;
  const float t1 = (v.y - mean) * rstd * ga.y + ba.y;
  const float t2 = (v.z - mean) * rstd * ga.z + ba.z;
  const float t3 = (v.w - mean) * rstd * ga.w + ba.w;
  s1 = t0 + t1 + t2 + t3;
  s2 = t0 * t0 + t1 * t1 + t2 * t2 + t3 * t3;
  for (int off = 32; off; off >>= 1) { s1 += __shfl_down(s1, off); s2 += __shfl_down(s2, off); }
  __syncthreads();
  if ((tid & 63) == 0) { red[0][tid >> 6] = s1; red[1][tid >> 6] = s2; }
  __syncthreads();
  s1 = red[0][0] + red[0][1] + red[0][2] + red[0][3];
  s2 = red[1][0] + red[1][1] + red[1][2] + red[1][3];
  mean = s1 * (1.0f / Cc);
  rstd = rsqrtf(s2 * (1.0f / Cc) - mean * mean + 1e-5f);
  const float4 gb = *(const float4*)(gm + c);
  const float4 bb = *(const float4*)(bm + c);
  ushort4 o;
  o.x = f2b((t0 - mean) * rstd * gb.x + bb.x);
  o.y = f2b((t1 - mean) * rstd * gb.y + bb.y);
  o.z = f2b((t2 - mean) * rstd * gb.z + bb.z);
  o.w = f2b((t3 - mean) * rstd * gb.w + bb.w);
  *(ushort4*)(h + (size_t)row * Cc + c) = o;
}

// ---------------- GEMM (wide-N): Y = A(MxK) @ BT(NxK)^T, fused epilogues ----------------
// 128x128 tile, BK=32, glds16 staging, T4 counted-vmcnt 4-buffer pipeline.
// R7-MEASURED-GOOD configuration: 8 waves (512 threads), wave = 64x32 quadrant
// (acc[4][2], 8 MFMA/step); staging 512 lanes x 16 B = one 8 KB half-tile per
// pass (1 A + 1 B load/lane); steady-state wait vmcnt(4); tails 2, 0.
// Used for KV (N=2048) and MLP1 (N=4096) only. (No XCD swizzle here — control
// for the R10 gemm64 swizzle experiment.)
template <int EPI>
__global__ __launch_bounds__(512) void gemm_kernel(
    const u16* __restrict__ A, const u16* __restrict__ BT, const float* __restrict__ bias,
    const float* __restrict__ bias2, const float* __restrict__ pos,
    u16* __restrict__ outb, u16* __restrict__ out2, int M, int N, int K) {
  __shared__ u16 A0s[128 * 32], A1s[128 * 32], A2s[128 * 32], A3s[128 * 32];
  __shared__ u16 B0s[128 * 32], B1s[128 * 32], B2s[128 * 32], B3s[128 * 32];
  const int tid = threadIdx.x;
  const int w = tid >> 6, lane = tid & 63, quad = lane >> 4, r16 = lane & 15;
  const int bm = blockIdx.y * 128, bn = blockIdx.x * 128;
  const int wm = (w >> 2) * 64, wn = (w & 3) * 32;  // 2 M-waves x 4 N-waves

  const int srow = tid >> 2, scol = (tid & 3) * 8;  // 512 lanes cover 128 rows x 32 cols
  const u16* aP = A + (size_t)(bm + srow) * K + scol;
  const u16* bP = BT + (size_t)(bn + srow) * K + scol;
  const int stg = (w * 16) * 32;  // wave-uniform LDS stage base (u16 offset)

  f32x4 acc[4][2] = {};

  auto STAGE = [&](u16* Ad, u16* Bd, int t) {
    const int ko = t * 32;
    glds16(aP + ko, Ad + stg);
    glds16(bP + ko, Bd + stg);
  };
  auto COMPUTE = [&](const u16* As, const u16* Bs) {
    bf16x8 af[4], bfr[2];
#pragma unroll
    for (int i = 0; i < 4; i++)
      af[i] = *reinterpret_cast<const bf16x8*>(&As[(wm + i * 16 + r16) * 32 + quad * 8]);
#pragma unroll
    for (int i = 0; i < 2; i++)
      bfr[i] = *reinterpret_cast<const bf16x8*>(&Bs[(wn + i * 16 + r16) * 32 + quad * 8]);
#pragma unroll
    for (int mi = 0; mi < 4; mi++)
#pragma unroll
      for (int ni = 0; ni < 2; ni++) acc[mi][ni] = mfma16(af[mi], bfr[ni], acc[mi][ni]);
  };

  const int NT = K / 32;  // 32 for all uses; divisible by 4
  STAGE(A0s, B0s, 0);
  STAGE(A1s, B1s, 1);
  for (int t = 0; t < NT; t += 4) {
    if (t + 2 < NT) { STAGE(A2s, B2s, t + 2); PIPE_WAIT(4); }
    else if (t + 1 < NT) PIPE_WAIT(2);
    else PIPE_WAIT(0);
    PIPE_BAR();
    COMPUTE(A0s, B0s);
    if (t + 3 < NT) { STAGE(A3s, B3s, t + 3); PIPE_WAIT(4); }
    else if (t + 2 < NT) PIPE_WAIT(2);
    else PIPE_WAIT(0);
    PIPE_BAR();
    COMPUTE(A1s, B1s);
    if (t + 4 < NT) { STAGE(A0s, B0s, t + 4); PIPE_WAIT(4); }
    else if (t + 3 < NT) PIPE_WAIT(2);
    else PIPE_WAIT(0);
    PIPE_BAR();
    COMPUTE(A2s, B2s);
    if (t + 5 < NT) { STAGE(A1s, B1s, t + 5); PIPE_WAIT(4); }
    else if (t + 4 < NT) PIPE_WAIT(2);
    else PIPE_WAIT(0);
    PIPE_BAR();
    COMPUTE(A3s, B3s);
  }

#pragma unroll
  for (int mi = 0; mi < 4; mi++) {
#pragma unroll
    for (int ni = 0; ni < 2; ni++) {
      const int col = bn + wn + ni * 16 + r16;
      const int row0 = bm + wm + mi * 16 + quad * 4;
      if constexpr (EPI == EPI_KV) {
        if (col < Cc) {
#pragma unroll
          for (int r = 0; r < 4; r++) {
            const int row = row0 + r;
            const int key = row & (S2c - 1);
            const float y =
                acc[mi][ni][r] + bias[col] + pos[(key & (Sc - 1)) * HDc + (col & 63)];
            outb[(size_t)row * Cc + col] = f2b(y);
          }
        } else {
          const int c2 = col - Cc;
          const int h = c2 >> 6, d = c2 & 63;
          const int b = row0 >> 11, key0 = row0 & (S2c - 1);
          const float bb = bias2[c2];
          ushort4 pk;
          pk.x = f2b(acc[mi][ni][0] + bb);
          pk.y = f2b(acc[mi][ni][1] + bb);
          pk.z = f2b(acc[mi][ni][2] + bb);
          pk.w = f2b(acc[mi][ni][3] + bb);
          *(ushort4*)&out2[(((size_t)(b * Hc + h) * HDc + d) << 11) + key0] = pk;
        }
      } else {  // EPI_GELU
#pragma unroll
        for (int r = 0; r < 4; r++) {
          const float y = acc[mi][ni][r] + bias[col];
          outb[(size_t)(row0 + r) * N + col] =
              f2b(0.5f * y * (1.0f + erff(y * 0.70710678118654752f)));
        }
      }
    }
  }
}

// ------------- GEMM64: 64x64 tile, intra-block split-K, fused epilogue -------------
// R18 (verified R9, -14us net) + R19: XCD-aware chunked block swizzle.
// R9 counters: FETCH_SIZE 76.5 MB (3x the ~25 MB ideal), HBM 2 TB/s, MfmaUtil
// 14.6% -> the 64x64 tile's L2 reuse is destroyed by round-robin XCD dispatch
// (consecutive blocks share an A-panel but land on 8 different private L2s).
// Fix (T1): nwg = 512 = 8 x 64 -> bijective chunked map xcd=bid%8,
// swz=xcd*64+bid/8: each XCD gets 4 M-panels x all 16 N-panels (K=1024:
// 0.5 MB A + 2 MB B per XCD -> fits 4 MB L2).
// Structure otherwise unchanged: 512 threads = 8 waves: 2x2 spatial quadrants
// (32x32, acc[2][2]) x 2 K-halves; T4 pipeline, vmcnt 4/2/0; cross-K-half
// reduction through dead A0s/A1s LDS; fused epilogue (no pbuf, no reduce).
template <int EPI>
__global__ __launch_bounds__(512) void gemm64_kernel(
    const u16* __restrict__ A, const u16* __restrict__ BT, const float* __restrict__ bias,
    const float* __restrict__ pos, const float* __restrict__ addsrc,
    u16* __restrict__ outb, float* __restrict__ outf, int M, int N, int K) {
  __shared__ u16 A0s[128 * 32], A1s[128 * 32], A2s[128 * 32], A3s[128 * 32];
  __shared__ u16 B0s[128 * 32], B1s[128 * 32], B2s[128 * 32], B3s[128 * 32];
  const int tid = threadIdx.x;
  const int w = tid >> 6, lane = tid & 63, quad = lane >> 4, r16 = lane & 15;
  const int kh = w >> 2, qd = w & 3;
  const int wm = (qd >> 1) * 32, wn = (qd & 1) * 32;
  // XCD-aware chunked swizzle (nwg = gridDim.x*gridDim.y = 512, 8 XCDs, 64/chunk)
  const int bid = blockIdx.y * gridDim.x + blockIdx.x;
  const int swz = (bid & 7) * 64 + (bid >> 3);
  const int bx = swz & (gridDim.x - 1), by = swz / gridDim.x;
  const int bm = by * 64, bn = bx * 64;
  const int K2 = K >> 1;

  // staging: lane tid stages A row (tid>>2)&63 of K-half tid>>8, 16 B at (tid&3)*8;
  // same for B. LDS flat dest = tid*8 u16 (wave-uniform base w*512 + lane*8).
  const int sr = (tid >> 2) & 63, sh = tid >> 8, scb = (tid & 3) * 8;
  const u16* aP = A + (size_t)(bm + sr) * K + sh * K2 + scb;
  const u16* bP = BT + (size_t)(bn + sr) * K + sh * K2 + scb;
  const int stg = w * 512;

  f32x4 acc[2][2] = {};

  auto STAGE = [&](u16* Ad, u16* Bd, int t) {
    glds16(aP + t * 32, Ad + stg);
    glds16(bP + t * 32, Bd + stg);
  };
  auto COMPUTE = [&](const u16* As, const u16* Bs) {
    bf16x8 af[2], bfr[2];
#pragma unroll
    for (int i = 0; i < 2; i++) {
      af[i] = *reinterpret_cast<const bf16x8*>(
          &As[(kh * 64 + wm + i * 16 + r16) * 32 + quad * 8]);
      bfr[i] = *reinterpret_cast<const bf16x8*>(
          &Bs[(kh * 64 + wn + i * 16 + r16) * 32 + quad * 8]);
    }
#pragma unroll
    for (int mi = 0; mi < 2; mi++)
#pragma unroll
      for (int ni = 0; ni < 2; ni++) acc[mi][ni] = mfma16(af[mi], bfr[ni], acc[mi][ni]);
  };

  const int NT = K2 / 32;  // 16 (K=1024) or 64 (K=4096); divisible by 4
  STAGE(A0s, B0s, 0);
  STAGE(A1s, B1s, 1);
  for (int t = 0; t < NT; t += 4) {
    if (t + 2 < NT) { STAGE(A2s, B2s, t + 2); PIPE_WAIT(4); }
    else if (t + 1 < NT) PIPE_WAIT(2);
    else PIPE_WAIT(0);
    PIPE_BAR();
    COMPUTE(A0s, B0s);
    if (t + 3 < NT) { STAGE(A3s, B3s, t + 3); PIPE_WAIT(4); }
    else if (t + 2 < NT) PIPE_WAIT(2);
    else PIPE_WAIT(0);
    PIPE_BAR();
    COMPUTE(A1s, B1s);
    if (t + 4 < NT) { STAGE(A0s, B0s, t + 4); PIPE_WAIT(4); }
    else if (t + 3 < NT) PIPE_WAIT(2);
    else PIPE_WAIT(0);
    PIPE_BAR();
    COMPUTE(A2s, B2s);
    if (t + 5 < NT) { STAGE(A1s, B1s, t + 5); PIPE_WAIT(4); }
    else if (t + 4 < NT) PIPE_WAIT(2);
    else PIPE_WAIT(0);
    PIPE_BAR();
    COMPUTE(A3s, B3s);
  }

  // cross-K-half reduction through the (now dead) A0s/A1s, then fused epilogue.
  PIPE_BAR();  // all LDS reads of the K-loop complete before reuse
  float* rb = (qd < 2 ? (float*)A0s : (float*)A1s) + (qd & 1) * 1024;  // 4 KB/quadrant
  if (kh == 1) {
#pragma unroll
    for (int mi = 0; mi < 2; mi++)
#pragma unroll
      for (int ni = 0; ni < 2; ni++)
#pragma unroll
        for (int r = 0; r < 4; r++)
          rb[(mi * 16 + quad * 4 + r) * 32 + ni * 16 + r16] = acc[mi][ni][r];
  }
  LGKM_FENCE();
  PIPE_BAR();
  if (kh == 0) {
#pragma unroll
    for (int mi = 0; mi < 2; mi++)
#pragma unroll
      for (int ni = 0; ni < 2; ni++) {
        const int col = bn + wn + ni * 16 + r16;
        const float bcol = bias[col];
#pragma unroll
        for (int r = 0; r < 4; r++) {
          const int row = bm + wm + mi * 16 + quad * 4 + r;
          const float y =
              acc[mi][ni][r] + rb[(mi * 16 + quad * 4 + r) * 32 + ni * 16 + r16] + bcol;
          const size_t flat = (size_t)row * N + col;
          if constexpr (EPI == EPI_Q) {
            constexpr float scq = 0.180336880111120426f;  // (1/8)*log2(e)
            outb[flat] = f2b((y + pos[(row & (Sc - 1)) * HDc + (col & 63)]) * scq);
          } else {  // EPI_O / EPI_FINAL: + addsrc, f32 out
            outf[flat] = y + addsrc[flat];
          }
        }
      }
  }
}

// ---------------- fused attention: grid (bh, qt) ----------------
// R13 (kept, verified R4): both halves in one block -> uniform 17 units/block;
// T4 counted-vmcnt pipeline (4 distinct K + 4 distinct V buffers, raw
// s_barrier, vmcnt(8) = 4 loads/unit x 2 units in flight); o/l accumulated
// in-register across both halves; normalized bf16 output written directly.
// Unit p: p<=qt -> keys p*64.. (f-half; mask key>qrow at p==qt);
//         p>qt  -> keys Sc+(p-1)*64.. (r-half; mask key-Sc<qrow at p==qt+1).
// qb: [b,q,h,d] bf16 (pre-scaled by (1/8)*log2e); kb: [b,key(2S),h,d];
// vT: [b,h,d,key(2S)]; ob: [b,q,h,d] bf16.
__global__ __launch_bounds__(256) void attn_kernel(const u16* __restrict__ qb,
                                                   const u16* __restrict__ kb,
                                                   const u16* __restrict__ vT,
                                                   u16* __restrict__ ob) {
  const int bh = blockIdx.x;
  const int qt = blockIdx.y;
  const int b = bh >> 4, head = bh & 15;
  const int tid = threadIdx.x;
  const int w = tid >> 6, lane = tid & 63, quad = lane >> 4, r16 = lane & 15;

  // per-unit K tile: [ks(2)][64 keys][32 d] (64-B rows); V tile: [ks][64 d][32 keys]
  __shared__ u16 K0s[4096], K1s[4096], K2s[4096], K3s[4096];
  __shared__ u16 V0s[4096], V1s[4096], V2s[4096], V3s[4096];
  __shared__ u16 Ps[4][16 * 68];  // per-wave P round-trip (stride 68: conflict-free)
  u16* ps = Ps[w];

  const int qw = qt * 64 + w * 16;  // this wave's 16 queries

  bf16x8 aq[2];
  {
    const u16* qp = qb + ((size_t)((b * Sc + qw + r16) * Hc + head)) * HDc + quad * 8;
    aq[0] = *(const bf16x8*)qp;
    aq[1] = *(const bf16x8*)(qp + 32);
  }

  const size_t krow = (size_t)Hc * HDc;
  const u16* kbase = kb + ((size_t)b * S2c * Hc + head) * HDc;
  const u16* vbase = vT + ((size_t)(b * Hc + head)) * HDc * S2c;

  // cooperative staging map: wave w covers rows w*16 + lane/4, 16 B at (lane&3)*8
  const int srow = w * 16 + (lane >> 2);
  const int scol = (lane & 3) * 8;
  const int stg = w * 16 * 32;  // wave-uniform LDS stage base (u16 offset)
  const u16* kS = kbase + (size_t)srow * krow + scol;   // + key0*krow (+32 for ks=1)
  const u16* vS = vbase + (size_t)srow * S2c + scol;    // + key0     (+32 for ks=1)

  f32x4 o_acc[4] = {};
  float lsum[4] = {};

  auto K0OF = [&](int p) -> int { return (p <= qt) ? p * 64 : Sc + (p - 1) * 64; };

  auto STAGE = [&](u16* Kd, u16* Vd, int p) {
    const int k0 = K0OF(p);
    glds16(kS + (size_t)k0 * krow, Kd + stg);
    glds16(kS + (size_t)k0 * krow + 32, Kd + 2048 + stg);
    glds16(vS + k0, Vd + stg);
    glds16(vS + k0 + 32, Vd + 2048 + stg);
  };

  auto COMPUTE = [&](const u16* Kc, const u16* Vc, int p) {
    const int k0 = K0OF(p);
    // QK^T from LDS
    f32x4 sacc[4] = {};
#pragma unroll
    for (int ks = 0; ks < 2; ks++)
#pragma unroll
      for (int ni = 0; ni < 4; ni++) {
        const bf16x8 bk = *(const bf16x8*)&Kc[ks * 2048 + (ni * 16 + r16) * 32 + quad * 8];
        sacc[ni] = mfma16(aq[ks], bk, sacc[ni]);
      }
    const int mode = (p == qt) ? 1 : ((p == qt + 1) ? 2 : 0);
#pragma unroll
    for (int r = 0; r < 4; r++) {
      const int qrow = qw + quad * 4 + r;
#pragma unroll
      for (int ni = 0; ni < 4; ni++) {
        float s = sacc[ni][r];
        if (mode == 1) { const int key = k0 + ni * 16 + r16; if (key > qrow) s = -128.0f; }
        else if (mode == 2) { const int key = k0 - Sc + ni * 16 + r16; if (key < qrow) s = -128.0f; }
        const float pe = __builtin_amdgcn_exp2f(s);
        lsum[r] += pe;
        ps[(quad * 4 + r) * 68 + ni * 16 + r16] = f2b_fast(pe);
      }
    }
    // PV from LDS (Ps is wave-private: lgkm ordering only, no barrier needed)
#pragma unroll
    for (int ks = 0; ks < 2; ks++) {
      const bf16x8 ap = *(const bf16x8*)(&ps[r16 * 68 + ks * 32 + quad * 8]);
#pragma unroll
      for (int ni = 0; ni < 4; ni++) {
        const bf16x8 bv_ = *(const bf16x8*)&Vc[ks * 2048 + (ni * 16 + r16) * 32 + quad * 8];
        o_acc[ni] = mfma16(ap, bv_, o_acc[ni]);
      }
    }
  };

  constexpr int NU = 17;  // (qt+1) + (16-qt), uniform for all blocks
  STAGE(K0s, V0s, 0);
  STAGE(K1s, V1s, 1);
  for (int t = 0; t < NU; t += 4) {
    {
      if (t + 2 < NU) { STAGE(K2s, V2s, t + 2); PIPE_WAIT(8); }
      else if (t + 1 < NU) PIPE_WAIT(4);
      else PIPE_WAIT(0);
      PIPE_BAR();
      COMPUTE(K0s, V0s, t);
    }
    if (t + 1 < NU) {
      if (t + 3 < NU) { STAGE(K3s, V3s, t + 3); PIPE_WAIT(8); }
      else if (t + 2 < NU) PIPE_WAIT(4);
      else PIPE_WAIT(0);
      PIPE_BAR();
      COMPUTE(K1s, V1s, t + 1);
    }
    if (t + 2 < NU) {
      if (t + 4 < NU) { STAGE(K0s, V0s, t + 4); PIPE_WAIT(8); }
      else if (t + 3 < NU) PIPE_WAIT(4);
      else PIPE_WAIT(0);
      PIPE_BAR();
      COMPUTE(K2s, V2s, t + 2);
    }
    if (t + 3 < NU) {
      if (t + 5 < NU) { STAGE(K1s, V1s, t + 5); PIPE_WAIT(8); }
      else if (t + 4 < NU) PIPE_WAIT(4);
      else PIPE_WAIT(0);
      PIPE_BAR();
      COMPUTE(K3s, V3s, t + 3);
    }
  }

  // normalize in-register and write bf16 [b,q,h,d] directly
#pragma unroll
  for (int r = 0; r < 4; r++) {
    float l = lsum[r];
    l += __shfl_xor(l, 1);
    l += __shfl_xor(l, 2);
    l += __shfl_xor(l, 4);
    l += __shfl_xor(l, 8);
    lsum[r] = 1.0f / l;
  }
#pragma unroll
  for (int r = 0; r < 4; r++) {
    u16* od = ob + ((size_t)((b * Sc + qw + quad * 4 + r) * Hc + head)) * HDc;
#pragma unroll
    for (int ni = 0; ni < 4; ni++) od[ni * 16 + r16] = f2b(o_acc[ni][r] * lsum[r]);
  }
}

extern "C" void kernel_launch(void* const* d_in, const int* in_sizes, int n_in, void* d_out,
                              int out_size, void* d_ws, size_t ws_size, hipStream_t stream) {
  const float* fwd = (const float*)d_in[0];
  const float* bwd = (const float*)d_in[1];
  const float* pos = (const float*)d_in[2];
  const float* ln1g = (const float*)d_in[3];
  const float* ln1b = (const float*)d_in[4];
  const float* Wq = (const float*)d_in[5];
  const float* bq = (const float*)d_in[6];
  const float* Wk = (const float*)d_in[7];
  const float* bk = (const float*)d_in[8];
  const float* Wv = (const float*)d_in[9];
  const float* bv = (const float*)d_in[10];
  const float* Wo = (const float*)d_in[11];
  const float* bo = (const float*)d_in[12];
  const float* ln2g = (const float*)d_in[13];
  const float* ln2b = (const float*)d_in[14];
  const float* mlpg = (const float*)d_in[15];
  const float* mlpb = (const float*)d_in[16];
  const float* W1 = (const float*)d_in[17];
  const float* b1 = (const float*)d_in[18];
  const float* W2 = (const float*)d_in[19];
  const float* b2 = (const float*)d_in[20];

  char* p = (char*)d_ws;
  auto alloc = [&](size_t bytes) -> char* {
    char* r = p;
    p += (bytes + 255) & ~(size_t)255;
    return r;
  };
  float* comb = (float*)alloc((size_t)BSc * Cc * 4);
  float* xbuf = (float*)alloc((size_t)BSc * Cc * 4);
  u16* cx = (u16*)alloc((size_t)BSc * Cc * 2);
  u16* ae = (u16*)alloc((size_t)BS2c * Cc * 2);
  u16* qbuf = (u16*)alloc((size_t)BSc * Cc * 2);
  u16* kbuf = (u16*)alloc((size_t)BS2c * Cc * 2);
  u16* vTb = (u16*)alloc((size_t)BS2c * Cc * 2);
  u16* obuf = (u16*)alloc((size_t)BSc * Cc * 2);
  u16* hb = (u16*)alloc((size_t)BSc * Cc * 2);
  u16* midb = (u16*)alloc((size_t)BSc * ECc * 2);
  u16* WqT = (u16*)alloc((size_t)Cc * Cc * 2);
  u16* WkvT = (u16*)alloc((size_t)2 * Cc * Cc * 2);
  u16* WoT = (u16*)alloc((size_t)Cc * Cc * 2);
  u16* W1T = (u16*)alloc((size_t)ECc * Cc * 2);
  u16* W2T = (u16*)alloc((size_t)Cc * ECc * 2);

  const dim3 tb(32, 8);
  transpose4_kernel<<<dim3(32, 32, 4), tb, 0, stream>>>(Wq, Wk, Wv, Wo, WqT, WkvT, WoT);
  transpose_kernel<<<dim3(128, 32), tb, 0, stream>>>(W1, W1T, Cc, ECc);
  transpose_kernel<<<dim3(32, 128), tb, 0, stream>>>(W2, W2T, ECc, Cc);

  prep_ln_kernel<<<BSc + BS2c, 256, 0, stream>>>(fwd, bwd, ln1g, ln1b, comb, cx, ae);

  // Q = bf16((cx @ WqT^T + bq + pos) * sc)  (64x64 tiles, fused epilogue, 512 blocks)
  gemm64_kernel<EPI_Q><<<dim3(Cc / 64, BSc / 64), 512, 0, stream>>>(
      cx, WqT, bq, pos, nullptr, qbuf, nullptr, BSc, Cc, Cc);

  // K,V fused (N=2048, 512 blocks)
  gemm_kernel<EPI_KV><<<dim3(2 * Cc / 128, BS2c / 128), 512, 0, stream>>>(
      ae, WkvT, bk, bv, pos, kbuf, vTb, BS2c, 2 * Cc, Cc);

  // fused attention (both halves per block; writes normalized bf16 obuf directly)
  attn_kernel<<<dim3(Bc * Hc, Sc / 64), 256, 0, stream>>>(qbuf, kbuf, vTb, obuf);

  // x = comb + (o @ WoT^T + bo)  (64x64 tiles, fused epilogue -> xbuf f32)
  gemm64_kernel<EPI_O><<<dim3(Cc / 64, BSc / 64), 512, 0, stream>>>(
      obuf, WoT, bo, nullptr, comb, nullptr, xbuf, BSc, Cc, Cc);

  ln2_kernel<<<BSc, 256, 0, stream>>>(xbuf, ln2g, ln2b, mlpg, mlpb, hb);

  // mid = gelu(h @ W1T^T + b1)  (N=4096, 512 blocks)
  gemm_kernel<EPI_GELU><<<dim3(ECc / 128, BSc / 128), 512, 0, stream>>>(
      hb, W1T, b1, nullptr, nullptr, midb, nullptr, BSc, ECc, Cc);

  // out = x + (mid @ W2T^T + b2)  (64x64 tiles over K=4096, fused epilogue -> d_out)
  gemm64_kernel<EPI_FINAL><<<dim3(Cc / 64, BSc / 64), 512, 0, stream>>>(
      midb, W2T, b2, nullptr, xbuf, nullptr, (float*)d_out, BSc, Cc, ECc);
}